// Round 4
// baseline (913.698 us; speedup 1.0000x reference)
//
#include <hip/hip_runtime.h>
#include <cstdint>

typedef unsigned short u16;
typedef __attribute__((ext_vector_type(8))) u16 u16x8;
typedef __attribute__((ext_vector_type(4))) u16 u16x4;
typedef __attribute__((ext_vector_type(8))) _Float16 f16x8;
typedef __attribute__((ext_vector_type(4))) float f32x4;

// ---------- helpers ----------
__device__ __forceinline__ u16 f2h(float f) {
  _Float16 h = (_Float16)f;
  return __builtin_bit_cast(u16, h);
}
__device__ __forceinline__ float h2f(u16 b) {
  _Float16 h = __builtin_bit_cast(_Float16, b);
  return (float)h;
}
__device__ __forceinline__ void gll16(const void* g, void* l) {
  auto gp = reinterpret_cast<const __attribute__((address_space(1))) unsigned int*>(
      reinterpret_cast<uintptr_t>(g));
  auto lp = reinterpret_cast<__attribute__((address_space(3))) unsigned int*>(
      reinterpret_cast<uintptr_t>(l));
  __builtin_amdgcn_global_load_lds(gp, lp, 16, 0, 0);
}

// ---------- prep: zero only the 34x34 halo ----------
__global__ __launch_bounds__(256) void halo_zero(u16* __restrict__ buf) {
  const int img = blockIdx.x, q = blockIdx.y, tid = threadIdx.x;
  u16* base = buf + (long)img * 34 * 34 * 1024;
  u16x8 z8 = {0, 0, 0, 0, 0, 0, 0, 0};
  if (q < 2) {
    u16* r0 = base + (long)(q ? 33 : 0) * 34 * 1024;
    for (int i = tid * 8; i < 34816; i += 2048) *(u16x8*)&r0[i] = z8;
  } else {
    const int x = (q == 2) ? 0 : 33;
    for (int i = tid * 8; i < 32768; i += 2048) {
      const int y = 1 + (i >> 10), c = i & 1023;
      *(u16x8*)&base[((long)y * 34 + x) * 1024 + c] = z8;
    }
  }
}

// ---------- prep: NCHW fp32 -> padded(34x34) NHWC fp16 ----------
__global__ __launch_bounds__(256) void pad_nhwc(const float* __restrict__ in,
                                                u16* __restrict__ outp) {
  const int img = blockIdx.x >> 5;
  const int y   = blockIdx.x & 31;
  __shared__ float tile[32][33];
  const int tid = threadIdx.x;
  const int xi = tid & 31, ci = tid >> 5;
  const int xo = tid >> 3, q = tid & 7;
  const float* ip = in + (long)img * 1048576 + y * 32;
  u16* op = outp + ((long)(img * 34) + y + 1) * 34 * 1024 + 1024;
  for (int c0 = 0; c0 < 1024; c0 += 32) {
#pragma unroll
    for (int k2 = 0; k2 < 4; k2++)
      tile[k2 * 8 + ci][xi] = ip[(long)(c0 + k2 * 8 + ci) * 1024 + xi];
    __syncthreads();
    u16x4 o4;
#pragma unroll
    for (int r = 0; r < 4; r++) o4[r] = f2h(tile[q * 4 + r][xo]);
    *(u16x4*)&op[(long)xo * 1024 + c0 + q * 4] = o4;
    __syncthreads();
  }
}

// ---------- prep: w[OC][1024][3][3] fp32 -> wT[OC][t*1024+c] fp16 ----------
__global__ __launch_bounds__(256) void wre3(const float* __restrict__ w,
                                            u16* __restrict__ o) {
  const int oc = blockIdx.x;
  __shared__ float buf[9216];
  const float* wp = w + (long)oc * 9216;
  for (int i = threadIdx.x; i < 9216; i += 256) buf[i] = wp[i];
  __syncthreads();
  u16* op = o + (long)oc * 9216;
  for (int k = threadIdx.x; k < 9216; k += 256) {
    int t = k >> 10, c = k & 1023;
    op[k] = f2h(buf[c * 9 + t]);
  }
}

__global__ __launch_bounds__(256) void cvt_lin(const float* __restrict__ in,
                                               u16* __restrict__ o, int n) {
  int i = (blockIdx.x * 256 + threadIdx.x) * 4;
  if (i + 3 < n) {
#pragma unroll
    for (int r = 0; r < 4; r++) o[i + r] = f2h(in[i + r]);
  }
}

// ---------- one-pass register softmax, L=15360 ----------
__global__ __launch_bounds__(256) void row_softmax60(u16* __restrict__ P) {
  u16* p = P + (long)blockIdx.x * 15360;
  const int tid = threadIdx.x;
  __shared__ float rm[4], rs[4];
  u16x4 v[15];
#pragma unroll
  for (int j = 0; j < 15; j++)
    v[j] = *(const u16x4*)(p + ((tid + (j << 8)) << 2));
  float m = -3.0e38f;
#pragma unroll
  for (int j = 0; j < 15; j++)
#pragma unroll
    for (int e = 0; e < 4; e++) m = fmaxf(m, h2f(v[j][e]));
#pragma unroll
  for (int o = 32; o > 0; o >>= 1) m = fmaxf(m, __shfl_xor(m, o, 64));
  if ((tid & 63) == 0) rm[tid >> 6] = m;
  __syncthreads();
  const float M = fmaxf(fmaxf(rm[0], rm[1]), fmaxf(rm[2], rm[3]));
  float s = 0.f;
#pragma unroll
  for (int j = 0; j < 15; j++)
#pragma unroll
    for (int e = 0; e < 4; e++) s += __expf(h2f(v[j][e]) - M);
#pragma unroll
  for (int o = 32; o > 0; o >>= 1) s += __shfl_xor(s, o, 64);
  if ((tid & 63) == 0) rs[tid >> 6] = s;
  __syncthreads();
  const float inv = 1.0f / (rs[0] + rs[1] + rs[2] + rs[3]);
#pragma unroll
  for (int j = 0; j < 15; j++) {
    u16x4 o4;
#pragma unroll
    for (int e = 0; e < 4; e++) o4[e] = f2h(__expf(h2f(v[j][e]) - M) * inv);
    *(u16x4*)(p + ((tid + (j << 8)) << 2)) = o4;
  }
}

// ---------- one-pass register softmax, L=1024 ----------
__global__ __launch_bounds__(256) void row_softmax4(u16* __restrict__ P) {
  u16* p = P + (long)blockIdx.x * 1024;
  const int tid = threadIdx.x;
  __shared__ float rm[4], rs[4];
  u16x4 v = *(const u16x4*)(p + (tid << 2));
  float m = fmaxf(fmaxf(h2f(v[0]), h2f(v[1])), fmaxf(h2f(v[2]), h2f(v[3])));
#pragma unroll
  for (int o = 32; o > 0; o >>= 1) m = fmaxf(m, __shfl_xor(m, o, 64));
  if ((tid & 63) == 0) rm[tid >> 6] = m;
  __syncthreads();
  const float M = fmaxf(fmaxf(rm[0], rm[1]), fmaxf(rm[2], rm[3]));
  float s = 0.f;
#pragma unroll
  for (int e = 0; e < 4; e++) s += __expf(h2f(v[e]) - M);
#pragma unroll
  for (int o = 32; o > 0; o >>= 1) s += __shfl_xor(s, o, 64);
  if ((tid & 63) == 0) rs[tid >> 6] = s;
  __syncthreads();
  const float inv = 1.0f / (rs[0] + rs[1] + rs[2] + rs[3]);
  u16x4 o4;
#pragma unroll
  for (int e = 0; e < 4; e++) o4[e] = f2h(__expf(h2f(v[e]) - M) * inv);
  *(u16x4*)(p + (tid << 2)) = o4;
}

// ---------- split-K partial reduce ----------
__global__ __launch_bounds__(256) void reduce4(const float* __restrict__ part,
                                               u16* __restrict__ o) {
  long j = ((long)blockIdx.x * 256 + threadIdx.x) * 4;
  int b = (int)(j >> 19);
  long i = j & 524287;
  const float* p = part + (long)b * 2097152 + i;
  f32x4 s = *(const f32x4*)&p[0];
#pragma unroll
  for (int c = 1; c < 4; c++) {
    f32x4 t = *(const f32x4*)&p[(long)c * 524288];
    s = s + t;
  }
  u16x4 o4;
#pragma unroll
  for (int r = 0; r < 4; r++) o4[r] = f2h(s[r]);
  *(u16x4*)&o[j] = o4;
}

// ---------- sv conv: spatial-patch implicit GEMM with 9-tap LDS reuse ----
// block = 16x16 pixel patch x 256 out-channels. B halo slab (18x18x64ch)
// staged once per c-block, all 9 taps read shifted windows from it.
// grid = 240 (120 patches x 2 mtiles, interleaved for XCD L2 sharing).
__global__ __launch_bounds__(512, 1)
void conv3x3sv(const u16* __restrict__ A, const u16* __restrict__ B,
               const float* __restrict__ bias, u16* __restrict__ out) {
  __shared__ u16 lds[75776];  // A: 2x16384 u16 @0 | B: 2x21504 u16 @32768
  const int tid = threadIdx.x, lane = tid & 63, wave = tid >> 6;
  int wg = blockIdx.x;
  wg = (wg & 7) * 30 + (wg >> 3);          // bijective XCD swizzle (240%8==0)
  const int patch = wg >> 1, mtile = wg & 1;
  const int img = patch >> 2, pq = patch & 3;
  const int y0 = (pq >> 1) * 16, x0 = (pq & 1) * 16;

  const int l3 = lane >> 3;
  const int slog = (lane & 7) ^ l3;

  // ---- A staging setup: 4 gll16/wave/tap, rows wave*32+j*8 ----
  const u16* aS[4];
  int aDst[4];
#pragma unroll
  for (int j = 0; j < 4; j++) {
    const int row = wave * 32 + j * 8 + l3;
    aS[j] = A + (long)(mtile * 256 + row) * 9216 + slog * 8;
    aDst[j] = (wave * 32 + j * 8) * 64;
  }
  // ---- B staging setup: inst I = k*8+wave (I<42), 8 px-rows each ----
  const u16* bS[6];
  int bDst[6];
  bool bV[6];
#pragma unroll
  for (int k = 0; k < 6; k++) {
    const int I = k * 8 + wave;
    bV[k] = (I < 42);
    const int Ic = (I < 42) ? I : 41;
    int r = Ic * 8 + l3;
    if (r > 323) r = 323;                  // clamp pad rows (never read)
    const int sy = r / 18, sx = r - sy * 18;
    bS[k] = B + ((long)(img * 34 + y0 + sy) * 34 + (x0 + sx)) * 1024 +
            ((lane & 7) ^ (r & 7)) * 8;
    bDst[k] = 32768 + Ic * 512;
  }

  // ---- fragment geometry ----
  const int g = lane >> 4, l15 = lane & 15;
  const int wm = wave >> 2, wn = wave & 3;
  int aRow[8];
#pragma unroll
  for (int mi = 0; mi < 8; mi++) aRow[mi] = (wm * 128 + mi * 16 + l15) * 64;
  int sxA[2];
#pragma unroll
  for (int ks = 0; ks < 2; ks++) sxA[ks] = ((ks * 4 + g) ^ (l15 & 7)) * 8;
  int rowB[4];
#pragma unroll
  for (int ni = 0; ni < 4; ni++) rowB[ni] = (wn * 4 + ni) * 18 + l15;

  f32x4 acc[8][4];
  const f32x4 zero = {0.f, 0.f, 0.f, 0.f};
#pragma unroll
  for (int i = 0; i < 8; i++)
#pragma unroll
    for (int j = 0; j < 4; j++) acc[i][j] = zero;

  // ---- prologue: stage A(s=0) into slab0, B(c=0) into slab0 ----
#pragma unroll
  for (int j = 0; j < 4; j++) gll16(aS[j], &lds[aDst[j]]);
#pragma unroll
  for (int k = 0; k < 6; k++)
    if (bV[k]) gll16(bS[k], &lds[bDst[k]]);
  asm volatile("s_waitcnt vmcnt(0)" ::: "memory");
  __builtin_amdgcn_s_barrier();
  __builtin_amdgcn_sched_barrier(0);

  for (int c = 0; c < 16; ++c) {
    const int bslab = 32768 + (c & 1) * 21504;
    const int bpN = ((c + 1) & 1) * 21504;
    const bool stB = (c + 1 < 16);
#pragma unroll
    for (int tap = 0; tap < 9; ++tap) {
      const int rowAdd = (tap / 3) * 18 + (tap % 3);
      const int aslab = ((c + tap) & 1) * 16384;
      const int aslabN = aslab ^ 16384;
      const bool stA = (c * 9 + tap + 1 < 144);
      const int koffN = (tap < 8) ? ((tap + 1) * 1024 + c * 64) : ((c + 1) * 64);
      f16x8 afr[4], bfr[4];
      // ---- phase 0: ks0, mi 0..3 ----
#pragma unroll
      for (int mi = 0; mi < 4; mi++)
        afr[mi] = *(const f16x8*)&lds[aslab + aRow[mi] + sxA[0]];
#pragma unroll
      for (int ni = 0; ni < 4; ni++) {
        const int row = rowB[ni] + rowAdd;
        bfr[ni] = *(const f16x8*)&lds[bslab + row * 64 + ((g ^ (row & 7)) * 8)];
      }
      if (stA) {
        gll16(aS[0] + koffN, &lds[aslabN + aDst[0]]);
        gll16(aS[1] + koffN, &lds[aslabN + aDst[1]]);
      }
      __builtin_amdgcn_s_barrier();
      __builtin_amdgcn_s_setprio(1);
#pragma unroll
      for (int mi = 0; mi < 4; mi++)
#pragma unroll
        for (int ni = 0; ni < 4; ni++)
          acc[mi][ni] = __builtin_amdgcn_mfma_f32_16x16x32_f16(
              afr[mi], bfr[ni], acc[mi][ni], 0, 0, 0);
      __builtin_amdgcn_s_setprio(0);
      __builtin_amdgcn_s_barrier();
      // ---- phase 1: ks0, mi 4..7 (reuse bfr) ----
#pragma unroll
      for (int mi = 0; mi < 4; mi++)
        afr[mi] = *(const f16x8*)&lds[aslab + aRow[mi + 4] + sxA[0]];
      if (stA) {
        gll16(aS[2] + koffN, &lds[aslabN + aDst[2]]);
        gll16(aS[3] + koffN, &lds[aslabN + aDst[3]]);
      }
      __builtin_amdgcn_s_barrier();
      __builtin_amdgcn_s_setprio(1);
#pragma unroll
      for (int mi = 0; mi < 4; mi++)
#pragma unroll
        for (int ni = 0; ni < 4; ni++)
          acc[mi + 4][ni] = __builtin_amdgcn_mfma_f32_16x16x32_f16(
              afr[mi], bfr[ni], acc[mi + 4][ni], 0, 0, 0);
      __builtin_amdgcn_s_setprio(0);
      __builtin_amdgcn_s_barrier();
      // ---- phase 2: ks1, mi 0..3 (B staging for c+1, taps 0..5) ----
#pragma unroll
      for (int mi = 0; mi < 4; mi++)
        afr[mi] = *(const f16x8*)&lds[aslab + aRow[mi] + sxA[1]];
#pragma unroll
      for (int ni = 0; ni < 4; ni++) {
        const int row = rowB[ni] + rowAdd;
        bfr[ni] = *(const f16x8*)&lds[bslab + row * 64 + (((4 + g) ^ (row & 7)) * 8)];
      }
      bool hasB = false;
      if (tap < 6) {
        hasB = stB && bV[tap];
        if (hasB) gll16(bS[tap] + (c + 1) * 64, &lds[bDst[tap] + bpN]);
      }
      __builtin_amdgcn_s_barrier();
      __builtin_amdgcn_s_setprio(1);
#pragma unroll
      for (int mi = 0; mi < 4; mi++)
#pragma unroll
        for (int ni = 0; ni < 4; ni++)
          acc[mi][ni] = __builtin_amdgcn_mfma_f32_16x16x32_f16(
              afr[mi], bfr[ni], acc[mi][ni], 0, 0, 0);
      __builtin_amdgcn_s_setprio(0);
      __builtin_amdgcn_s_barrier();
      // ---- phase 3: ks1, mi 4..7; counted gate at tap end ----
#pragma unroll
      for (int mi = 0; mi < 4; mi++)
        afr[mi] = *(const f16x8*)&lds[aslab + aRow[mi + 4] + sxA[1]];
      __builtin_amdgcn_s_barrier();
      __builtin_amdgcn_s_setprio(1);
#pragma unroll
      for (int mi = 0; mi < 4; mi++)
#pragma unroll
        for (int ni = 0; ni < 4; ni++)
          acc[mi + 4][ni] = __builtin_amdgcn_mfma_f32_16x16x32_f16(
              afr[mi], bfr[ni], acc[mi + 4][ni], 0, 0, 0);
      __builtin_amdgcn_s_setprio(0);
      if (hasB) {
        asm volatile("s_waitcnt vmcnt(1)" ::: "memory");  // A(next) done, B may fly
      } else {
        asm volatile("s_waitcnt vmcnt(0)" ::: "memory");
      }
      __builtin_amdgcn_s_barrier();
      __builtin_amdgcn_sched_barrier(0);
    }
  }

  // ---- epilogue: SVA[b][m][col] ----
  const int bz = (img >= 15) ? 1 : 0;
  const int simg = img - bz * 15;
#pragma unroll
  for (int mi = 0; mi < 8; mi++) {
#pragma unroll
    for (int ni = 0; ni < 4; ni++) {
      f32x4 v = acc[mi][ni];
      const int m0 = mtile * 256 + wm * 128 + mi * 16 + g * 4;
      const int col = simg * 1024 + (y0 + wn * 4 + ni) * 32 + x0 + l15;
#pragma unroll
      for (int r = 0; r < 4; r++) {
        const int m = m0 + r;
        out[(long)bz * 7864320 + (long)m * 15360 + col] = f2h(v[r] + bias[m]);
      }
    }
  }
}

// ---------- 128x128 NT GEMM (2-phase, general purpose) ----------
template <int BMODE, int EPI, int SPLITK>
__global__ __launch_bounds__(256, 2)
void gemm_nt(const u16* __restrict__ A, long Azoff, int Astride,
             const u16* __restrict__ B, long Bzoff, int Bstride,
             int K, float scale,
             const float* __restrict__ bias, const float* __restrict__ bias2,
             void* __restrict__ out0, void* __restrict__ out1,
             long out_zoff, int ldo) {
  __shared__ u16 lds[4 * 8192];
  const int tid = threadIdx.x;
  const int lane = tid & 63;
  const int wave = tid >> 6;
  const int mtile = blockIdx.y, ntile = blockIdx.x, z = blockIdx.z;

  const int zb = (SPLITK > 1) ? z / SPLITK : z;
  const int zc = (SPLITK > 1) ? z % SPLITK : 0;
  const u16* Ab = A + (long)zb * Azoff + (long)zc * K;
  const u16* Bb = B + (long)zb * Bzoff + (long)zc * K;

  const int r8 = lane >> 3;
  const int sphys = lane & 7;
  const u16* aSrc[4];
  const u16* bSrc[4];
  u16* aDst[4];
  u16* bDst[4];
#pragma unroll
  for (int i = 0; i < 4; i++) {
    const int row = wave * 32 + i * 8 + r8;
    const int slog = sphys ^ (row & 7);
    aSrc[i] = Ab + (long)(mtile * 128 + row) * Astride + slog * 8;
    if (BMODE == 0) {
      bSrc[i] = Bb + (long)(ntile * 128 + row) * Bstride + slog * 8;
    } else {
      const int n = ntile * 128 + row;
      const int img = n >> 10;
      const int p = n & 1023;
      const int y = p >> 5, x = p & 31;
      bSrc[i] = Bb + ((long)(img * 34 + y) * 34 + x) * 1024 + slog * 8;
    }
    aDst[i] = &lds[0] + (wave * 32 + i * 8) * 64;
    bDst[i] = &lds[0] + 8192 + (wave * 32 + i * 8) * 64;
  }

  const int g = lane >> 4, l15 = lane & 15;
  const int wm = wave >> 1, wn = wave & 1;
  int offA[2][4], offB[2][4];
#pragma unroll
  for (int ks = 0; ks < 2; ks++) {
    const int sl = ks * 4 + g;
#pragma unroll
    for (int i = 0; i < 4; i++) {
      const int ra = wm * 64 + i * 16 + l15;
      offA[ks][i] = ra * 64 + ((sl ^ (ra & 7)) * 8);
      const int rb = wn * 64 + i * 16 + l15;
      offB[ks][i] = 8192 + rb * 64 + ((sl ^ (rb & 7)) * 8);
    }
  }

  auto stage = [&](int buf, int kb) {
    int bAdd;
    if (BMODE == 0) {
      bAdd = kb;
    } else if (BMODE == 1) {
      const int t = kb >> 10, c0 = kb & 1023;
      const int dy = t / 3, dx = t - dy * 3;
      bAdd = (dy * 34 + dx) * 1024 + c0;
    } else {
      bAdd = 35 * 1024 + kb;
    }
    const int bufo = buf * 16384;
#pragma unroll
    for (int i = 0; i < 4; i++) gll16(aSrc[i] + kb, aDst[i] + bufo);
#pragma unroll
    for (int i = 0; i < 4; i++) gll16(bSrc[i] + bAdd, bDst[i] + bufo);
  };

  f32x4 acc[4][4];
  const f32x4 zero = {0.f, 0.f, 0.f, 0.f};
#pragma unroll
  for (int i = 0; i < 4; i++)
#pragma unroll
    for (int j = 0; j < 4; j++) acc[i][j] = zero;

  const int nkt = K >> 6;
  stage(0, 0);
  __syncthreads();
  for (int kt = 0; kt < nkt; ++kt) {
    const int buf = kt & 1;
    if (kt + 1 < nkt) stage(buf ^ 1, (kt + 1) << 6);
#pragma unroll
    for (int ks = 0; ks < 2; ks++) {
      f16x8 af[4], bfg[4];
#pragma unroll
      for (int i = 0; i < 4; i++)
        af[i] = *(const f16x8*)&lds[buf * 16384 + offA[ks][i]];
#pragma unroll
      for (int i = 0; i < 4; i++)
        bfg[i] = *(const f16x8*)&lds[buf * 16384 + offB[ks][i]];
#pragma unroll
      for (int mi = 0; mi < 4; mi++)
#pragma unroll
        for (int ni = 0; ni < 4; ni++)
          acc[mi][ni] = __builtin_amdgcn_mfma_f32_16x16x32_f16(
              af[mi], bfg[ni], acc[mi][ni], 0, 0, 0);
    }
    __syncthreads();
  }

#pragma unroll
  for (int mi = 0; mi < 4; mi++) {
#pragma unroll
    for (int ni = 0; ni < 4; ni++) {
      f32x4 v = acc[mi][ni];
      const int m0 = mtile * 128 + wm * 64 + mi * 16 + g * 4;
      const int n = ntile * 128 + wn * 64 + ni * 16 + l15;
      if (EPI == 0) {
        u16* ob = (u16*)out0;
        const float* bs = bias;
        int mm = m0;
        if (out1 != nullptr && m0 >= 128) { ob = (u16*)out1; bs = bias2; mm = m0 - 128; }
        u16x4 pk;
#pragma unroll
        for (int r = 0; r < 4; r++) {
          float val = v[r] * scale + (bs ? bs[mm + r] : 0.f);
          pk[r] = f2h(val);
        }
        *(u16x4*)&ob[(long)n * ldo + mm] = pk;
      } else if (EPI == 1) {
        u16* ob = (u16*)out0 + (long)z * out_zoff;
#pragma unroll
        for (int r = 0; r < 4; r++) {
          const int m = m0 + r;
          float val = v[r] * scale + (bias ? bias[m] : 0.f);
          ob[(long)m * ldo + n] = f2h(val);
        }
      } else if (EPI == 2) {
        float* of = (float*)out0;
        const int img = n >> 10, p = n & 1023;
#pragma unroll
        for (int r = 0; r < 4; r++) {
          const int m = m0 + r;
          of[(long)img * 1048576 + (long)(512 + m) * 1024 + p] =
              v[r] + (bias ? bias[m] : 0.f);
        }
      } else if (EPI == 3) {
        float* of = (float*)out0;
        const int f = n >> 10, p = n & 1023;
#pragma unroll
        for (int r = 0; r < 4; r++) {
          const int m = m0 + r;
          of[(long)z * 5242880 + (long)f * 1048576 + (long)m * 1024 + p] = v[r];
        }
      } else {  // EPI == 4: fp32 partial row store (split-K)
        float* of = (float*)out0 + (long)z * out_zoff;
#pragma unroll
        for (int r = 0; r < 4; r++) {
          of[(long)(m0 + r) * ldo + n] = v[r];
        }
      }
    }
  }
}

// ---------- launch ----------
extern "C" void kernel_launch(void* const* d_in, const int* in_sizes, int n_in,
                              void* d_out, int out_size, void* d_ws, size_t ws_size,
                              hipStream_t stream) {
  (void)in_sizes; (void)n_in; (void)out_size;
  const float* query   = (const float*)d_in[0];
  const float* support = (const float*)d_in[1];
  const float* w_sk = (const float*)d_in[2];  const float* b_sk = (const float*)d_in[3];
  const float* w_sv = (const float*)d_in[4];  const float* b_sv = (const float*)d_in[5];
  const float* w_qq = (const float*)d_in[6];  const float* b_qq = (const float*)d_in[7];
  const float* w_qk = (const float*)d_in[8];  const float* b_qk = (const float*)d_in[9];
  const float* w_cq = (const float*)d_in[10]; const float* b_cq = (const float*)d_in[11];
  float* out = (float*)d_out;
  char* ws = (char*)d_ws;

  if (ws_size < 158924800u) return;

  u16* PQ    = (u16*)(ws + 0);           // padded query NHWC f16: 10*34*34*1024
  u16* PS    = (u16*)(ws + 23674880);    // padded support: 30*34*34*1024
  u16* WTSK  = (u16*)(ws + 94699520);    // [128][9216]
  u16* WTSV  = (u16*)(ws + 97058816);    // [512][9216]
  u16* WTQQK = (u16*)(ws + 106496000);   // [256][9216]
  u16* WCQ   = (u16*)(ws + 111214592);   // [512][1024]
  u16* SKR   = (u16*)(ws + 112263168);   // [30720][128]
  u16* SVA   = (u16*)(ws + 120127488);   // [2][512][15360]
  u16* QQR   = (u16*)(ws + 151584768);   // [10240][128]
  u16* QKR   = (u16*)(ws + 154206208);   // [10240][128]
  u16* NEWV  = (u16*)(ws + 156827648);   // [2][512][1024]
  u16* P1T   = PS;                       // alias after sk/sv convs consume PS
  u16* P2T   = PQ;                       // alias after qqk/qf convs consume PQ
  float* PART = (float*)(ws + 94699520); // alias over weights: [8][512][1024] fp32

  const float SCALE = 0.08838834764831843f;  // 1/sqrt(128)

  halo_zero<<<dim3(10, 4), 256, 0, stream>>>(PQ);
  halo_zero<<<dim3(30, 4), 256, 0, stream>>>(PS);
  pad_nhwc<<<dim3(320), 256, 0, stream>>>(query, PQ);
  pad_nhwc<<<dim3(960), 256, 0, stream>>>(support, PS);
  wre3<<<dim3(128), 256, 0, stream>>>(w_sk, WTSK);
  wre3<<<dim3(512), 256, 0, stream>>>(w_sv, WTSV);
  wre3<<<dim3(128), 256, 0, stream>>>(w_qq, WTQQK);
  wre3<<<dim3(128), 256, 0, stream>>>(w_qk, WTQQK + (long)128 * 9216);
  cvt_lin<<<dim3(512), 256, 0, stream>>>(w_cq, WCQ, 524288);

  // convs (implicit GEMM)
  gemm_nt<1, 0, 1><<<dim3(240, 1, 1), 256, 0, stream>>>(
      WTSK, 0, 9216, PS, 0, 0, 9216, 1.0f, b_sk, nullptr, SKR, nullptr, 0, 128);
  conv3x3sv<<<dim3(240), 512, 0, stream>>>(WTSV, PS, b_sv, SVA);
  gemm_nt<1, 0, 1><<<dim3(80, 2, 1), 256, 0, stream>>>(
      WTQQK, 0, 9216, PQ, 0, 0, 9216, 1.0f, b_qq, b_qk, QQR, QKR, 0, 128);
  gemm_nt<2, 2, 1><<<dim3(80, 4, 1), 256, 0, stream>>>(
      WCQ, 0, 1024, PQ, 0, 0, 1024, 1.0f, b_cq, nullptr, out, nullptr, 0, 0);

  // stage 1
  gemm_nt<0, 1, 1><<<dim3(120, 8, 2), 256, 0, stream>>>(
      QQR + 262144, 655360L, 128, SKR, 1966080L, 128, 128, SCALE, nullptr,
      nullptr, P1T, nullptr, 15728640L, 15360);
  row_softmax60<<<dim3(2048), 256, 0, stream>>>(P1T);
  gemm_nt<0, 4, 4><<<dim3(8, 4, 8), 256, 0, stream>>>(
      SVA, 7864320L, 15360, P1T, 15728640L, 15360, 3840, 1.0f, nullptr,
      nullptr, PART, nullptr, 524288L, 1024);
  reduce4<<<dim3(1024), 256, 0, stream>>>(PART, NEWV);

  // stage 2
  gemm_nt<0, 1, 1><<<dim3(8, 40, 2), 256, 0, stream>>>(
      QQR, 655360L, 128, QKR + 262144, 655360L, 128, 128, SCALE, nullptr,
      nullptr, P2T, nullptr, 5242880L, 1024);
  row_softmax4<<<dim3(10240), 256, 0, stream>>>(P2T);
  gemm_nt<0, 3, 1><<<dim3(40, 4, 2), 256, 0, stream>>>(
      NEWV, 524288L, 1024, P2T, 5242880L, 1024, 1024, 1.0f, nullptr, nullptr,
      out, nullptr, 0, 0);
}

// Round 5
// 696.877 us; speedup vs baseline: 1.3111x; 1.3111x over previous
//
#include <hip/hip_runtime.h>
#include <cstdint>

typedef unsigned short u16;
typedef __attribute__((ext_vector_type(8))) u16 u16x8;
typedef __attribute__((ext_vector_type(4))) u16 u16x4;
typedef __attribute__((ext_vector_type(8))) _Float16 f16x8;
typedef __attribute__((ext_vector_type(4))) float f32x4;

// ---------- helpers ----------
__device__ __forceinline__ u16 f2h(float f) {
  _Float16 h = (_Float16)f;
  return __builtin_bit_cast(u16, h);
}
__device__ __forceinline__ float h2f(u16 b) {
  _Float16 h = __builtin_bit_cast(_Float16, b);
  return (float)h;
}
__device__ __forceinline__ void gll16(const void* g, void* l) {
  auto gp = reinterpret_cast<const __attribute__((address_space(1))) unsigned int*>(
      reinterpret_cast<uintptr_t>(g));
  auto lp = reinterpret_cast<__attribute__((address_space(3))) unsigned int*>(
      reinterpret_cast<uintptr_t>(l));
  __builtin_amdgcn_global_load_lds(gp, lp, 16, 0, 0);
}

// ---------- prep: NCHW fp32 -> padded(34x34) NHWC fp16, halo fused ----------
__global__ __launch_bounds__(256) void pad_nhwc(const float* __restrict__ in,
                                                u16* __restrict__ outp) {
  const int img = blockIdx.x >> 5;
  const int y   = blockIdx.x & 31;
  __shared__ float tile[32][33];
  const int tid = threadIdx.x;
  u16* base = outp + (long)img * 34 * 34 * 1024;
  const u16x8 z8 = {0, 0, 0, 0, 0, 0, 0, 0};
  // halo: this row's x=0 and x=33 columns
  {
    u16* r = base + (long)(y + 1) * 34 * 1024;
    if (tid < 128) *(u16x8*)&r[tid * 8] = z8;
    else *(u16x8*)&r[33 * 1024 + (tid - 128) * 8] = z8;
  }
  if (y == 0) {
    for (int i = tid * 8; i < 34816; i += 2048) *(u16x8*)&base[i] = z8;
  }
  if (y == 31) {
    u16* r = base + 33L * 34 * 1024;
    for (int i = tid * 8; i < 34816; i += 2048) *(u16x8*)&r[i] = z8;
  }
  const int xi = tid & 31, ci = tid >> 5;
  const int xo = tid >> 3, q = tid & 7;
  const float* ip = in + (long)img * 1048576 + y * 32;
  u16* op = base + ((long)(y + 1) * 34 + 1) * 1024;
  for (int c0 = 0; c0 < 1024; c0 += 32) {
#pragma unroll
    for (int k2 = 0; k2 < 4; k2++)
      tile[k2 * 8 + ci][xi] = ip[(long)(c0 + k2 * 8 + ci) * 1024 + xi];
    __syncthreads();
    u16x4 o4;
#pragma unroll
    for (int r = 0; r < 4; r++) o4[r] = f2h(tile[q * 4 + r][xo]);
    *(u16x4*)&op[(long)xo * 1024 + c0 + q * 4] = o4;
    __syncthreads();
  }
}

// ---------- merged weight prep: 4x wre3 + cvt_lin in one dispatch ----------
__device__ __forceinline__ void wre3_body(const float* __restrict__ wp,
                                          u16* __restrict__ op, float* buf) {
  for (int i = threadIdx.x; i < 9216; i += 256) buf[i] = wp[i];
  __syncthreads();
  for (int k = threadIdx.x; k < 9216; k += 256) {
    int t = k >> 10, c = k & 1023;
    op[k] = f2h(buf[c * 9 + t]);
  }
}
__global__ __launch_bounds__(256) void wprep(
    const float* __restrict__ w_sk, const float* __restrict__ w_sv,
    const float* __restrict__ w_qq, const float* __restrict__ w_qk,
    const float* __restrict__ w_cq, u16* __restrict__ WTSK,
    u16* __restrict__ WTSV, u16* __restrict__ WTQQK, u16* __restrict__ WCQ) {
  __shared__ float buf[9216];
  const int b = blockIdx.x;
  if (b < 128) {
    wre3_body(w_sk + (long)b * 9216, WTSK + (long)b * 9216, buf);
  } else if (b < 640) {
    const int oc = b - 128;
    wre3_body(w_sv + (long)oc * 9216, WTSV + (long)oc * 9216, buf);
  } else if (b < 768) {
    const int oc = b - 640;
    wre3_body(w_qq + (long)oc * 9216, WTQQK + (long)oc * 9216, buf);
  } else if (b < 896) {
    const int oc = b - 768;
    wre3_body(w_qk + (long)oc * 9216, WTQQK + (long)(oc + 128) * 9216, buf);
  } else {
    const int i = (b - 896) * 1024 + threadIdx.x * 4;
#pragma unroll
    for (int r = 0; r < 4; r++) WCQ[i + r] = f2h(w_cq[i + r]);
  }
}

// ---------- one-pass register softmax, L=15360 ----------
__global__ __launch_bounds__(256) void row_softmax60(u16* __restrict__ P) {
  u16* p = P + (long)blockIdx.x * 15360;
  const int tid = threadIdx.x;
  __shared__ float rm[4], rs[4];
  u16x4 v[15];
#pragma unroll
  for (int j = 0; j < 15; j++)
    v[j] = *(const u16x4*)(p + ((tid + (j << 8)) << 2));
  float m = -3.0e38f;
#pragma unroll
  for (int j = 0; j < 15; j++)
#pragma unroll
    for (int e = 0; e < 4; e++) m = fmaxf(m, h2f(v[j][e]));
#pragma unroll
  for (int o = 32; o > 0; o >>= 1) m = fmaxf(m, __shfl_xor(m, o, 64));
  if ((tid & 63) == 0) rm[tid >> 6] = m;
  __syncthreads();
  const float M = fmaxf(fmaxf(rm[0], rm[1]), fmaxf(rm[2], rm[3]));
  float s = 0.f;
#pragma unroll
  for (int j = 0; j < 15; j++)
#pragma unroll
    for (int e = 0; e < 4; e++) s += __expf(h2f(v[j][e]) - M);
#pragma unroll
  for (int o = 32; o > 0; o >>= 1) s += __shfl_xor(s, o, 64);
  if ((tid & 63) == 0) rs[tid >> 6] = s;
  __syncthreads();
  const float inv = 1.0f / (rs[0] + rs[1] + rs[2] + rs[3]);
#pragma unroll
  for (int j = 0; j < 15; j++) {
    u16x4 o4;
#pragma unroll
    for (int e = 0; e < 4; e++) o4[e] = f2h(__expf(h2f(v[j][e]) - M) * inv);
    *(u16x4*)(p + ((tid + (j << 8)) << 2)) = o4;
  }
}

// ---------- one-pass register softmax, L=1024 ----------
__global__ __launch_bounds__(256) void row_softmax4(u16* __restrict__ P) {
  u16* p = P + (long)blockIdx.x * 1024;
  const int tid = threadIdx.x;
  __shared__ float rm[4], rs[4];
  u16x4 v = *(const u16x4*)(p + (tid << 2));
  float m = fmaxf(fmaxf(h2f(v[0]), h2f(v[1])), fmaxf(h2f(v[2]), h2f(v[3])));
#pragma unroll
  for (int o = 32; o > 0; o >>= 1) m = fmaxf(m, __shfl_xor(m, o, 64));
  if ((tid & 63) == 0) rm[tid >> 6] = m;
  __syncthreads();
  const float M = fmaxf(fmaxf(rm[0], rm[1]), fmaxf(rm[2], rm[3]));
  float s = 0.f;
#pragma unroll
  for (int e = 0; e < 4; e++) s += __expf(h2f(v[e]) - M);
#pragma unroll
  for (int o = 32; o > 0; o >>= 1) s += __shfl_xor(s, o, 64);
  if ((tid & 63) == 0) rs[tid >> 6] = s;
  __syncthreads();
  const float inv = 1.0f / (rs[0] + rs[1] + rs[2] + rs[3]);
  u16x4 o4;
#pragma unroll
  for (int e = 0; e < 4; e++) o4[e] = f2h(__expf(h2f(v[e]) - M) * inv);
  *(u16x4*)(p + (tid << 2)) = o4;
}

// ---------- split-K reducers ----------
__global__ __launch_bounds__(256) void reduce4(const float* __restrict__ part,
                                               u16* __restrict__ o) {
  long j = ((long)blockIdx.x * 256 + threadIdx.x) * 4;
  int b = (int)(j >> 19);
  long i = j & 524287;
  const float* p = part + (long)b * 2097152 + i;
  f32x4 s = *(const f32x4*)&p[0];
#pragma unroll
  for (int c = 1; c < 4; c++) s = s + *(const f32x4*)&p[(long)c * 524288];
  u16x4 o4;
#pragma unroll
  for (int r = 0; r < 4; r++) o4[r] = f2h(s[r]);
  *(u16x4*)&o[j] = o4;
}
// SKR[n][128] = sum_z PARTK[z][n][128] + bias[m]
__global__ __launch_bounds__(256) void reduce_sk(const float* __restrict__ part,
                                                 const float* __restrict__ bias,
                                                 u16* __restrict__ o) {
  long i = ((long)blockIdx.x * 256 + threadIdx.x) * 4;
  f32x4 s = *(const f32x4*)&part[i];
  s = s + *(const f32x4*)&part[i + 3932160];
  f32x4 bb = *(const f32x4*)&bias[(int)(i & 127)];
  u16x4 o4;
#pragma unroll
  for (int r = 0; r < 4; r++) o4[r] = f2h(s[r] + bb[r]);
  *(u16x4*)&o[i] = o4;
}
// QQR/QKR[n][128] = sum_z PARTQ[z][n][256](half) + bias
__global__ __launch_bounds__(256) void reduce_qqk(
    const float* __restrict__ part, const float* __restrict__ b_qq,
    const float* __restrict__ b_qk, u16* __restrict__ QQR,
    u16* __restrict__ QKR) {
  long i = ((long)blockIdx.x * 256 + threadIdx.x) * 4;
  const int n = (int)(i >> 8), m = (int)(i & 255);
  f32x4 s = *(const f32x4*)&part[i];
  s = s + *(const f32x4*)&part[i + 2621440];
  const int lo = (m < 128);
  const int mm = m & 127;
  const float* bs = lo ? b_qq : b_qk;
  f32x4 bb = *(const f32x4*)&bs[mm];
  u16* dst = (lo ? QQR : QKR) + (long)n * 128 + mm;
  u16x4 o4;
#pragma unroll
  for (int r = 0; r < 4; r++) o4[r] = f2h(s[r] + bb[r]);
  *(u16x4*)dst = o4;
}

// ---------- 256x256 4-phase GEMM for the sv conv (r3-proven, 1062 TF) ------
__global__ __launch_bounds__(512, 1)
void gemm256(const u16* __restrict__ A, const u16* __restrict__ B,
             const float* __restrict__ bias, u16* __restrict__ out) {
  __shared__ u16 lds[65536];
  const int tid = threadIdx.x, lane = tid & 63, wave = tid >> 6;
  const int nwg = gridDim.x * gridDim.y;
  int wg = blockIdx.x + gridDim.x * blockIdx.y;
  wg = (wg & 7) * (nwg >> 3) + (wg >> 3);
  const int ntile = wg % gridDim.x;
  const int mtile = wg / gridDim.x;

  const int slog = (lane & 7) ^ ((lane >> 3) & 7);
  const u16* aS[4];
  const u16* bS[4];
  int aD[4], bD[4];
#pragma unroll
  for (int j = 0; j < 4; j++) {
    const int r = wave * 32 + j * 8 + (lane >> 3);
    aS[j] = A + (long)(mtile * 256 + r) * 9216 + slog * 8;
    aD[j] = (wave * 32 + j * 8) * 64;
    const int n = ntile * 256 + r;
    const int img = n >> 10, p = n & 1023;
    const int y = p >> 5, x = p & 31;
    bS[j] = B + ((long)((img * 34 + y) * 34 + x)) * 1024 + slog * 8;
    bD[j] = 16384 + (wave * 32 + j * 8) * 64;
  }

  const int g = lane >> 4, l15 = lane & 15;
  const int wm = wave >> 2, wn = wave & 3;
  int aRow[8], bRow[4], sx[2];
#pragma unroll
  for (int mi = 0; mi < 8; mi++) aRow[mi] = (wm * 128 + mi * 16 + l15) * 64;
#pragma unroll
  for (int ni = 0; ni < 4; ni++) bRow[ni] = 16384 + (wn * 64 + ni * 16 + l15) * 64;
#pragma unroll
  for (int ks = 0; ks < 2; ks++) sx[ks] = ((ks * 4 + g) ^ (l15 & 7)) * 8;

  f32x4 acc[8][4];
  const f32x4 zero = {0.f, 0.f, 0.f, 0.f};
#pragma unroll
  for (int i = 0; i < 8; i++)
#pragma unroll
    for (int j = 0; j < 4; j++) acc[i][j] = zero;

  const int nkt = 144;
  {
#pragma unroll
    for (int j = 0; j < 4; j++) gll16(aS[j], &lds[aD[j]]);
#pragma unroll
    for (int j = 0; j < 4; j++) gll16(bS[j], &lds[bD[j]]);
    asm volatile("s_waitcnt vmcnt(0)" ::: "memory");
    __builtin_amdgcn_s_barrier();
  }

  for (int kt = 0; kt < nkt; ++kt) {
    const int buf = (kt & 1) << 15;
    const int nbuf = buf ^ 32768;
    const bool st = (kt + 1 < nkt);
    const int kb1 = (kt + 1) << 6;
    int bAdd = 0;
    if (st) {
      const int t = kb1 >> 10, c0 = kb1 & 1023;
      const int dy = t / 3, dx = t - dy * 3;
      bAdd = (dy * 34 + dx) * 1024 + c0;
    }
    f16x8 afr[4], bfr[4];
#pragma unroll
    for (int mi = 0; mi < 4; mi++) afr[mi] = *(const f16x8*)&lds[buf + aRow[mi] + sx[0]];
#pragma unroll
    for (int ni = 0; ni < 4; ni++) bfr[ni] = *(const f16x8*)&lds[buf + bRow[ni] + sx[0]];
    if (st) {
      gll16(aS[0] + kb1, &lds[nbuf + aD[0]]);
      gll16(aS[1] + kb1, &lds[nbuf + aD[1]]);
      gll16(bS[0] + bAdd, &lds[nbuf + bD[0]]);
      gll16(bS[1] + bAdd, &lds[nbuf + bD[1]]);
    }
    __builtin_amdgcn_s_barrier();
    __builtin_amdgcn_s_setprio(1);
#pragma unroll
    for (int mi = 0; mi < 4; mi++)
#pragma unroll
      for (int ni = 0; ni < 4; ni++)
        acc[mi][ni] = __builtin_amdgcn_mfma_f32_16x16x32_f16(afr[mi], bfr[ni], acc[mi][ni], 0, 0, 0);
    __builtin_amdgcn_s_setprio(0);
    __builtin_amdgcn_s_barrier();
#pragma unroll
    for (int mi = 0; mi < 4; mi++) afr[mi] = *(const f16x8*)&lds[buf + aRow[mi + 4] + sx[0]];
    if (st) {
      gll16(aS[2] + kb1, &lds[nbuf + aD[2]]);
      gll16(aS[3] + kb1, &lds[nbuf + aD[3]]);
      gll16(bS[2] + bAdd, &lds[nbuf + bD[2]]);
      gll16(bS[3] + bAdd, &lds[nbuf + bD[3]]);
    }
    __builtin_amdgcn_s_barrier();
    __builtin_amdgcn_s_setprio(1);
#pragma unroll
    for (int mi = 0; mi < 4; mi++)
#pragma unroll
      for (int ni = 0; ni < 4; ni++)
        acc[mi + 4][ni] = __builtin_amdgcn_mfma_f32_16x16x32_f16(afr[mi], bfr[ni], acc[mi + 4][ni], 0, 0, 0);
    __builtin_amdgcn_s_setprio(0);
    __builtin_amdgcn_s_barrier();
#pragma unroll
    for (int mi = 0; mi < 4; mi++) afr[mi] = *(const f16x8*)&lds[buf + aRow[mi] + sx[1]];
#pragma unroll
    for (int ni = 0; ni < 4; ni++) bfr[ni] = *(const f16x8*)&lds[buf + bRow[ni] + sx[1]];
    __builtin_amdgcn_s_barrier();
    __builtin_amdgcn_s_setprio(1);
#pragma unroll
    for (int mi = 0; mi < 4; mi++)
#pragma unroll
      for (int ni = 0; ni < 4; ni++)
        acc[mi][ni] = __builtin_amdgcn_mfma_f32_16x16x32_f16(afr[mi], bfr[ni], acc[mi][ni], 0, 0, 0);
    __builtin_amdgcn_s_setprio(0);
    __builtin_amdgcn_s_barrier();
#pragma unroll
    for (int mi = 0; mi < 4; mi++) afr[mi] = *(const f16x8*)&lds[buf + aRow[mi + 4] + sx[1]];
    __builtin_amdgcn_s_barrier();
    __builtin_amdgcn_s_setprio(1);
#pragma unroll
    for (int mi = 0; mi < 4; mi++)
#pragma unroll
      for (int ni = 0; ni < 4; ni++)
        acc[mi + 4][ni] = __builtin_amdgcn_mfma_f32_16x16x32_f16(afr[mi], bfr[ni], acc[mi + 4][ni], 0, 0, 0);
    __builtin_amdgcn_s_setprio(0);
    asm volatile("s_waitcnt vmcnt(0)" ::: "memory");
    __builtin_amdgcn_s_barrier();
  }

  const int b0 = 0;
  (void)b0;
#pragma unroll
  for (int mi = 0; mi < 8; mi++) {
#pragma unroll
    for (int ni = 0; ni < 4; ni++) {
      f32x4 v = acc[mi][ni];
      const int m0 = mtile * 256 + wm * 128 + mi * 16 + g * 4;
      const int n = ntile * 256 + wn * 64 + ni * 16 + l15;
      const int b = (n >= 15360) ? 1 : 0;
      const int rem = n - b * 15360;
#pragma unroll
      for (int r = 0; r < 4; r++) {
        const int m = m0 + r;
        out[(long)b * 7864320 + (long)m * 15360 + rem] = f2h(v[r] + bias[m]);
      }
    }
  }
}

// ---------- 128x128 NT GEMM (2-phase, general purpose) ----------
// BMODE: 0 plain rows [n][K]; 1 = 3x3 conv patches (padded NHWC); 2 = 1x1 center
// EPI: 0 f16 transposed store (dual out); 1 f16 row store *scale(+bias);
//      2 qf fp32; 3 final fp32; 4 fp32 partial row store; 5 fp32 transposed partial
template <int BMODE, int EPI, int SPLITK>
__global__ __launch_bounds__(256, 2)
void gemm_nt(const u16* __restrict__ A, long Azoff, int Astride,
             const u16* __restrict__ B, long Bzoff, int Bstride,
             int K, float scale,
             const float* __restrict__ bias, const float* __restrict__ bias2,
             void* __restrict__ out0, void* __restrict__ out1,
             long out_zoff, int ldo) {
  __shared__ u16 lds[4 * 8192];
  const int tid = threadIdx.x;
  const int lane = tid & 63;
  const int wave = tid >> 6;
  const int mtile = blockIdx.y, ntile = blockIdx.x, z = blockIdx.z;

  const int zb = (SPLITK > 1) ? z / SPLITK : z;
  const int zc = (SPLITK > 1) ? z % SPLITK : 0;
  const u16* Ab = A + (long)zb * Azoff + (long)zc * K;
  const u16* Bb = B + (long)zb * Bzoff + ((BMODE == 0) ? (long)zc * K : 0);

  const int r8 = lane >> 3;
  const int sphys = lane & 7;
  const u16* aSrc[4];
  const u16* bSrc[4];
  u16* aDst[4];
  u16* bDst[4];
#pragma unroll
  for (int i = 0; i < 4; i++) {
    const int row = wave * 32 + i * 8 + r8;
    const int slog = sphys ^ (row & 7);
    aSrc[i] = Ab + (long)(mtile * 128 + row) * Astride + slog * 8;
    if (BMODE == 0) {
      bSrc[i] = Bb + (long)(ntile * 128 + row) * Bstride + slog * 8;
    } else {
      const int n = ntile * 128 + row;
      const int img = n >> 10;
      const int p = n & 1023;
      const int y = p >> 5, x = p & 31;
      bSrc[i] = Bb + ((long)(img * 34 + y) * 34 + x) * 1024 + slog * 8;
    }
    aDst[i] = &lds[0] + (wave * 32 + i * 8) * 64;
    bDst[i] = &lds[0] + 8192 + (wave * 32 + i * 8) * 64;
  }

  const int g = lane >> 4, l15 = lane & 15;
  const int wm = wave >> 1, wn = wave & 1;
  int offA[2][4], offB[2][4];
#pragma unroll
  for (int ks = 0; ks < 2; ks++) {
    const int sl = ks * 4 + g;
#pragma unroll
    for (int i = 0; i < 4; i++) {
      const int ra = wm * 64 + i * 16 + l15;
      offA[ks][i] = ra * 64 + ((sl ^ (ra & 7)) * 8);
      const int rb = wn * 64 + i * 16 + l15;
      offB[ks][i] = 8192 + rb * 64 + ((sl ^ (rb & 7)) * 8);
    }
  }

  auto stage = [&](int buf, int kb) {
    int bAdd;
    if (BMODE == 0) {
      bAdd = kb;
    } else if (BMODE == 1) {
      const int kbg = zc * K + kb;  // global k for tap decomposition
      const int t = kbg >> 10, c0 = kbg & 1023;
      const int dy = t / 3, dx = t - dy * 3;
      bAdd = (dy * 34 + dx) * 1024 + c0;
    } else {
      bAdd = 35 * 1024 + kb;
    }
    const int bufo = buf * 16384;
#pragma unroll
    for (int i = 0; i < 4; i++) gll16(aSrc[i] + kb, aDst[i] + bufo);
#pragma unroll
    for (int i = 0; i < 4; i++) gll16(bSrc[i] + bAdd, bDst[i] + bufo);
  };

  f32x4 acc[4][4];
  const f32x4 zero = {0.f, 0.f, 0.f, 0.f};
#pragma unroll
  for (int i = 0; i < 4; i++)
#pragma unroll
    for (int j = 0; j < 4; j++) acc[i][j] = zero;

  const int nkt = K >> 6;
  stage(0, 0);
  __syncthreads();
  for (int kt = 0; kt < nkt; ++kt) {
    const int buf = kt & 1;
    if (kt + 1 < nkt) stage(buf ^ 1, (kt + 1) << 6);
#pragma unroll
    for (int ks = 0; ks < 2; ks++) {
      f16x8 af[4], bfg[4];
#pragma unroll
      for (int i = 0; i < 4; i++)
        af[i] = *(const f16x8*)&lds[buf * 16384 + offA[ks][i]];
#pragma unroll
      for (int i = 0; i < 4; i++)
        bfg[i] = *(const f16x8*)&lds[buf * 16384 + offB[ks][i]];
#pragma unroll
      for (int mi = 0; mi < 4; mi++)
#pragma unroll
        for (int ni = 0; ni < 4; ni++)
          acc[mi][ni] = __builtin_amdgcn_mfma_f32_16x16x32_f16(
              af[mi], bfg[ni], acc[mi][ni], 0, 0, 0);
    }
    __syncthreads();
  }

#pragma unroll
  for (int mi = 0; mi < 4; mi++) {
#pragma unroll
    for (int ni = 0; ni < 4; ni++) {
      f32x4 v = acc[mi][ni];
      const int m0 = mtile * 128 + wm * 64 + mi * 16 + g * 4;
      const int n = ntile * 128 + wn * 64 + ni * 16 + l15;
      if (EPI == 0) {
        u16* ob = (u16*)out0;
        const float* bs = bias;
        int mm = m0;
        if (out1 != nullptr && m0 >= 128) { ob = (u16*)out1; bs = bias2; mm = m0 - 128; }
        u16x4 pk;
#pragma unroll
        for (int r = 0; r < 4; r++) {
          float val = v[r] * scale + (bs ? bs[mm + r] : 0.f);
          pk[r] = f2h(val);
        }
        *(u16x4*)&ob[(long)n * ldo + mm] = pk;
      } else if (EPI == 1) {
        u16* ob = (u16*)out0 + (long)z * out_zoff;
#pragma unroll
        for (int r = 0; r < 4; r++) {
          const int m = m0 + r;
          float val = v[r] * scale + (bias ? bias[m] : 0.f);
          ob[(long)m * ldo + n] = f2h(val);
        }
      } else if (EPI == 2) {
        float* of = (float*)out0;
        const int img = n >> 10, p = n & 1023;
#pragma unroll
        for (int r = 0; r < 4; r++) {
          const int m = m0 + r;
          of[(long)img * 1048576 + (long)(512 + m) * 1024 + p] =
              v[r] + (bias ? bias[m] : 0.f);
        }
      } else if (EPI == 3) {
        float* of = (float*)out0;
        const int f = n >> 10, p = n & 1023;
#pragma unroll
        for (int r = 0; r < 4; r++) {
          const int m = m0 + r;
          of[(long)z * 5242880 + (long)f * 1048576 + (long)m * 1024 + p] = v[r];
        }
      } else if (EPI == 4) {
        float* of = (float*)out0 + (long)z * out_zoff;
#pragma unroll
        for (int r = 0; r < 4; r++) of[(long)(m0 + r) * ldo + n] = v[r];
      } else {  // EPI == 5: fp32 transposed partial store [zc][n][ldo]+m
        float* of = (float*)out0 + (long)zc * out_zoff;
        *(f32x4*)&of[(long)n * ldo + m0] = v;
      }
    }
  }
}

// ---------- launch ----------
extern "C" void kernel_launch(void* const* d_in, const int* in_sizes, int n_in,
                              void* d_out, int out_size, void* d_ws, size_t ws_size,
                              hipStream_t stream) {
  (void)in_sizes; (void)n_in; (void)out_size;
  const float* query   = (const float*)d_in[0];
  const float* support = (const float*)d_in[1];
  const float* w_sk = (const float*)d_in[2];  const float* b_sk = (const float*)d_in[3];
  const float* w_sv = (const float*)d_in[4];  const float* b_sv = (const float*)d_in[5];
  const float* w_qq = (const float*)d_in[6];  const float* b_qq = (const float*)d_in[7];
  const float* w_qk = (const float*)d_in[8];  const float* b_qk = (const float*)d_in[9];
  const float* w_cq = (const float*)d_in[10]; const float* b_cq = (const float*)d_in[11];
  float* out = (float*)d_out;
  char* ws = (char*)d_ws;

  if (ws_size < 158924800u) return;

  u16* PQ    = (u16*)(ws + 0);           // padded query NHWC f16: 10*34*34*1024
  u16* PS    = (u16*)(ws + 23674880);    // padded support: 30*34*34*1024
  u16* WTSK  = (u16*)(ws + 94699520);    // [128][9216]
  u16* WTSV  = (u16*)(ws + 97058816);    // [512][9216]
  u16* WTQQK = (u16*)(ws + 106496000);   // [256][9216]
  u16* WCQ   = (u16*)(ws + 111214592);   // [512][1024]
  u16* SKR   = (u16*)(ws + 112263168);   // [30720][128]
  u16* SVA   = (u16*)(ws + 120127488);   // [2][512][15360]
  u16* QQR   = (u16*)(ws + 151584768);   // [10240][128]
  u16* QKR   = (u16*)(ws + 154206208);   // [10240][128]
  u16* NEWV  = (u16*)(ws + 156827648);   // [2][512][1024]
  u16* P1T   = PS;                       // alias (PS dead after sv conv)
  u16* P2T   = PQ;                       // alias (PQ dead after qqk/qf convs)
  float* PART  = (float*)(ws + 94699520);  // over weights: [8][512][1024] fp32
  float* PARTK = (float*)SVA;              // [2][30720][128] fp32 (pre-sv)
  float* PARTQ = (float*)SVA;              // [2][10240][256] fp32 (pre-sv)

  const float SCALE = 0.08838834764831843f;  // 1/sqrt(128)

  pad_nhwc<<<dim3(320), 256, 0, stream>>>(query, PQ);
  pad_nhwc<<<dim3(960), 256, 0, stream>>>(support, PS);
  wprep<<<dim3(1408), 256, 0, stream>>>(w_sk, w_sv, w_qq, w_qk, w_cq,
                                        WTSK, WTSV, WTQQK, WCQ);

  // sk conv: split-K=2 -> fp32 partials, then reduce(+bias)
  gemm_nt<1, 5, 2><<<dim3(240, 1, 2), 256, 0, stream>>>(
      WTSK, 0, 9216, PS, 0, 0, 4608, 1.0f, nullptr, nullptr, PARTK, nullptr,
      3932160L, 128);
  reduce_sk<<<dim3(3840), 256, 0, stream>>>(PARTK, b_sk, SKR);

  // qq+qk conv: split-K=2 -> fp32 partials [zc][n][256], then reduce(+bias)
  gemm_nt<1, 5, 2><<<dim3(80, 2, 2), 256, 0, stream>>>(
      WTQQK, 0, 9216, PQ, 0, 0, 4608, 1.0f, nullptr, nullptr, PARTQ, nullptr,
      2621440L, 256);
  reduce_qqk<<<dim3(2560), 256, 0, stream>>>(PARTQ, b_qq, b_qk, QQR, QKR);

  // sv conv (overwrites the partial region -> after reducers)
  gemm256<<<dim3(120, 2), 512, 0, stream>>>(WTSV, PS, b_sv, SVA);

  // qf 1x1 conv
  gemm_nt<2, 2, 1><<<dim3(80, 4, 1), 256, 0, stream>>>(
      WCQ, 0, 1024, PQ, 0, 0, 1024, 1.0f, b_cq, nullptr, out, nullptr, 0, 0);

  // stage 1
  gemm_nt<0, 1, 1><<<dim3(120, 8, 2), 256, 0, stream>>>(
      QQR + 262144, 655360L, 128, SKR, 1966080L, 128, 128, SCALE, nullptr,
      nullptr, P1T, nullptr, 15728640L, 15360);
  row_softmax60<<<dim3(2048), 256, 0, stream>>>(P1T);
  gemm_nt<0, 4, 4><<<dim3(8, 4, 8), 256, 0, stream>>>(
      SVA, 7864320L, 15360, P1T, 15728640L, 15360, 3840, 1.0f, nullptr,
      nullptr, PART, nullptr, 524288L, 1024);
  reduce4<<<dim3(1024), 256, 0, stream>>>(PART, NEWV);

  // stage 2
  gemm_nt<0, 1, 1><<<dim3(8, 40, 2), 256, 0, stream>>>(
      QQR, 655360L, 128, QKR + 262144, 655360L, 128, 128, SCALE, nullptr,
      nullptr, P2T, nullptr, 5242880L, 1024);
  row_softmax4<<<dim3(10240), 256, 0, stream>>>(P2T);
  gemm_nt<0, 3, 1><<<dim3(40, 4, 2), 256, 0, stream>>>(
      NEWV, 524288L, 1024, P2T, 5242880L, 1024, 1024, 1.0f, nullptr, nullptr,
      out, nullptr, 0, 0);
}

// Round 6
// 686.454 us; speedup vs baseline: 1.3310x; 1.0152x over previous
//
#include <hip/hip_runtime.h>
#include <cstdint>

typedef unsigned short u16;
typedef __attribute__((ext_vector_type(8))) u16 u16x8;
typedef __attribute__((ext_vector_type(4))) u16 u16x4;
typedef __attribute__((ext_vector_type(8))) _Float16 f16x8;
typedef __attribute__((ext_vector_type(4))) float f32x4;

// ---------- helpers ----------
__device__ __forceinline__ u16 f2h(float f) {
  _Float16 h = (_Float16)f;
  return __builtin_bit_cast(u16, h);
}
__device__ __forceinline__ float h2f(u16 b) {
  _Float16 h = __builtin_bit_cast(_Float16, b);
  return (float)h;
}
__device__ __forceinline__ void gll16(const void* g, void* l) {
  auto gp = reinterpret_cast<const __attribute__((address_space(1))) unsigned int*>(
      reinterpret_cast<uintptr_t>(g));
  auto lp = reinterpret_cast<__attribute__((address_space(3))) unsigned int*>(
      reinterpret_cast<uintptr_t>(l));
  __builtin_amdgcn_global_load_lds(gp, lp, 16, 0, 0);
}

// ---------- prep: NCHW fp32 -> padded(34x34) NHWC fp16, halo fused ----------
__global__ __launch_bounds__(256) void pad_nhwc(const float* __restrict__ in,
                                                u16* __restrict__ outp) {
  const int img = blockIdx.x >> 5;
  const int y   = blockIdx.x & 31;
  __shared__ float tile[32][33];
  const int tid = threadIdx.x;
  u16* base = outp + (long)img * 34 * 34 * 1024;
  const u16x8 z8 = {0, 0, 0, 0, 0, 0, 0, 0};
  {
    u16* r = base + (long)(y + 1) * 34 * 1024;
    if (tid < 128) *(u16x8*)&r[tid * 8] = z8;
    else *(u16x8*)&r[33 * 1024 + (tid - 128) * 8] = z8;
  }
  if (y == 0) {
    for (int i = tid * 8; i < 34816; i += 2048) *(u16x8*)&base[i] = z8;
  }
  if (y == 31) {
    u16* r = base + 33L * 34 * 1024;
    for (int i = tid * 8; i < 34816; i += 2048) *(u16x8*)&r[i] = z8;
  }
  const int xi = tid & 31, ci = tid >> 5;
  const int xo = tid >> 3, q = tid & 7;
  const float* ip = in + (long)img * 1048576 + y * 32;
  u16* op = base + ((long)(y + 1) * 34 + 1) * 1024;
  for (int c0 = 0; c0 < 1024; c0 += 32) {
#pragma unroll
    for (int k2 = 0; k2 < 4; k2++)
      tile[k2 * 8 + ci][xi] = ip[(long)(c0 + k2 * 8 + ci) * 1024 + xi];
    __syncthreads();
    u16x4 o4;
#pragma unroll
    for (int r = 0; r < 4; r++) o4[r] = f2h(tile[q * 4 + r][xo]);
    *(u16x4*)&op[(long)xo * 1024 + c0 + q * 4] = o4;
    __syncthreads();
  }
}

// ---------- merged weight prep ----------
__device__ __forceinline__ void wre3_body(const float* __restrict__ wp,
                                          u16* __restrict__ op, float* buf) {
  for (int i = threadIdx.x; i < 9216; i += 256) buf[i] = wp[i];
  __syncthreads();
  for (int k = threadIdx.x; k < 9216; k += 256) {
    int t = k >> 10, c = k & 1023;
    op[k] = f2h(buf[c * 9 + t]);
  }
}
__global__ __launch_bounds__(256) void wprep(
    const float* __restrict__ w_sk, const float* __restrict__ w_sv,
    const float* __restrict__ w_qq, const float* __restrict__ w_qk,
    const float* __restrict__ w_cq, u16* __restrict__ WTSK,
    u16* __restrict__ WTSV, u16* __restrict__ WTQQK, u16* __restrict__ WCQ) {
  __shared__ float buf[9216];
  const int b = blockIdx.x;
  if (b < 128) {
    wre3_body(w_sk + (long)b * 9216, WTSK + (long)b * 9216, buf);
  } else if (b < 640) {
    const int oc = b - 128;
    wre3_body(w_sv + (long)oc * 9216, WTSV + (long)oc * 9216, buf);
  } else if (b < 768) {
    const int oc = b - 640;
    wre3_body(w_qq + (long)oc * 9216, WTQQK + (long)oc * 9216, buf);
  } else if (b < 896) {
    const int oc = b - 768;
    wre3_body(w_qk + (long)oc * 9216, WTQQK + (long)(oc + 128) * 9216, buf);
  } else {
    const int i = (b - 896) * 1024 + threadIdx.x * 4;
#pragma unroll
    for (int r = 0; r < 4; r++) WCQ[i + r] = f2h(w_cq[i + r]);
  }
}

// ---------- one-pass register softmax, L=15360 ----------
__global__ __launch_bounds__(256) void row_softmax60(u16* __restrict__ P) {
  u16* p = P + (long)blockIdx.x * 15360;
  const int tid = threadIdx.x;
  __shared__ float rm[4], rs[4];
  u16x4 v[15];
#pragma unroll
  for (int j = 0; j < 15; j++)
    v[j] = *(const u16x4*)(p + ((tid + (j << 8)) << 2));
  float m = -3.0e38f;
#pragma unroll
  for (int j = 0; j < 15; j++)
#pragma unroll
    for (int e = 0; e < 4; e++) m = fmaxf(m, h2f(v[j][e]));
#pragma unroll
  for (int o = 32; o > 0; o >>= 1) m = fmaxf(m, __shfl_xor(m, o, 64));
  if ((tid & 63) == 0) rm[tid >> 6] = m;
  __syncthreads();
  const float M = fmaxf(fmaxf(rm[0], rm[1]), fmaxf(rm[2], rm[3]));
  float s = 0.f;
#pragma unroll
  for (int j = 0; j < 15; j++)
#pragma unroll
    for (int e = 0; e < 4; e++) s += __expf(h2f(v[j][e]) - M);
#pragma unroll
  for (int o = 32; o > 0; o >>= 1) s += __shfl_xor(s, o, 64);
  if ((tid & 63) == 0) rs[tid >> 6] = s;
  __syncthreads();
  const float inv = 1.0f / (rs[0] + rs[1] + rs[2] + rs[3]);
#pragma unroll
  for (int j = 0; j < 15; j++) {
    u16x4 o4;
#pragma unroll
    for (int e = 0; e < 4; e++) o4[e] = f2h(__expf(h2f(v[j][e]) - M) * inv);
    *(u16x4*)(p + ((tid + (j << 8)) << 2)) = o4;
  }
}

// ---------- one-pass register softmax, L=1024 ----------
__global__ __launch_bounds__(256) void row_softmax4(u16* __restrict__ P) {
  u16* p = P + (long)blockIdx.x * 1024;
  const int tid = threadIdx.x;
  __shared__ float rm[4], rs[4];
  u16x4 v = *(const u16x4*)(p + (tid << 2));
  float m = fmaxf(fmaxf(h2f(v[0]), h2f(v[1])), fmaxf(h2f(v[2]), h2f(v[3])));
#pragma unroll
  for (int o = 32; o > 0; o >>= 1) m = fmaxf(m, __shfl_xor(m, o, 64));
  if ((tid & 63) == 0) rm[tid >> 6] = m;
  __syncthreads();
  const float M = fmaxf(fmaxf(rm[0], rm[1]), fmaxf(rm[2], rm[3]));
  float s = 0.f;
#pragma unroll
  for (int e = 0; e < 4; e++) s += __expf(h2f(v[e]) - M);
#pragma unroll
  for (int o = 32; o > 0; o >>= 1) s += __shfl_xor(s, o, 64);
  if ((tid & 63) == 0) rs[tid >> 6] = s;
  __syncthreads();
  const float inv = 1.0f / (rs[0] + rs[1] + rs[2] + rs[3]);
  u16x4 o4;
#pragma unroll
  for (int e = 0; e < 4; e++) o4[e] = f2h(__expf(h2f(v[e]) - M) * inv);
  *(u16x4*)(p + (tid << 2)) = o4;
}

// ---------- split-K reducers ----------
// NEWV f16 = sum of 8 f16 chunks [b][8][512][1024]
__global__ __launch_bounds__(256) void reduce8h(const u16* __restrict__ part,
                                                u16* __restrict__ o) {
  long j = ((long)blockIdx.x * 256 + threadIdx.x) * 4;
  int b = (int)(j >> 19);
  long i = j & 524287;
  const u16* p = part + (long)b * 4194304 + i;
  float s0 = 0.f, s1 = 0.f, s2 = 0.f, s3 = 0.f;
#pragma unroll
  for (int c = 0; c < 8; c++) {
    u16x4 v = *(const u16x4*)&p[(long)c * 524288];
    s0 += h2f(v[0]); s1 += h2f(v[1]); s2 += h2f(v[2]); s3 += h2f(v[3]);
  }
  u16x4 o4 = {f2h(s0), f2h(s1), f2h(s2), f2h(s3)};
  *(u16x4*)&o[j] = o4;
}
// SKR[n][128] = sum_z PARTK[z][n][128] + bias[m]
__global__ __launch_bounds__(256) void reduce_sk(const float* __restrict__ part,
                                                 const float* __restrict__ bias,
                                                 u16* __restrict__ o) {
  long i = ((long)blockIdx.x * 256 + threadIdx.x) * 4;
  f32x4 s = *(const f32x4*)&part[i];
  s = s + *(const f32x4*)&part[i + 3932160];
  f32x4 bb = *(const f32x4*)&bias[(int)(i & 127)];
  u16x4 o4;
#pragma unroll
  for (int r = 0; r < 4; r++) o4[r] = f2h(s[r] + bb[r]);
  *(u16x4*)&o[i] = o4;
}
// QQR/QKR[n][128] = sum_z PARTQ[z][n][256](half) + bias
__global__ __launch_bounds__(256) void reduce_qqk(
    const float* __restrict__ part, const float* __restrict__ b_qq,
    const float* __restrict__ b_qk, u16* __restrict__ QQR,
    u16* __restrict__ QKR) {
  long i = ((long)blockIdx.x * 256 + threadIdx.x) * 4;
  const int n = (int)(i >> 8), m = (int)(i & 255);
  f32x4 s = *(const f32x4*)&part[i];
  s = s + *(const f32x4*)&part[i + 2621440];
  const int lo = (m < 128);
  const int mm = m & 127;
  const float* bs = lo ? b_qq : b_qk;
  f32x4 bb = *(const f32x4*)&bs[mm];
  u16* dst = (lo ? QQR : QKR) + (long)n * 128 + mm;
  u16x4 o4;
#pragma unroll
  for (int r = 0; r < 4; r++) o4[r] = f2h(s[r] + bb[r]);
  *(u16x4*)dst = o4;
}

// ---------- 256x256 4-phase GEMM, B 3-slab ring + counted vmcnt ----------
// A L2-resident (distance-1 prefetch); B HBM (distance-2 prefetch).
// LDS: A 2x32KB @0 | B 3x32KB @65536B. Gate vmcnt(4) once per K-tile.
__global__ __launch_bounds__(512, 1)
void gemm256(const u16* __restrict__ A, const u16* __restrict__ B,
             const float* __restrict__ bias, u16* __restrict__ out) {
  __shared__ u16 lds[81920];  // 163840 B = full LDS
  const int tid = threadIdx.x, lane = tid & 63, wave = tid >> 6;
  const int nwg = gridDim.x * gridDim.y;
  int wg = blockIdx.x + gridDim.x * blockIdx.y;
  wg = (wg & 7) * (nwg >> 3) + (wg >> 3);
  const int ntile = wg % gridDim.x;
  const int mtile = wg / gridDim.x;

  const int slog = (lane & 7) ^ ((lane >> 3) & 7);
  const u16* aS[4];
  const u16* bS[4];
  int aD[4], bD[4];
#pragma unroll
  for (int j = 0; j < 4; j++) {
    const int r = wave * 32 + j * 8 + (lane >> 3);
    aS[j] = A + (long)(mtile * 256 + r) * 9216 + slog * 8;
    aD[j] = (wave * 32 + j * 8) * 64;
    const int n = ntile * 256 + r;
    const int img = n >> 10, p = n & 1023;
    const int y = p >> 5, x = p & 31;
    bS[j] = B + ((long)((img * 34 + y) * 34 + x)) * 1024 + slog * 8;
    bD[j] = (wave * 32 + j * 8) * 64;
  }

  const int g = lane >> 4, l15 = lane & 15;
  const int wm = wave >> 2, wn = wave & 3;
  int aRow[8], bRow[4], sx[2];
#pragma unroll
  for (int mi = 0; mi < 8; mi++) aRow[mi] = (wm * 128 + mi * 16 + l15) * 64;
#pragma unroll
  for (int ni = 0; ni < 4; ni++) bRow[ni] = (wn * 64 + ni * 16 + l15) * 64;
#pragma unroll
  for (int ks = 0; ks < 2; ks++) sx[ks] = ((ks * 4 + g) ^ (l15 & 7)) * 8;

  auto conv_badd = [](int kb) {
    const int t = kb >> 10, c0 = kb & 1023;
    const int dy = t / 3, dx = t - dy * 3;
    return (dy * 34 + dx) * 1024 + c0;
  };

  f32x4 acc[8][4];
  const f32x4 zero = {0.f, 0.f, 0.f, 0.f};
#pragma unroll
  for (int i = 0; i < 8; i++)
#pragma unroll
    for (int j = 0; j < 4; j++) acc[i][j] = zero;

  const int nkt = 144;
  // prologue: A(0)->aslab0, B(0)->bslab0, B(1)->bslab1; gate 8 oldest
  {
#pragma unroll
    for (int j = 0; j < 4; j++) gll16(aS[j], &lds[aD[j]]);
    const int b0 = conv_badd(0), b1 = conv_badd(64);
#pragma unroll
    for (int j = 0; j < 4; j++) gll16(bS[j] + b0, &lds[32768 + bD[j]]);
#pragma unroll
    for (int j = 0; j < 4; j++) gll16(bS[j] + b1, &lds[49152 + bD[j]]);
    asm volatile("s_waitcnt vmcnt(4)" ::: "memory");
    __builtin_amdgcn_s_barrier();
  }

  int bc = 0;  // current B slab (= kt % 3)
  for (int kt = 0; kt < nkt; ++kt) {
    const int abuf = (kt & 1) << 14;          // u16 offset: 0 / 16384
    const int anbuf = abuf ^ 16384;
    const int bbuf = 32768 + bc * 16384;
    int bsn = bc + 2; if (bsn >= 3) bsn -= 3; // staging slab for kt+2
    const int bnbuf = 32768 + bsn * 16384;
    const bool stA = (kt + 1 < nkt);
    const bool stB = (kt + 2 < nkt);
    const int kA = (kt + 1) << 6;
    const int bAdd2 = stB ? conv_badd((kt + 2) << 6) : 0;
    f16x8 afr[4], bfr[4];
    // ---- phase 0: ks0, mi 0..3 ; stage A j0,j1 (kt+1) ----
#pragma unroll
    for (int mi = 0; mi < 4; mi++) afr[mi] = *(const f16x8*)&lds[abuf + aRow[mi] + sx[0]];
#pragma unroll
    for (int ni = 0; ni < 4; ni++) bfr[ni] = *(const f16x8*)&lds[bbuf + bRow[ni] + sx[0]];
    if (stA) {
      gll16(aS[0] + kA, &lds[anbuf + aD[0]]);
      gll16(aS[1] + kA, &lds[anbuf + aD[1]]);
    }
    __builtin_amdgcn_s_barrier();
    __builtin_amdgcn_s_setprio(1);
#pragma unroll
    for (int mi = 0; mi < 4; mi++)
#pragma unroll
      for (int ni = 0; ni < 4; ni++)
        acc[mi][ni] = __builtin_amdgcn_mfma_f32_16x16x32_f16(afr[mi], bfr[ni], acc[mi][ni], 0, 0, 0);
    __builtin_amdgcn_s_setprio(0);
    __builtin_amdgcn_s_barrier();
    // ---- phase 1: ks0, mi 4..7 ; stage A j2,j3 ----
#pragma unroll
    for (int mi = 0; mi < 4; mi++) afr[mi] = *(const f16x8*)&lds[abuf + aRow[mi + 4] + sx[0]];
    if (stA) {
      gll16(aS[2] + kA, &lds[anbuf + aD[2]]);
      gll16(aS[3] + kA, &lds[anbuf + aD[3]]);
    }
    __builtin_amdgcn_s_barrier();
    __builtin_amdgcn_s_setprio(1);
#pragma unroll
    for (int mi = 0; mi < 4; mi++)
#pragma unroll
      for (int ni = 0; ni < 4; ni++)
        acc[mi + 4][ni] = __builtin_amdgcn_mfma_f32_16x16x32_f16(afr[mi], bfr[ni], acc[mi + 4][ni], 0, 0, 0);
    __builtin_amdgcn_s_setprio(0);
    __builtin_amdgcn_s_barrier();
    // ---- phase 2: ks1, mi 0..3 ; stage B j0,j1 (kt+2) ----
#pragma unroll
    for (int mi = 0; mi < 4; mi++) afr[mi] = *(const f16x8*)&lds[abuf + aRow[mi] + sx[1]];
#pragma unroll
    for (int ni = 0; ni < 4; ni++) bfr[ni] = *(const f16x8*)&lds[bbuf + bRow[ni] + sx[1]];
    if (stB) {
      gll16(bS[0] + bAdd2, &lds[bnbuf + bD[0]]);
      gll16(bS[1] + bAdd2, &lds[bnbuf + bD[1]]);
    }
    __builtin_amdgcn_s_barrier();
    __builtin_amdgcn_s_setprio(1);
#pragma unroll
    for (int mi = 0; mi < 4; mi++)
#pragma unroll
      for (int ni = 0; ni < 4; ni++)
        acc[mi][ni] = __builtin_amdgcn_mfma_f32_16x16x32_f16(afr[mi], bfr[ni], acc[mi][ni], 0, 0, 0);
    __builtin_amdgcn_s_setprio(0);
    __builtin_amdgcn_s_barrier();
    // ---- phase 3: ks1, mi 4..7 ; stage B j2,j3 ; counted gate ----
#pragma unroll
    for (int mi = 0; mi < 4; mi++) afr[mi] = *(const f16x8*)&lds[abuf + aRow[mi + 4] + sx[1]];
    if (stB) {
      gll16(bS[2] + bAdd2, &lds[bnbuf + bD[2]]);
      gll16(bS[3] + bAdd2, &lds[bnbuf + bD[3]]);
    }
    __builtin_amdgcn_s_barrier();
    __builtin_amdgcn_s_setprio(1);
#pragma unroll
    for (int mi = 0; mi < 4; mi++)
#pragma unroll
      for (int ni = 0; ni < 4; ni++)
        acc[mi + 4][ni] = __builtin_amdgcn_mfma_f32_16x16x32_f16(afr[mi], bfr[ni], acc[mi + 4][ni], 0, 0, 0);
    __builtin_amdgcn_s_setprio(0);
    if (stB) {
      asm volatile("s_waitcnt vmcnt(4)" ::: "memory");  // A(t+1),B(t+1) done; B(t+2) flies
    } else if (stA) {
      asm volatile("s_waitcnt vmcnt(0)" ::: "memory");
    }
    __builtin_amdgcn_s_barrier();
    bc = bc + 1; if (bc >= 3) bc -= 3;
  }

  // ---- epilogue: SVA[b][m][col] = acc + bias[m] ----
#pragma unroll
  for (int mi = 0; mi < 8; mi++) {
#pragma unroll
    for (int ni = 0; ni < 4; ni++) {
      f32x4 v = acc[mi][ni];
      const int m0 = mtile * 256 + wm * 128 + mi * 16 + g * 4;
      const int n = ntile * 256 + wn * 64 + ni * 16 + l15;
      const int b = (n >= 15360) ? 1 : 0;
      const int rem = n - b * 15360;
#pragma unroll
      for (int r = 0; r < 4; r++) {
        const int m = m0 + r;
        out[(long)b * 7864320 + (long)m * 15360 + rem] = f2h(v[r] + bias[m]);
      }
    }
  }
}

// ---------- 128x128 NT GEMM (2-phase, general purpose) ----------
// BMODE: 0 plain rows [n][K]; 1 = 3x3 conv patches (padded NHWC); 2 = 1x1 center
// EPI: 0 f16 transposed store (dual out); 1 f16 row store *scale(+bias);
//      2 qf fp32; 3 final fp32; 4 fp32 partial row; 5 fp32 transposed partial;
//      6 f16 partial row
template <int BMODE, int EPI, int SPLITK>
__global__ __launch_bounds__(256, 2)
void gemm_nt(const u16* __restrict__ A, long Azoff, int Astride,
             const u16* __restrict__ B, long Bzoff, int Bstride,
             int K, float scale,
             const float* __restrict__ bias, const float* __restrict__ bias2,
             void* __restrict__ out0, void* __restrict__ out1,
             long out_zoff, int ldo) {
  __shared__ u16 lds[4 * 8192];
  const int tid = threadIdx.x;
  const int lane = tid & 63;
  const int wave = tid >> 6;
  const int mtile = blockIdx.y, ntile = blockIdx.x, z = blockIdx.z;

  const int zb = (SPLITK > 1) ? z / SPLITK : z;
  const int zc = (SPLITK > 1) ? z % SPLITK : 0;
  const u16* Ab = A + (long)zb * Azoff + (long)zc * K;
  const u16* Bb = B + (long)zb * Bzoff + ((BMODE == 0) ? (long)zc * K : 0);

  const int r8 = lane >> 3;
  const int sphys = lane & 7;
  const u16* aSrc[4];
  const u16* bSrc[4];
  u16* aDst[4];
  u16* bDst[4];
#pragma unroll
  for (int i = 0; i < 4; i++) {
    const int row = wave * 32 + i * 8 + r8;
    const int slog = sphys ^ (row & 7);
    aSrc[i] = Ab + (long)(mtile * 128 + row) * Astride + slog * 8;
    if (BMODE == 0) {
      bSrc[i] = Bb + (long)(ntile * 128 + row) * Bstride + slog * 8;
    } else {
      const int n = ntile * 128 + row;
      const int img = n >> 10;
      const int p = n & 1023;
      const int y = p >> 5, x = p & 31;
      bSrc[i] = Bb + ((long)(img * 34 + y) * 34 + x) * 1024 + slog * 8;
    }
    aDst[i] = &lds[0] + (wave * 32 + i * 8) * 64;
    bDst[i] = &lds[0] + 8192 + (wave * 32 + i * 8) * 64;
  }

  const int g = lane >> 4, l15 = lane & 15;
  const int wm = wave >> 1, wn = wave & 1;
  int offA[2][4], offB[2][4];
#pragma unroll
  for (int ks = 0; ks < 2; ks++) {
    const int sl = ks * 4 + g;
#pragma unroll
    for (int i = 0; i < 4; i++) {
      const int ra = wm * 64 + i * 16 + l15;
      offA[ks][i] = ra * 64 + ((sl ^ (ra & 7)) * 8);
      const int rb = wn * 64 + i * 16 + l15;
      offB[ks][i] = 8192 + rb * 64 + ((sl ^ (rb & 7)) * 8);
    }
  }

  auto stage = [&](int buf, int kb) {
    int bAdd;
    if (BMODE == 0) {
      bAdd = kb;
    } else if (BMODE == 1) {
      const int kbg = zc * K + kb;
      const int t = kbg >> 10, c0 = kbg & 1023;
      const int dy = t / 3, dx = t - dy * 3;
      bAdd = (dy * 34 + dx) * 1024 + c0;
    } else {
      bAdd = 35 * 1024 + kb;
    }
    const int bufo = buf * 16384;
#pragma unroll
    for (int i = 0; i < 4; i++) gll16(aSrc[i] + kb, aDst[i] + bufo);
#pragma unroll
    for (int i = 0; i < 4; i++) gll16(bSrc[i] + bAdd, bDst[i] + bufo);
  };

  f32x4 acc[4][4];
  const f32x4 zero = {0.f, 0.f, 0.f, 0.f};
#pragma unroll
  for (int i = 0; i < 4; i++)
#pragma unroll
    for (int j = 0; j < 4; j++) acc[i][j] = zero;

  const int nkt = K >> 6;
  stage(0, 0);
  __syncthreads();
  for (int kt = 0; kt < nkt; ++kt) {
    const int buf = kt & 1;
    if (kt + 1 < nkt) stage(buf ^ 1, (kt + 1) << 6);
#pragma unroll
    for (int ks = 0; ks < 2; ks++) {
      f16x8 af[4], bfg[4];
#pragma unroll
      for (int i = 0; i < 4; i++)
        af[i] = *(const f16x8*)&lds[buf * 16384 + offA[ks][i]];
#pragma unroll
      for (int i = 0; i < 4; i++)
        bfg[i] = *(const f16x8*)&lds[buf * 16384 + offB[ks][i]];
#pragma unroll
      for (int mi = 0; mi < 4; mi++)
#pragma unroll
        for (int ni = 0; ni < 4; ni++)
          acc[mi][ni] = __builtin_amdgcn_mfma_f32_16x16x32_f16(
              af[mi], bfg[ni], acc[mi][ni], 0, 0, 0);
    }
    __syncthreads();
  }

#pragma unroll
  for (int mi = 0; mi < 4; mi++) {
#pragma unroll
    for (int ni = 0; ni < 4; ni++) {
      f32x4 v = acc[mi][ni];
      const int m0 = mtile * 128 + wm * 64 + mi * 16 + g * 4;
      const int n = ntile * 128 + wn * 64 + ni * 16 + l15;
      if (EPI == 0) {
        u16* ob = (u16*)out0;
        const float* bs = bias;
        int mm = m0;
        if (out1 != nullptr && m0 >= 128) { ob = (u16*)out1; bs = bias2; mm = m0 - 128; }
        u16x4 pk;
#pragma unroll
        for (int r = 0; r < 4; r++) {
          float val = v[r] * scale + (bs ? bs[mm + r] : 0.f);
          pk[r] = f2h(val);
        }
        *(u16x4*)&ob[(long)n * ldo + mm] = pk;
      } else if (EPI == 1) {
        u16* ob = (u16*)out0 + (long)z * out_zoff;
#pragma unroll
        for (int r = 0; r < 4; r++) {
          const int m = m0 + r;
          float val = v[r] * scale + (bias ? bias[m] : 0.f);
          ob[(long)m * ldo + n] = f2h(val);
        }
      } else if (EPI == 2) {
        float* of = (float*)out0;
        const int img = n >> 10, p = n & 1023;
#pragma unroll
        for (int r = 0; r < 4; r++) {
          const int m = m0 + r;
          of[(long)img * 1048576 + (long)(512 + m) * 1024 + p] =
              v[r] + (bias ? bias[m] : 0.f);
        }
      } else if (EPI == 3) {
        float* of = (float*)out0;
        const int f = n >> 10, p = n & 1023;
#pragma unroll
        for (int r = 0; r < 4; r++) {
          const int m = m0 + r;
          of[(long)z * 5242880 + (long)f * 1048576 + (long)m * 1024 + p] = v[r];
        }
      } else if (EPI == 4) {
        float* of = (float*)out0 + (long)z * out_zoff;
#pragma unroll
        for (int r = 0; r < 4; r++) of[(long)(m0 + r) * ldo + n] = v[r];
      } else if (EPI == 5) {
        float* of = (float*)out0 + (long)zc * out_zoff;
        *(f32x4*)&of[(long)n * ldo + m0] = v;
      } else {  // EPI == 6: f16 partial row store
        u16* ob = (u16*)out0 + (long)z * out_zoff;
#pragma unroll
        for (int r = 0; r < 4; r++) ob[(long)(m0 + r) * ldo + n] = f2h(v[r]);
      }
    }
  }
}

// ---------- launch ----------
extern "C" void kernel_launch(void* const* d_in, const int* in_sizes, int n_in,
                              void* d_out, int out_size, void* d_ws, size_t ws_size,
                              hipStream_t stream) {
  (void)in_sizes; (void)n_in; (void)out_size;
  const float* query   = (const float*)d_in[0];
  const float* support = (const float*)d_in[1];
  const float* w_sk = (const float*)d_in[2];  const float* b_sk = (const float*)d_in[3];
  const float* w_sv = (const float*)d_in[4];  const float* b_sv = (const float*)d_in[5];
  const float* w_qq = (const float*)d_in[6];  const float* b_qq = (const float*)d_in[7];
  const float* w_qk = (const float*)d_in[8];  const float* b_qk = (const float*)d_in[9];
  const float* w_cq = (const float*)d_in[10]; const float* b_cq = (const float*)d_in[11];
  float* out = (float*)d_out;
  char* ws = (char*)d_ws;

  if (ws_size < 158924800u) return;

  u16* PQ    = (u16*)(ws + 0);           // padded query NHWC f16: 10*34*34*1024
  u16* PS    = (u16*)(ws + 23674880);    // padded support: 30*34*34*1024
  u16* WTSK  = (u16*)(ws + 94699520);    // [128][9216]
  u16* WTSV  = (u16*)(ws + 97058816);    // [512][9216]
  u16* WTQQK = (u16*)(ws + 106496000);   // [256][9216]
  u16* WCQ   = (u16*)(ws + 111214592);   // [512][1024]
  u16* SKR   = (u16*)(ws + 112263168);   // [30720][128]
  u16* SVA   = (u16*)(ws + 120127488);   // [2][512][15360]
  u16* QQR   = (u16*)(ws + 151584768);   // [10240][128]
  u16* QKR   = (u16*)(ws + 154206208);   // [10240][128]
  u16* NEWV  = (u16*)(ws + 156827648);   // [2][512][1024]
  u16* P1T   = PS;                       // alias (PS dead after sv conv)
  u16* P2T   = PQ;                       // alias (PQ dead after qqk/qf convs)
  u16* PART2 = (u16*)(ws + 94699520);    // over weights: [16][512][1024] f16
  float* PARTK = (float*)SVA;            // [2][30720][128] fp32 (pre-sv)
  float* PARTQ = (float*)SVA;            // [2][10240][256] fp32 (pre-sv)

  const float SCALE = 0.08838834764831843f;  // 1/sqrt(128)

  pad_nhwc<<<dim3(320), 256, 0, stream>>>(query, PQ);
  pad_nhwc<<<dim3(960), 256, 0, stream>>>(support, PS);
  wprep<<<dim3(1408), 256, 0, stream>>>(w_sk, w_sv, w_qq, w_qk, w_cq,
                                        WTSK, WTSV, WTQQK, WCQ);

  // sk conv: split-K=2 -> fp32 partials, then reduce(+bias)
  gemm_nt<1, 5, 2><<<dim3(240, 1, 2), 256, 0, stream>>>(
      WTSK, 0, 9216, PS, 0, 0, 4608, 1.0f, nullptr, nullptr, PARTK, nullptr,
      3932160L, 128);
  reduce_sk<<<dim3(3840), 256, 0, stream>>>(PARTK, b_sk, SKR);

  // qq+qk conv: split-K=2 -> fp32 partials [zc][n][256], then reduce(+bias)
  gemm_nt<1, 5, 2><<<dim3(80, 2, 2), 256, 0, stream>>>(
      WTQQK, 0, 9216, PQ, 0, 0, 4608, 1.0f, nullptr, nullptr, PARTQ, nullptr,
      2621440L, 256);
  reduce_qqk<<<dim3(2560), 256, 0, stream>>>(PARTQ, b_qq, b_qk, QQR, QKR);

  // sv conv (overwrites the partial region -> after reducers)
  gemm256<<<dim3(120, 2), 512, 0, stream>>>(WTSV, PS, b_sv, SVA);

  // qf 1x1 conv
  gemm_nt<2, 2, 1><<<dim3(80, 4, 1), 256, 0, stream>>>(
      WCQ, 0, 1024, PQ, 0, 0, 1024, 1.0f, b_cq, nullptr, out, nullptr, 0, 0);

  // stage 1
  gemm_nt<0, 1, 1><<<dim3(120, 8, 2), 256, 0, stream>>>(
      QQR + 262144, 655360L, 128, SKR, 1966080L, 128, 128, SCALE, nullptr,
      nullptr, P1T, nullptr, 15728640L, 15360);
  row_softmax60<<<dim3(2048), 256, 0, stream>>>(P1T);
  gemm_nt<0, 6, 8><<<dim3(8, 4, 16), 256, 0, stream>>>(
      SVA, 7864320L, 15360, P1T, 15728640L, 15360, 1920, 1.0f, nullptr,
      nullptr, PART2, nullptr, 524288L, 1024);
  reduce8h<<<dim3(1024), 256, 0, stream>>>(PART2, NEWV);

  // stage 2
  gemm_nt<0, 1, 1><<<dim3(8, 40, 2), 256, 0, stream>>>(
      QQR, 655360L, 128, QKR + 262144, 655360L, 128, 128, SCALE, nullptr,
      nullptr, P2T, nullptr, 5242880L, 1024);
  row_softmax4<<<dim3(10240), 256, 0, stream>>>(P2T);
  gemm_nt<0, 3, 1><<<dim3(40, 4, 2), 256, 0, stream>>>(
      NEWV, 524288L, 1024, P2T, 5242880L, 1024, 1024, 1.0f, nullptr, nullptr,
      out, nullptr, 0, 0);
}

// Round 7
// 668.753 us; speedup vs baseline: 1.3663x; 1.0265x over previous
//
#include <hip/hip_runtime.h>
#include <cstdint>

typedef unsigned short u16;
typedef __attribute__((ext_vector_type(8))) u16 u16x8;
typedef __attribute__((ext_vector_type(4))) u16 u16x4;
typedef __attribute__((ext_vector_type(8))) _Float16 f16x8;
typedef __attribute__((ext_vector_type(4))) float f32x4;

// ---------- helpers ----------
__device__ __forceinline__ u16 f2h(float f) {
  _Float16 h = (_Float16)f;
  return __builtin_bit_cast(u16, h);
}
__device__ __forceinline__ float h2f(u16 b) {
  _Float16 h = __builtin_bit_cast(_Float16, b);
  return (float)h;
}
__device__ __forceinline__ void gll16(const void* g, void* l) {
  auto gp = reinterpret_cast<const __attribute__((address_space(1))) unsigned int*>(
      reinterpret_cast<uintptr_t>(g));
  auto lp = reinterpret_cast<__attribute__((address_space(3))) unsigned int*>(
      reinterpret_cast<uintptr_t>(l));
  __builtin_amdgcn_global_load_lds(gp, lp, 16, 0, 0);
}

// ---------- prep: NCHW fp32 -> padded(34x34) NHWC fp16, halo fused ----------
__global__ __launch_bounds__(256) void pad_nhwc(const float* __restrict__ in,
                                                u16* __restrict__ outp) {
  const int img = blockIdx.x >> 5;
  const int y   = blockIdx.x & 31;
  __shared__ float tile[32][33];
  const int tid = threadIdx.x;
  u16* base = outp + (long)img * 34 * 34 * 1024;
  const u16x8 z8 = {0, 0, 0, 0, 0, 0, 0, 0};
  {
    u16* r = base + (long)(y + 1) * 34 * 1024;
    if (tid < 128) *(u16x8*)&r[tid * 8] = z8;
    else *(u16x8*)&r[33 * 1024 + (tid - 128) * 8] = z8;
  }
  if (y == 0) {
    for (int i = tid * 8; i < 34816; i += 2048) *(u16x8*)&base[i] = z8;
  }
  if (y == 31) {
    u16* r = base + 33L * 34 * 1024;
    for (int i = tid * 8; i < 34816; i += 2048) *(u16x8*)&r[i] = z8;
  }
  const int xi = tid & 31, ci = tid >> 5;
  const int xo = tid >> 3, q = tid & 7;
  const float* ip = in + (long)img * 1048576 + y * 32;
  u16* op = base + ((long)(y + 1) * 34 + 1) * 1024;
  for (int c0 = 0; c0 < 1024; c0 += 32) {
#pragma unroll
    for (int k2 = 0; k2 < 4; k2++)
      tile[k2 * 8 + ci][xi] = ip[(long)(c0 + k2 * 8 + ci) * 1024 + xi];
    __syncthreads();
    u16x4 o4;
#pragma unroll
    for (int r = 0; r < 4; r++) o4[r] = f2h(tile[q * 4 + r][xo]);
    *(u16x4*)&op[(long)xo * 1024 + c0 + q * 4] = o4;
    __syncthreads();
  }
}

// ---------- merged weight prep ----------
// 3x3 weights are emitted in CHANNEL-BLOCK-MAJOR, TAP-MINOR k-order:
//   k = cblk*576 + tap*64 + ci   (cblk = c>>6, ci = c&63)
// so that 9 consecutive K-tiles (64 k each) reuse one 64-channel slab of B.
__device__ __forceinline__ void wre3_body(const float* __restrict__ wp,
                                          u16* __restrict__ op, float* buf) {
  for (int i = threadIdx.x; i < 9216; i += 256) buf[i] = wp[i];
  __syncthreads();
  for (int k = threadIdx.x; k < 9216; k += 256) {
    const int cblk = k / 576;
    const int r = k - cblk * 576;
    const int t = r >> 6, ci = r & 63;
    op[k] = f2h(buf[(cblk * 64 + ci) * 9 + t]);
  }
}
__global__ __launch_bounds__(256) void wprep(
    const float* __restrict__ w_sk, const float* __restrict__ w_sv,
    const float* __restrict__ w_qq, const float* __restrict__ w_qk,
    const float* __restrict__ w_cq, u16* __restrict__ WTSK,
    u16* __restrict__ WTSV, u16* __restrict__ WTQQK, u16* __restrict__ WCQ) {
  __shared__ float buf[9216];
  const int b = blockIdx.x;
  if (b < 128) {
    wre3_body(w_sk + (long)b * 9216, WTSK + (long)b * 9216, buf);
  } else if (b < 640) {
    const int oc = b - 128;
    wre3_body(w_sv + (long)oc * 9216, WTSV + (long)oc * 9216, buf);
  } else if (b < 768) {
    const int oc = b - 640;
    wre3_body(w_qq + (long)oc * 9216, WTQQK + (long)oc * 9216, buf);
  } else if (b < 896) {
    const int oc = b - 768;
    wre3_body(w_qk + (long)oc * 9216, WTQQK + (long)(oc + 128) * 9216, buf);
  } else {
    const int i = (b - 896) * 1024 + threadIdx.x * 4;
#pragma unroll
    for (int r = 0; r < 4; r++) WCQ[i + r] = f2h(w_cq[i + r]);
  }
}

// ---------- one-pass register softmax, L=15360 ----------
__global__ __launch_bounds__(256) void row_softmax60(u16* __restrict__ P) {
  u16* p = P + (long)blockIdx.x * 15360;
  const int tid = threadIdx.x;
  __shared__ float rm[4], rs[4];
  u16x4 v[15];
#pragma unroll
  for (int j = 0; j < 15; j++)
    v[j] = *(const u16x4*)(p + ((tid + (j << 8)) << 2));
  float m = -3.0e38f;
#pragma unroll
  for (int j = 0; j < 15; j++)
#pragma unroll
    for (int e = 0; e < 4; e++) m = fmaxf(m, h2f(v[j][e]));
#pragma unroll
  for (int o = 32; o > 0; o >>= 1) m = fmaxf(m, __shfl_xor(m, o, 64));
  if ((tid & 63) == 0) rm[tid >> 6] = m;
  __syncthreads();
  const float M = fmaxf(fmaxf(rm[0], rm[1]), fmaxf(rm[2], rm[3]));
  float s = 0.f;
#pragma unroll
  for (int j = 0; j < 15; j++)
#pragma unroll
    for (int e = 0; e < 4; e++) s += __expf(h2f(v[j][e]) - M);
#pragma unroll
  for (int o = 32; o > 0; o >>= 1) s += __shfl_xor(s, o, 64);
  if ((tid & 63) == 0) rs[tid >> 6] = s;
  __syncthreads();
  const float inv = 1.0f / (rs[0] + rs[1] + rs[2] + rs[3]);
#pragma unroll
  for (int j = 0; j < 15; j++) {
    u16x4 o4;
#pragma unroll
    for (int e = 0; e < 4; e++) o4[e] = f2h(__expf(h2f(v[j][e]) - M) * inv);
    *(u16x4*)(p + ((tid + (j << 8)) << 2)) = o4;
  }
}

// ---------- one-pass register softmax, L=1024 ----------
__global__ __launch_bounds__(256) void row_softmax4(u16* __restrict__ P) {
  u16* p = P + (long)blockIdx.x * 1024;
  const int tid = threadIdx.x;
  __shared__ float rm[4], rs[4];
  u16x4 v = *(const u16x4*)(p + (tid << 2));
  float m = fmaxf(fmaxf(h2f(v[0]), h2f(v[1])), fmaxf(h2f(v[2]), h2f(v[3])));
#pragma unroll
  for (int o = 32; o > 0; o >>= 1) m = fmaxf(m, __shfl_xor(m, o, 64));
  if ((tid & 63) == 0) rm[tid >> 6] = m;
  __syncthreads();
  const float M = fmaxf(fmaxf(rm[0], rm[1]), fmaxf(rm[2], rm[3]));
  float s = 0.f;
#pragma unroll
  for (int e = 0; e < 4; e++) s += __expf(h2f(v[e]) - M);
#pragma unroll
  for (int o = 32; o > 0; o >>= 1) s += __shfl_xor(s, o, 64);
  if ((tid & 63) == 0) rs[tid >> 6] = s;
  __syncthreads();
  const float inv = 1.0f / (rs[0] + rs[1] + rs[2] + rs[3]);
  u16x4 o4;
#pragma unroll
  for (int e = 0; e < 4; e++) o4[e] = f2h(__expf(h2f(v[e]) - M) * inv);
  *(u16x4*)(p + (tid << 2)) = o4;
}

// ---------- split-K reducers ----------
__global__ __launch_bounds__(256) void reduce8h(const u16* __restrict__ part,
                                                u16* __restrict__ o) {
  long j = ((long)blockIdx.x * 256 + threadIdx.x) * 4;
  int b = (int)(j >> 19);
  long i = j & 524287;
  const u16* p = part + (long)b * 4194304 + i;
  float s0 = 0.f, s1 = 0.f, s2 = 0.f, s3 = 0.f;
#pragma unroll
  for (int c = 0; c < 8; c++) {
    u16x4 v = *(const u16x4*)&p[(long)c * 524288];
    s0 += h2f(v[0]); s1 += h2f(v[1]); s2 += h2f(v[2]); s3 += h2f(v[3]);
  }
  u16x4 o4 = {f2h(s0), f2h(s1), f2h(s2), f2h(s3)};
  *(u16x4*)&o[j] = o4;
}
__global__ __launch_bounds__(256) void reduce_sk(const float* __restrict__ part,
                                                 const float* __restrict__ bias,
                                                 u16* __restrict__ o) {
  long i = ((long)blockIdx.x * 256 + threadIdx.x) * 4;
  f32x4 s = *(const f32x4*)&part[i];
  s = s + *(const f32x4*)&part[i + 3932160];
  f32x4 bb = *(const f32x4*)&bias[(int)(i & 127)];
  u16x4 o4;
#pragma unroll
  for (int r = 0; r < 4; r++) o4[r] = f2h(s[r] + bb[r]);
  *(u16x4*)&o[i] = o4;
}
__global__ __launch_bounds__(256) void reduce_qqk(
    const float* __restrict__ part, const float* __restrict__ b_qq,
    const float* __restrict__ b_qk, u16* __restrict__ QQR,
    u16* __restrict__ QKR) {
  long i = ((long)blockIdx.x * 256 + threadIdx.x) * 4;
  const int n = (int)(i >> 8), m = (int)(i & 255);
  f32x4 s = *(const f32x4*)&part[i];
  s = s + *(const f32x4*)&part[i + 2621440];
  const int lo = (m < 128);
  const int mm = m & 127;
  const float* bs = lo ? b_qq : b_qk;
  f32x4 bb = *(const f32x4*)&bs[mm];
  u16* dst = (lo ? QQR : QKR) + (long)n * 128 + mm;
  u16x4 o4;
#pragma unroll
  for (int r = 0; r < 4; r++) o4[r] = f2h(s[r] + bb[r]);
  *(u16x4*)dst = o4;
}

// ---------- 256x256 4-phase GEMM, B 3-slab ring + counted vmcnt ----------
// K-order: cblk-major, tap-minor (K-tile kt -> cblk=kt/9, tap=kt%9), so
// 9 consecutive K-tiles re-read one L2-resident 64-channel B slab.
__global__ __launch_bounds__(512, 1)
void gemm256(const u16* __restrict__ A, const u16* __restrict__ B,
             const float* __restrict__ bias, u16* __restrict__ out) {
  __shared__ u16 lds[81920];
  const int tid = threadIdx.x, lane = tid & 63, wave = tid >> 6;
  const int nwg = gridDim.x * gridDim.y;
  int wg = blockIdx.x + gridDim.x * blockIdx.y;
  wg = (wg & 7) * (nwg >> 3) + (wg >> 3);
  const int ntile = wg % gridDim.x;
  const int mtile = wg / gridDim.x;

  const int slog = (lane & 7) ^ ((lane >> 3) & 7);
  const u16* aS[4];
  const u16* bS[4];
  int aD[4], bD[4];
#pragma unroll
  for (int j = 0; j < 4; j++) {
    const int r = wave * 32 + j * 8 + (lane >> 3);
    aS[j] = A + (long)(mtile * 256 + r) * 9216 + slog * 8;
    aD[j] = (wave * 32 + j * 8) * 64;
    const int n = ntile * 256 + r;
    const int img = n >> 10, p = n & 1023;
    const int y = p >> 5, x = p & 31;
    bS[j] = B + ((long)((img * 34 + y) * 34 + x)) * 1024 + slog * 8;
    bD[j] = (wave * 32 + j * 8) * 64;
  }

  const int g = lane >> 4, l15 = lane & 15;
  const int wm = wave >> 2, wn = wave & 3;
  int aRow[8], bRow[4], sx[2];
#pragma unroll
  for (int mi = 0; mi < 8; mi++) aRow[mi] = (wm * 128 + mi * 16 + l15) * 64;
#pragma unroll
  for (int ni = 0; ni < 4; ni++) bRow[ni] = (wn * 64 + ni * 16 + l15) * 64;
#pragma unroll
  for (int ks = 0; ks < 2; ks++) sx[ks] = ((ks * 4 + g) ^ (l15 & 7)) * 8;

  // B element offset for K-tile kt (channel-block-major, tap-minor)
  auto conv_badd = [](int kt) {
    const int cblk = kt / 9;
    const int t = kt - cblk * 9;
    const int dy = t / 3, dx = t - dy * 3;
    return (dy * 34 + dx) * 1024 + cblk * 64;
  };

  f32x4 acc[8][4];
  const f32x4 zero = {0.f, 0.f, 0.f, 0.f};
#pragma unroll
  for (int i = 0; i < 8; i++)
#pragma unroll
    for (int j = 0; j < 4; j++) acc[i][j] = zero;

  const int nkt = 144;
  {
#pragma unroll
    for (int j = 0; j < 4; j++) gll16(aS[j], &lds[aD[j]]);
    const int b0 = conv_badd(0), b1 = conv_badd(1);
#pragma unroll
    for (int j = 0; j < 4; j++) gll16(bS[j] + b0, &lds[32768 + bD[j]]);
#pragma unroll
    for (int j = 0; j < 4; j++) gll16(bS[j] + b1, &lds[49152 + bD[j]]);
    asm volatile("s_waitcnt vmcnt(4)" ::: "memory");
    __builtin_amdgcn_s_barrier();
  }

  int bc = 0;
  for (int kt = 0; kt < nkt; ++kt) {
    const int abuf = (kt & 1) << 14;
    const int anbuf = abuf ^ 16384;
    const int bbuf = 32768 + bc * 16384;
    int bsn = bc + 2; if (bsn >= 3) bsn -= 3;
    const int bnbuf = 32768 + bsn * 16384;
    const bool stA = (kt + 1 < nkt);
    const bool stB = (kt + 2 < nkt);
    const int kA = (kt + 1) << 6;
    const int bAdd2 = stB ? conv_badd(kt + 2) : 0;
    f16x8 afr[4], bfr[4];
    // ---- phase 0: ks0, mi 0..3 ; stage A j0,j1 (kt+1) ----
#pragma unroll
    for (int mi = 0; mi < 4; mi++) afr[mi] = *(const f16x8*)&lds[abuf + aRow[mi] + sx[0]];
#pragma unroll
    for (int ni = 0; ni < 4; ni++) bfr[ni] = *(const f16x8*)&lds[bbuf + bRow[ni] + sx[0]];
    if (stA) {
      gll16(aS[0] + kA, &lds[anbuf + aD[0]]);
      gll16(aS[1] + kA, &lds[anbuf + aD[1]]);
    }
    __builtin_amdgcn_s_barrier();
    __builtin_amdgcn_s_setprio(1);
#pragma unroll
    for (int mi = 0; mi < 4; mi++)
#pragma unroll
      for (int ni = 0; ni < 4; ni++)
        acc[mi][ni] = __builtin_amdgcn_mfma_f32_16x16x32_f16(afr[mi], bfr[ni], acc[mi][ni], 0, 0, 0);
    __builtin_amdgcn_s_setprio(0);
    __builtin_amdgcn_s_barrier();
    // ---- phase 1: ks0, mi 4..7 ; stage A j2,j3 ----
#pragma unroll
    for (int mi = 0; mi < 4; mi++) afr[mi] = *(const f16x8*)&lds[abuf + aRow[mi + 4] + sx[0]];
    if (stA) {
      gll16(aS[2] + kA, &lds[anbuf + aD[2]]);
      gll16(aS[3] + kA, &lds[anbuf + aD[3]]);
    }
    __builtin_amdgcn_s_barrier();
    __builtin_amdgcn_s_setprio(1);
#pragma unroll
    for (int mi = 0; mi < 4; mi++)
#pragma unroll
      for (int ni = 0; ni < 4; ni++)
        acc[mi + 4][ni] = __builtin_amdgcn_mfma_f32_16x16x32_f16(afr[mi], bfr[ni], acc[mi + 4][ni], 0, 0, 0);
    __builtin_amdgcn_s_setprio(0);
    __builtin_amdgcn_s_barrier();
    // ---- phase 2: ks1, mi 0..3 ; stage B j0,j1 (kt+2) ----
#pragma unroll
    for (int mi = 0; mi < 4; mi++) afr[mi] = *(const f16x8*)&lds[abuf + aRow[mi] + sx[1]];
#pragma unroll
    for (int ni = 0; ni < 4; ni++) bfr[ni] = *(const f16x8*)&lds[bbuf + bRow[ni] + sx[1]];
    if (stB) {
      gll16(bS[0] + bAdd2, &lds[bnbuf + bD[0]]);
      gll16(bS[1] + bAdd2, &lds[bnbuf + bD[1]]);
    }
    __builtin_amdgcn_s_barrier();
    __builtin_amdgcn_s_setprio(1);
#pragma unroll
    for (int mi = 0; mi < 4; mi++)
#pragma unroll
      for (int ni = 0; ni < 4; ni++)
        acc[mi][ni] = __builtin_amdgcn_mfma_f32_16x16x32_f16(afr[mi], bfr[ni], acc[mi][ni], 0, 0, 0);
    __builtin_amdgcn_s_setprio(0);
    __builtin_amdgcn_s_barrier();
    // ---- phase 3: ks1, mi 4..7 ; stage B j2,j3 ; counted gate ----
#pragma unroll
    for (int mi = 0; mi < 4; mi++) afr[mi] = *(const f16x8*)&lds[abuf + aRow[mi + 4] + sx[1]];
    if (stB) {
      gll16(bS[2] + bAdd2, &lds[bnbuf + bD[2]]);
      gll16(bS[3] + bAdd2, &lds[bnbuf + bD[3]]);
    }
    __builtin_amdgcn_s_barrier();
    __builtin_amdgcn_s_setprio(1);
#pragma unroll
    for (int mi = 0; mi < 4; mi++)
#pragma unroll
      for (int ni = 0; ni < 4; ni++)
        acc[mi + 4][ni] = __builtin_amdgcn_mfma_f32_16x16x32_f16(afr[mi], bfr[ni], acc[mi + 4][ni], 0, 0, 0);
    __builtin_amdgcn_s_setprio(0);
    if (stB) {
      asm volatile("s_waitcnt vmcnt(4)" ::: "memory");
    } else if (stA) {
      asm volatile("s_waitcnt vmcnt(0)" ::: "memory");
    }
    __builtin_amdgcn_s_barrier();
    bc = bc + 1; if (bc >= 3) bc -= 3;
  }

#pragma unroll
  for (int mi = 0; mi < 8; mi++) {
#pragma unroll
    for (int ni = 0; ni < 4; ni++) {
      f32x4 v = acc[mi][ni];
      const int m0 = mtile * 256 + wm * 128 + mi * 16 + g * 4;
      const int n = ntile * 256 + wn * 64 + ni * 16 + l15;
      const int b = (n >= 15360) ? 1 : 0;
      const int rem = n - b * 15360;
#pragma unroll
      for (int r = 0; r < 4; r++) {
        const int m = m0 + r;
        out[(long)b * 7864320 + (long)m * 15360 + rem] = f2h(v[r] + bias[m]);
      }
    }
  }
}

// ---------- 128x128 NT GEMM (2-phase, general purpose) ----------
template <int BMODE, int EPI, int SPLITK>
__global__ __launch_bounds__(256, 2)
void gemm_nt(const u16* __restrict__ A, long Azoff, int Astride,
             const u16* __restrict__ B, long Bzoff, int Bstride,
             int K, float scale,
             const float* __restrict__ bias, const float* __restrict__ bias2,
             void* __restrict__ out0, void* __restrict__ out1,
             long out_zoff, int ldo) {
  __shared__ u16 lds[4 * 8192];
  const int tid = threadIdx.x;
  const int lane = tid & 63;
  const int wave = tid >> 6;
  const int mtile = blockIdx.y, ntile = blockIdx.x, z = blockIdx.z;

  const int zb = (SPLITK > 1) ? z / SPLITK : z;
  const int zc = (SPLITK > 1) ? z % SPLITK : 0;
  const u16* Ab = A + (long)zb * Azoff + (long)zc * K;
  const u16* Bb = B + (long)zb * Bzoff + ((BMODE == 0) ? (long)zc * K : 0);

  const int r8 = lane >> 3;
  const int sphys = lane & 7;
  const u16* aSrc[4];
  const u16* bSrc[4];
  u16* aDst[4];
  u16* bDst[4];
#pragma unroll
  for (int i = 0; i < 4; i++) {
    const int row = wave * 32 + i * 8 + r8;
    const int slog = sphys ^ (row & 7);
    aSrc[i] = Ab + (long)(mtile * 128 + row) * Astride + slog * 8;
    if (BMODE == 0) {
      bSrc[i] = Bb + (long)(ntile * 128 + row) * Bstride + slog * 8;
    } else {
      const int n = ntile * 128 + row;
      const int img = n >> 10;
      const int p = n & 1023;
      const int y = p >> 5, x = p & 31;
      bSrc[i] = Bb + ((long)(img * 34 + y) * 34 + x) * 1024 + slog * 8;
    }
    aDst[i] = &lds[0] + (wave * 32 + i * 8) * 64;
    bDst[i] = &lds[0] + 8192 + (wave * 32 + i * 8) * 64;
  }

  const int g = lane >> 4, l15 = lane & 15;
  const int wm = wave >> 1, wn = wave & 1;
  int offA[2][4], offB[2][4];
#pragma unroll
  for (int ks = 0; ks < 2; ks++) {
    const int sl = ks * 4 + g;
#pragma unroll
    for (int i = 0; i < 4; i++) {
      const int ra = wm * 64 + i * 16 + l15;
      offA[ks][i] = ra * 64 + ((sl ^ (ra & 7)) * 8);
      const int rb = wn * 64 + i * 16 + l15;
      offB[ks][i] = 8192 + rb * 64 + ((sl ^ (rb & 7)) * 8);
    }
  }

  auto stage = [&](int buf, int kb) {
    int bAdd;
    if (BMODE == 0) {
      bAdd = kb;
    } else if (BMODE == 1) {
      // channel-block-major, tap-minor decode on the GLOBAL k
      const int ktg = (zc * K + kb) >> 6;
      const int cblk = ktg / 9;
      const int t = ktg - cblk * 9;
      const int dy = t / 3, dx = t - dy * 3;
      bAdd = (dy * 34 + dx) * 1024 + cblk * 64;
    } else {
      bAdd = 35 * 1024 + kb;
    }
    const int bufo = buf * 16384;
#pragma unroll
    for (int i = 0; i < 4; i++) gll16(aSrc[i] + kb, aDst[i] + bufo);
#pragma unroll
    for (int i = 0; i < 4; i++) gll16(bSrc[i] + bAdd, bDst[i] + bufo);
  };

  f32x4 acc[4][4];
  const f32x4 zero = {0.f, 0.f, 0.f, 0.f};
#pragma unroll
  for (int i = 0; i < 4; i++)
#pragma unroll
    for (int j = 0; j < 4; j++) acc[i][j] = zero;

  const int nkt = K >> 6;
  stage(0, 0);
  __syncthreads();
  for (int kt = 0; kt < nkt; ++kt) {
    const int buf = kt & 1;
    if (kt + 1 < nkt) stage(buf ^ 1, (kt + 1) << 6);
#pragma unroll
    for (int ks = 0; ks < 2; ks++) {
      f16x8 af[4], bfg[4];
#pragma unroll
      for (int i = 0; i < 4; i++)
        af[i] = *(const f16x8*)&lds[buf * 16384 + offA[ks][i]];
#pragma unroll
      for (int i = 0; i < 4; i++)
        bfg[i] = *(const f16x8*)&lds[buf * 16384 + offB[ks][i]];
#pragma unroll
      for (int mi = 0; mi < 4; mi++)
#pragma unroll
        for (int ni = 0; ni < 4; ni++)
          acc[mi][ni] = __builtin_amdgcn_mfma_f32_16x16x32_f16(
              af[mi], bfg[ni], acc[mi][ni], 0, 0, 0);
    }
    __syncthreads();
  }

#pragma unroll
  for (int mi = 0; mi < 4; mi++) {
#pragma unroll
    for (int ni = 0; ni < 4; ni++) {
      f32x4 v = acc[mi][ni];
      const int m0 = mtile * 128 + wm * 64 + mi * 16 + g * 4;
      const int n = ntile * 128 + wn * 64 + ni * 16 + l15;
      if (EPI == 0) {
        u16* ob = (u16*)out0;
        const float* bs = bias;
        int mm = m0;
        if (out1 != nullptr && m0 >= 128) { ob = (u16*)out1; bs = bias2; mm = m0 - 128; }
        u16x4 pk;
#pragma unroll
        for (int r = 0; r < 4; r++) {
          float val = v[r] * scale + (bs ? bs[mm + r] : 0.f);
          pk[r] = f2h(val);
        }
        *(u16x4*)&ob[(long)n * ldo + mm] = pk;
      } else if (EPI == 1) {
        u16* ob = (u16*)out0 + (long)z * out_zoff;
#pragma unroll
        for (int r = 0; r < 4; r++) {
          const int m = m0 + r;
          float val = v[r] * scale + (bias ? bias[m] : 0.f);
          ob[(long)m * ldo + n] = f2h(val);
        }
      } else if (EPI == 2) {
        float* of = (float*)out0;
        const int img = n >> 10, p = n & 1023;
#pragma unroll
        for (int r = 0; r < 4; r++) {
          const int m = m0 + r;
          of[(long)img * 1048576 + (long)(512 + m) * 1024 + p] =
              v[r] + (bias ? bias[m] : 0.f);
        }
      } else if (EPI == 3) {
        float* of = (float*)out0;
        const int f = n >> 10, p = n & 1023;
#pragma unroll
        for (int r = 0; r < 4; r++) {
          const int m = m0 + r;
          of[(long)z * 5242880 + (long)f * 1048576 + (long)m * 1024 + p] = v[r];
        }
      } else if (EPI == 4) {
        float* of = (float*)out0 + (long)z * out_zoff;
#pragma unroll
        for (int r = 0; r < 4; r++) of[(long)(m0 + r) * ldo + n] = v[r];
      } else if (EPI == 5) {
        float* of = (float*)out0 + (long)zc * out_zoff;
        *(f32x4*)&of[(long)n * ldo + m0] = v;
      } else {  // EPI == 6: f16 partial row store
        u16* ob = (u16*)out0 + (long)z * out_zoff;
#pragma unroll
        for (int r = 0; r < 4; r++) ob[(long)(m0 + r) * ldo + n] = f2h(v[r]);
      }
    }
  }
}

// ---------- launch ----------
extern "C" void kernel_launch(void* const* d_in, const int* in_sizes, int n_in,
                              void* d_out, int out_size, void* d_ws, size_t ws_size,
                              hipStream_t stream) {
  (void)in_sizes; (void)n_in; (void)out_size;
  const float* query   = (const float*)d_in[0];
  const float* support = (const float*)d_in[1];
  const float* w_sk = (const float*)d_in[2];  const float* b_sk = (const float*)d_in[3];
  const float* w_sv = (const float*)d_in[4];  const float* b_sv = (const float*)d_in[5];
  const float* w_qq = (const float*)d_in[6];  const float* b_qq = (const float*)d_in[7];
  const float* w_qk = (const float*)d_in[8];  const float* b_qk = (const float*)d_in[9];
  const float* w_cq = (const float*)d_in[10]; const float* b_cq = (const float*)d_in[11];
  float* out = (float*)d_out;
  char* ws = (char*)d_ws;

  if (ws_size < 158924800u) return;

  u16* PQ    = (u16*)(ws + 0);
  u16* PS    = (u16*)(ws + 23674880);
  u16* WTSK  = (u16*)(ws + 94699520);
  u16* WTSV  = (u16*)(ws + 97058816);
  u16* WTQQK = (u16*)(ws + 106496000);
  u16* WCQ   = (u16*)(ws + 111214592);
  u16* SKR   = (u16*)(ws + 112263168);
  u16* SVA   = (u16*)(ws + 120127488);
  u16* QQR   = (u16*)(ws + 151584768);
  u16* QKR   = (u16*)(ws + 154206208);
  u16* NEWV  = (u16*)(ws + 156827648);
  u16* P1T   = PS;
  u16* P2T   = PQ;
  u16* PART2 = (u16*)(ws + 94699520);
  float* PARTK = (float*)SVA;
  float* PARTQ = (float*)SVA;

  const float SCALE = 0.08838834764831843f;  // 1/sqrt(128)

  pad_nhwc<<<dim3(320), 256, 0, stream>>>(query, PQ);
  pad_nhwc<<<dim3(960), 256, 0, stream>>>(support, PS);
  wprep<<<dim3(1408), 256, 0, stream>>>(w_sk, w_sv, w_qq, w_qk, w_cq,
                                        WTSK, WTSV, WTQQK, WCQ);

  // sk conv: split-K=2 -> fp32 partials, then reduce(+bias)
  gemm_nt<1, 5, 2><<<dim3(240, 1, 2), 256, 0, stream>>>(
      WTSK, 0, 9216, PS, 0, 0, 4608, 1.0f, nullptr, nullptr, PARTK, nullptr,
      3932160L, 128);
  reduce_sk<<<dim3(3840), 256, 0, stream>>>(PARTK, b_sk, SKR);

  // qq+qk conv: split-K=2 -> fp32 partials, then reduce(+bias)
  gemm_nt<1, 5, 2><<<dim3(80, 2, 2), 256, 0, stream>>>(
      WTQQK, 0, 9216, PQ, 0, 0, 4608, 1.0f, nullptr, nullptr, PARTQ, nullptr,
      2621440L, 256);
  reduce_qqk<<<dim3(2560), 256, 0, stream>>>(PARTQ, b_qq, b_qk, QQR, QKR);

  // sv conv
  gemm256<<<dim3(120, 2), 512, 0, stream>>>(WTSV, PS, b_sv, SVA);

  // qf 1x1 conv
  gemm_nt<2, 2, 1><<<dim3(80, 4, 1), 256, 0, stream>>>(
      WCQ, 0, 1024, PQ, 0, 0, 1024, 1.0f, b_cq, nullptr, out, nullptr, 0, 0);

  // stage 1
  gemm_nt<0, 1, 1><<<dim3(120, 8, 2), 256, 0, stream>>>(
      QQR + 262144, 655360L, 128, SKR, 1966080L, 128, 128, SCALE, nullptr,
      nullptr, P1T, nullptr, 15728640L, 15360);
  row_softmax60<<<dim3(2048), 256, 0, stream>>>(P1T);
  gemm_nt<0, 6, 8><<<dim3(8, 4, 16), 256, 0, stream>>>(
      SVA, 7864320L, 15360, P1T, 15728640L, 15360, 1920, 1.0f, nullptr,
      nullptr, PART2, nullptr, 524288L, 1024);
  reduce8h<<<dim3(1024), 256, 0, stream>>>(PART2, NEWV);

  // stage 2
  gemm_nt<0, 1, 1><<<dim3(8, 40, 2), 256, 0, stream>>>(
      QQR, 655360L, 128, QKR + 262144, 655360L, 128, 128, SCALE, nullptr,
      nullptr, P2T, nullptr, 5242880L, 1024);
  row_softmax4<<<dim3(10240), 256, 0, stream>>>(P2T);
  gemm_nt<0, 3, 1><<<dim3(40, 4, 2), 256, 0, stream>>>(
      NEWV, 524288L, 1024, P2T, 5242880L, 1024, 1024, 1.0f, nullptr, nullptr,
      out, nullptr, 0, 0);
}

// Round 8
// 659.578 us; speedup vs baseline: 1.3853x; 1.0139x over previous
//
#include <hip/hip_runtime.h>
#include <cstdint>

typedef unsigned short u16;
typedef __attribute__((ext_vector_type(8))) u16 u16x8;
typedef __attribute__((ext_vector_type(4))) u16 u16x4;
typedef __attribute__((ext_vector_type(8))) _Float16 f16x8;
typedef __attribute__((ext_vector_type(4))) float f32x4;

// ---------- helpers ----------
__device__ __forceinline__ u16 f2h(float f) {
  _Float16 h = (_Float16)f;
  return __builtin_bit_cast(u16, h);
}
__device__ __forceinline__ float h2f(u16 b) {
  _Float16 h = __builtin_bit_cast(_Float16, b);
  return (float)h;
}
__device__ __forceinline__ void gll16(const void* g, void* l) {
  auto gp = reinterpret_cast<const __attribute__((address_space(1))) unsigned int*>(
      reinterpret_cast<uintptr_t>(g));
  auto lp = reinterpret_cast<__attribute__((address_space(3))) unsigned int*>(
      reinterpret_cast<uintptr_t>(l));
  __builtin_amdgcn_global_load_lds(gp, lp, 16, 0, 0);
}

// ---------- prep: NCHW fp32 -> padded(34x34) NHWC fp16, halo fused ----------
__global__ __launch_bounds__(256) void pad_nhwc(const float* __restrict__ in,
                                                u16* __restrict__ outp) {
  const int img = blockIdx.x >> 5;
  const int y   = blockIdx.x & 31;
  __shared__ float tile[32][33];
  const int tid = threadIdx.x;
  u16* base = outp + (long)img * 34 * 34 * 1024;
  const u16x8 z8 = {0, 0, 0, 0, 0, 0, 0, 0};
  {
    u16* r = base + (long)(y + 1) * 34 * 1024;
    if (tid < 128) *(u16x8*)&r[tid * 8] = z8;
    else *(u16x8*)&r[33 * 1024 + (tid - 128) * 8] = z8;
  }
  if (y == 0) {
    for (int i = tid * 8; i < 34816; i += 2048) *(u16x8*)&base[i] = z8;
  }
  if (y == 31) {
    u16* r = base + 33L * 34 * 1024;
    for (int i = tid * 8; i < 34816; i += 2048) *(u16x8*)&r[i] = z8;
  }
  const int xi = tid & 31, ci = tid >> 5;
  const int xo = tid >> 3, q = tid & 7;
  const float* ip = in + (long)img * 1048576 + y * 32;
  u16* op = base + ((long)(y + 1) * 34 + 1) * 1024;
  for (int c0 = 0; c0 < 1024; c0 += 32) {
#pragma unroll
    for (int k2 = 0; k2 < 4; k2++)
      tile[k2 * 8 + ci][xi] = ip[(long)(c0 + k2 * 8 + ci) * 1024 + xi];
    __syncthreads();
    u16x4 o4;
#pragma unroll
    for (int r = 0; r < 4; r++) o4[r] = f2h(tile[q * 4 + r][xo]);
    *(u16x4*)&op[(long)xo * 1024 + c0 + q * 4] = o4;
    __syncthreads();
  }
}

// ---------- merged weight prep ----------
// 3x3 weights in CHANNEL-BLOCK-MAJOR, TAP-MINOR k-order:
//   k = cblk*576 + tap*64 + ci   (cblk = c>>6, ci = c&63)
__device__ __forceinline__ void wre3_body(const float* __restrict__ wp,
                                          u16* __restrict__ op, float* buf) {
  for (int i = threadIdx.x; i < 9216; i += 256) buf[i] = wp[i];
  __syncthreads();
  for (int k = threadIdx.x; k < 9216; k += 256) {
    const int cblk = k / 576;
    const int r = k - cblk * 576;
    const int t = r >> 6, ci = r & 63;
    op[k] = f2h(buf[(cblk * 64 + ci) * 9 + t]);
  }
}
__global__ __launch_bounds__(256) void wprep(
    const float* __restrict__ w_sk, const float* __restrict__ w_sv,
    const float* __restrict__ w_qq, const float* __restrict__ w_qk,
    const float* __restrict__ w_cq, u16* __restrict__ WTSK,
    u16* __restrict__ WTSV, u16* __restrict__ WTQQK, u16* __restrict__ WCQ) {
  __shared__ float buf[9216];
  const int b = blockIdx.x;
  if (b < 128) {
    wre3_body(w_sk + (long)b * 9216, WTSK + (long)b * 9216, buf);
  } else if (b < 640) {
    const int oc = b - 128;
    wre3_body(w_sv + (long)oc * 9216, WTSV + (long)oc * 9216, buf);
  } else if (b < 768) {
    const int oc = b - 640;
    wre3_body(w_qq + (long)oc * 9216, WTQQK + (long)oc * 9216, buf);
  } else if (b < 896) {
    const int oc = b - 768;
    wre3_body(w_qk + (long)oc * 9216, WTQQK + (long)(oc + 128) * 9216, buf);
  } else {
    const int i = (b - 896) * 1024 + threadIdx.x * 4;
#pragma unroll
    for (int r = 0; r < 4; r++) WCQ[i + r] = f2h(w_cq[i + r]);
  }
}

// ---------- one-pass register softmax, L=15360 ----------
__global__ __launch_bounds__(256) void row_softmax60(u16* __restrict__ P) {
  u16* p = P + (long)blockIdx.x * 15360;
  const int tid = threadIdx.x;
  __shared__ float rm[4], rs[4];
  u16x4 v[15];
#pragma unroll
  for (int j = 0; j < 15; j++)
    v[j] = *(const u16x4*)(p + ((tid + (j << 8)) << 2));
  float m = -3.0e38f;
#pragma unroll
  for (int j = 0; j < 15; j++)
#pragma unroll
    for (int e = 0; e < 4; e++) m = fmaxf(m, h2f(v[j][e]));
#pragma unroll
  for (int o = 32; o > 0; o >>= 1) m = fmaxf(m, __shfl_xor(m, o, 64));
  if ((tid & 63) == 0) rm[tid >> 6] = m;
  __syncthreads();
  const float M = fmaxf(fmaxf(rm[0], rm[1]), fmaxf(rm[2], rm[3]));
  float s = 0.f;
#pragma unroll
  for (int j = 0; j < 15; j++)
#pragma unroll
    for (int e = 0; e < 4; e++) s += __expf(h2f(v[j][e]) - M);
#pragma unroll
  for (int o = 32; o > 0; o >>= 1) s += __shfl_xor(s, o, 64);
  if ((tid & 63) == 0) rs[tid >> 6] = s;
  __syncthreads();
  const float inv = 1.0f / (rs[0] + rs[1] + rs[2] + rs[3]);
#pragma unroll
  for (int j = 0; j < 15; j++) {
    u16x4 o4;
#pragma unroll
    for (int e = 0; e < 4; e++) o4[e] = f2h(__expf(h2f(v[j][e]) - M) * inv);
    *(u16x4*)(p + ((tid + (j << 8)) << 2)) = o4;
  }
}

// ---------- one-pass register softmax, L=1024 ----------
__global__ __launch_bounds__(256) void row_softmax4(u16* __restrict__ P) {
  u16* p = P + (long)blockIdx.x * 1024;
  const int tid = threadIdx.x;
  __shared__ float rm[4], rs[4];
  u16x4 v = *(const u16x4*)(p + (tid << 2));
  float m = fmaxf(fmaxf(h2f(v[0]), h2f(v[1])), fmaxf(h2f(v[2]), h2f(v[3])));
#pragma unroll
  for (int o = 32; o > 0; o >>= 1) m = fmaxf(m, __shfl_xor(m, o, 64));
  if ((tid & 63) == 0) rm[tid >> 6] = m;
  __syncthreads();
  const float M = fmaxf(fmaxf(rm[0], rm[1]), fmaxf(rm[2], rm[3]));
  float s = 0.f;
#pragma unroll
  for (int e = 0; e < 4; e++) s += __expf(h2f(v[e]) - M);
#pragma unroll
  for (int o = 32; o > 0; o >>= 1) s += __shfl_xor(s, o, 64);
  if ((tid & 63) == 0) rs[tid >> 6] = s;
  __syncthreads();
  const float inv = 1.0f / (rs[0] + rs[1] + rs[2] + rs[3]);
  u16x4 o4;
#pragma unroll
  for (int e = 0; e < 4; e++) o4[e] = f2h(__expf(h2f(v[e]) - M) * inv);
  *(u16x4*)(p + (tid << 2)) = o4;
}

// ---------- split-K reducers ----------
__global__ __launch_bounds__(256) void reduce8h(const u16* __restrict__ part,
                                                u16* __restrict__ o) {
  long j = ((long)blockIdx.x * 256 + threadIdx.x) * 4;
  int b = (int)(j >> 19);
  long i = j & 524287;
  const u16* p = part + (long)b * 4194304 + i;
  float s0 = 0.f, s1 = 0.f, s2 = 0.f, s3 = 0.f;
#pragma unroll
  for (int c = 0; c < 8; c++) {
    u16x4 v = *(const u16x4*)&p[(long)c * 524288];
    s0 += h2f(v[0]); s1 += h2f(v[1]); s2 += h2f(v[2]); s3 += h2f(v[3]);
  }
  u16x4 o4 = {f2h(s0), f2h(s1), f2h(s2), f2h(s3)};
  *(u16x4*)&o[j] = o4;
}
__global__ __launch_bounds__(256) void reduce_sk(const float* __restrict__ part,
                                                 const float* __restrict__ bias,
                                                 u16* __restrict__ o) {
  long i = ((long)blockIdx.x * 256 + threadIdx.x) * 4;
  f32x4 s = *(const f32x4*)&part[i];
  s = s + *(const f32x4*)&part[i + 3932160];
  f32x4 bb = *(const f32x4*)&bias[(int)(i & 127)];
  u16x4 o4;
#pragma unroll
  for (int r = 0; r < 4; r++) o4[r] = f2h(s[r] + bb[r]);
  *(u16x4*)&o[i] = o4;
}
__global__ __launch_bounds__(256) void reduce_qqk(
    const float* __restrict__ part, const float* __restrict__ b_qq,
    const float* __restrict__ b_qk, u16* __restrict__ QQR,
    u16* __restrict__ QKR) {
  long i = ((long)blockIdx.x * 256 + threadIdx.x) * 4;
  const int n = (int)(i >> 8), m = (int)(i & 255);
  f32x4 s = *(const f32x4*)&part[i];
  s = s + *(const f32x4*)&part[i + 2621440];
  const int lo = (m < 128);
  const int mm = m & 127;
  const float* bs = lo ? b_qq : b_qk;
  f32x4 bb = *(const f32x4*)&bs[mm];
  u16* dst = (lo ? QQR : QKR) + (long)n * 128 + mm;
  u16x4 o4;
#pragma unroll
  for (int r = 0; r < 4; r++) o4[r] = f2h(s[r] + bb[r]);
  *(u16x4*)dst = o4;
}

// ---------- 256x256 GEMM, barrier-free K-tile interior ----------
// Frag loads pipelined in-register (a0/a1/a3/b0/b2); last MFMA quadrant of
// each tile deferred past the tile barrier so the next tile's ds_read flood
// drains under matrix work. One vmcnt(4)+barrier per K-tile (slab ring).
__global__ __launch_bounds__(512, 2)
void gemm256(const u16* __restrict__ A, const u16* __restrict__ B,
             const float* __restrict__ bias, u16* __restrict__ out) {
  __shared__ u16 lds[81920];  // A: 2x32KB @0, B: 3x32KB @32768(u16)
  const int tid = threadIdx.x, lane = tid & 63, wave = tid >> 6;
  const int nwg = gridDim.x * gridDim.y;
  int wg = blockIdx.x + gridDim.x * blockIdx.y;
  wg = (wg & 7) * (nwg >> 3) + (wg >> 3);
  const int ntile = wg % gridDim.x;
  const int mtile = wg / gridDim.x;

  const int slog = (lane & 7) ^ ((lane >> 3) & 7);
  const u16* aS[4];
  const u16* bS[4];
  int aD[4], bD[4];
#pragma unroll
  for (int j = 0; j < 4; j++) {
    const int r = wave * 32 + j * 8 + (lane >> 3);
    aS[j] = A + (long)(mtile * 256 + r) * 9216 + slog * 8;
    aD[j] = (wave * 32 + j * 8) * 64;
    const int n = ntile * 256 + r;
    const int img = n >> 10, p = n & 1023;
    const int y = p >> 5, x = p & 31;
    bS[j] = B + ((long)((img * 34 + y) * 34 + x)) * 1024 + slog * 8;
    bD[j] = (wave * 32 + j * 8) * 64;
  }

  const int g = lane >> 4, l15 = lane & 15;
  const int wm = wave >> 2, wn = wave & 3;
  int aRow[8], bRow[4], sx[2];
#pragma unroll
  for (int mi = 0; mi < 8; mi++) aRow[mi] = (wm * 128 + mi * 16 + l15) * 64;
#pragma unroll
  for (int ni = 0; ni < 4; ni++) bRow[ni] = (wn * 64 + ni * 16 + l15) * 64;
#pragma unroll
  for (int ks = 0; ks < 2; ks++) sx[ks] = ((ks * 4 + g) ^ (l15 & 7)) * 8;

  auto conv_badd = [](int kt) {
    const int cblk = kt / 9;
    const int t = kt - cblk * 9;
    const int dy = t / 3, dx = t - dy * 3;
    return (dy * 34 + dx) * 1024 + cblk * 64;
  };

  f32x4 acc[8][4];
  const f32x4 zero = {0.f, 0.f, 0.f, 0.f};
#pragma unroll
  for (int i = 0; i < 8; i++)
#pragma unroll
    for (int j = 0; j < 4; j++) acc[i][j] = zero;

  const int nkt = 144;
  // prologue: A(0)->abuf0, B(0)->slab0, B(1)->slab1
  {
#pragma unroll
    for (int j = 0; j < 4; j++) gll16(aS[j], &lds[aD[j]]);
    const int b0o = conv_badd(0), b1o = conv_badd(1);
#pragma unroll
    for (int j = 0; j < 4; j++) gll16(bS[j] + b0o, &lds[32768 + bD[j]]);
#pragma unroll
    for (int j = 0; j < 4; j++) gll16(bS[j] + b1o, &lds[49152 + bD[j]]);
    asm volatile("s_waitcnt vmcnt(4)" ::: "memory");
    __builtin_amdgcn_s_barrier();
  }

  // pipelined fragment registers (a3/b2 carry the deferred quadrant)
  f16x8 a0[4], a1[4], a3[4], b0[4], b2[4];
  f16x8 zf;
#pragma unroll
  for (int j = 0; j < 8; j++) zf[j] = (_Float16)0.0f;
#pragma unroll
  for (int i = 0; i < 4; i++) { a3[i] = zf; b2[i] = zf; }

  int bc = 0;
  for (int kt = 0; kt < nkt; ++kt) {
    const int abuf = (kt & 1) << 14;
    const int anbuf = abuf ^ 16384;
    const int bbuf = 32768 + bc * 16384;
    int bsn = bc + 2; if (bsn >= 3) bsn -= 3;
    const int bnbuf = 32768 + bsn * 16384;
    const bool stA = (kt + 1 < nkt);
    const bool stB = (kt + 2 < nkt);
    const int kA = (kt + 1) << 6;
    const int bAdd2 = stB ? conv_badd(kt + 2) : 0;

    // L0: ks0 fragments (12 ds_read_b128)
#pragma unroll
    for (int i = 0; i < 4; i++) a0[i] = *(const f16x8*)&lds[abuf + aRow[i] + sx[0]];
#pragma unroll
    for (int i = 0; i < 4; i++) b0[i] = *(const f16x8*)&lds[bbuf + bRow[i] + sx[0]];
#pragma unroll
    for (int i = 0; i < 4; i++) a1[i] = *(const f16x8*)&lds[abuf + aRow[i + 4] + sx[0]];
    // deferred ph3 of previous tile (zeros on kt==0)
#pragma unroll
    for (int mi = 0; mi < 4; mi++)
#pragma unroll
      for (int ni = 0; ni < 4; ni++)
        acc[mi + 4][ni] = __builtin_amdgcn_mfma_f32_16x16x32_f16(
            a3[mi], b2[ni], acc[mi + 4][ni], 0, 0, 0);
    if (stA) {
#pragma unroll
      for (int j = 0; j < 4; j++) gll16(aS[j] + kA, &lds[anbuf + aD[j]]);
    }
    // ph0
#pragma unroll
    for (int mi = 0; mi < 4; mi++)
#pragma unroll
      for (int ni = 0; ni < 4; ni++)
        acc[mi][ni] = __builtin_amdgcn_mfma_f32_16x16x32_f16(
            a0[mi], b0[ni], acc[mi][ni], 0, 0, 0);
    // L1: ks1 rows 0-3 (reuse a0) + B ks1
#pragma unroll
    for (int i = 0; i < 4; i++) a0[i] = *(const f16x8*)&lds[abuf + aRow[i] + sx[1]];
#pragma unroll
    for (int i = 0; i < 4; i++) b2[i] = *(const f16x8*)&lds[bbuf + bRow[i] + sx[1]];
    if (stB) {
#pragma unroll
      for (int j = 0; j < 4; j++) gll16(bS[j] + bAdd2, &lds[bnbuf + bD[j]]);
    }
    // ph1
#pragma unroll
    for (int mi = 0; mi < 4; mi++)
#pragma unroll
      for (int ni = 0; ni < 4; ni++)
        acc[mi + 4][ni] = __builtin_amdgcn_mfma_f32_16x16x32_f16(
            a1[mi], b0[ni], acc[mi + 4][ni], 0, 0, 0);
    // L2: ks1 rows 4-7 (feeds deferred ph3 next tile)
#pragma unroll
    for (int i = 0; i < 4; i++) a3[i] = *(const f16x8*)&lds[abuf + aRow[i + 4] + sx[1]];
    // ph2
#pragma unroll
    for (int mi = 0; mi < 4; mi++)
#pragma unroll
      for (int ni = 0; ni < 4; ni++)
        acc[mi][ni] = __builtin_amdgcn_mfma_f32_16x16x32_f16(
            a0[mi], b2[ni], acc[mi][ni], 0, 0, 0);
    // tile gate: counted, never drains the dist-2 B prefetch
    if (stB) {
      asm volatile("s_waitcnt vmcnt(4)" ::: "memory");
    } else if (stA) {
      asm volatile("s_waitcnt vmcnt(0)" ::: "memory");
    }
    __builtin_amdgcn_s_barrier();
    bc = bc + 1; if (bc >= 3) bc -= 3;
  }
  // final deferred ph3
#pragma unroll
  for (int mi = 0; mi < 4; mi++)
#pragma unroll
    for (int ni = 0; ni < 4; ni++)
      acc[mi + 4][ni] = __builtin_amdgcn_mfma_f32_16x16x32_f16(
          a3[mi], b2[ni], acc[mi + 4][ni], 0, 0, 0);

  // ---- epilogue: SVA[b][m][col] = acc + bias[m] ----
#pragma unroll
  for (int mi = 0; mi < 8; mi++) {
#pragma unroll
    for (int ni = 0; ni < 4; ni++) {
      f32x4 v = acc[mi][ni];
      const int m0 = mtile * 256 + wm * 128 + mi * 16 + g * 4;
      const int n = ntile * 256 + wn * 64 + ni * 16 + l15;
      const int b = (n >= 15360) ? 1 : 0;
      const int rem = n - b * 15360;
#pragma unroll
      for (int r = 0; r < 4; r++) {
        const int m = m0 + r;
        out[(long)b * 7864320 + (long)m * 15360 + rem] = f2h(v[r] + bias[m]);
      }
    }
  }
}

// ---------- 128x128 NT GEMM (2-phase, general purpose) ----------
template <int BMODE, int EPI, int SPLITK>
__global__ __launch_bounds__(256, 2)
void gemm_nt(const u16* __restrict__ A, long Azoff, int Astride,
             const u16* __restrict__ B, long Bzoff, int Bstride,
             int K, float scale,
             const float* __restrict__ bias, const float* __restrict__ bias2,
             void* __restrict__ out0, void* __restrict__ out1,
             long out_zoff, int ldo) {
  __shared__ u16 lds[4 * 8192];
  const int tid = threadIdx.x;
  const int lane = tid & 63;
  const int wave = tid >> 6;
  const int mtile = blockIdx.y, ntile = blockIdx.x, z = blockIdx.z;

  const int zb = (SPLITK > 1) ? z / SPLITK : z;
  const int zc = (SPLITK > 1) ? z % SPLITK : 0;
  const u16* Ab = A + (long)zb * Azoff + (long)zc * K;
  const u16* Bb = B + (long)zb * Bzoff + ((BMODE == 0) ? (long)zc * K : 0);

  const int r8 = lane >> 3;
  const int sphys = lane & 7;
  const u16* aSrc[4];
  const u16* bSrc[4];
  u16* aDst[4];
  u16* bDst[4];
#pragma unroll
  for (int i = 0; i < 4; i++) {
    const int row = wave * 32 + i * 8 + r8;
    const int slog = sphys ^ (row & 7);
    aSrc[i] = Ab + (long)(mtile * 128 + row) * Astride + slog * 8;
    if (BMODE == 0) {
      bSrc[i] = Bb + (long)(ntile * 128 + row) * Bstride + slog * 8;
    } else {
      const int n = ntile * 128 + row;
      const int img = n >> 10;
      const int p = n & 1023;
      const int y = p >> 5, x = p & 31;
      bSrc[i] = Bb + ((long)(img * 34 + y) * 34 + x) * 1024 + slog * 8;
    }
    aDst[i] = &lds[0] + (wave * 32 + i * 8) * 64;
    bDst[i] = &lds[0] + 8192 + (wave * 32 + i * 8) * 64;
  }

  const int g = lane >> 4, l15 = lane & 15;
  const int wm = wave >> 1, wn = wave & 1;
  int offA[2][4], offB[2][4];
#pragma unroll
  for (int ks = 0; ks < 2; ks++) {
    const int sl = ks * 4 + g;
#pragma unroll
    for (int i = 0; i < 4; i++) {
      const int ra = wm * 64 + i * 16 + l15;
      offA[ks][i] = ra * 64 + ((sl ^ (ra & 7)) * 8);
      const int rb = wn * 64 + i * 16 + l15;
      offB[ks][i] = 8192 + rb * 64 + ((sl ^ (rb & 7)) * 8);
    }
  }

  auto stage = [&](int buf, int kb) {
    int bAdd;
    if (BMODE == 0) {
      bAdd = kb;
    } else if (BMODE == 1) {
      const int ktg = (zc * K + kb) >> 6;
      const int cblk = ktg / 9;
      const int t = ktg - cblk * 9;
      const int dy = t / 3, dx = t - dy * 3;
      bAdd = (dy * 34 + dx) * 1024 + cblk * 64;
    } else {
      bAdd = 35 * 1024 + kb;
    }
    const int bufo = buf * 16384;
#pragma unroll
    for (int i = 0; i < 4; i++) gll16(aSrc[i] + kb, aDst[i] + bufo);
#pragma unroll
    for (int i = 0; i < 4; i++) gll16(bSrc[i] + bAdd, bDst[i] + bufo);
  };

  f32x4 acc[4][4];
  const f32x4 zero = {0.f, 0.f, 0.f, 0.f};
#pragma unroll
  for (int i = 0; i < 4; i++)
#pragma unroll
    for (int j = 0; j < 4; j++) acc[i][j] = zero;

  const int nkt = K >> 6;
  stage(0, 0);
  __syncthreads();
  for (int kt = 0; kt < nkt; ++kt) {
    const int buf = kt & 1;
    if (kt + 1 < nkt) stage(buf ^ 1, (kt + 1) << 6);
#pragma unroll
    for (int ks = 0; ks < 2; ks++) {
      f16x8 af[4], bfg[4];
#pragma unroll
      for (int i = 0; i < 4; i++)
        af[i] = *(const f16x8*)&lds[buf * 16384 + offA[ks][i]];
#pragma unroll
      for (int i = 0; i < 4; i++)
        bfg[i] = *(const f16x8*)&lds[buf * 16384 + offB[ks][i]];
#pragma unroll
      for (int mi = 0; mi < 4; mi++)
#pragma unroll
        for (int ni = 0; ni < 4; ni++)
          acc[mi][ni] = __builtin_amdgcn_mfma_f32_16x16x32_f16(
              af[mi], bfg[ni], acc[mi][ni], 0, 0, 0);
    }
    __syncthreads();
  }

#pragma unroll
  for (int mi = 0; mi < 4; mi++) {
#pragma unroll
    for (int ni = 0; ni < 4; ni++) {
      f32x4 v = acc[mi][ni];
      const int m0 = mtile * 128 + wm * 64 + mi * 16 + g * 4;
      const int n = ntile * 128 + wn * 64 + ni * 16 + l15;
      if (EPI == 0) {
        u16* ob = (u16*)out0;
        const float* bs = bias;
        int mm = m0;
        if (out1 != nullptr && m0 >= 128) { ob = (u16*)out1; bs = bias2; mm = m0 - 128; }
        u16x4 pk;
#pragma unroll
        for (int r = 0; r < 4; r++) {
          float val = v[r] * scale + (bs ? bs[mm + r] : 0.f);
          pk[r] = f2h(val);
        }
        *(u16x4*)&ob[(long)n * ldo + mm] = pk;
      } else if (EPI == 1) {
        u16* ob = (u16*)out0 + (long)z * out_zoff;
#pragma unroll
        for (int r = 0; r < 4; r++) {
          const int m = m0 + r;
          float val = v[r] * scale + (bias ? bias[m] : 0.f);
          ob[(long)m * ldo + n] = f2h(val);
        }
      } else if (EPI == 2) {
        float* of = (float*)out0;
        const int img = n >> 10, p = n & 1023;
#pragma unroll
        for (int r = 0; r < 4; r++) {
          const int m = m0 + r;
          of[(long)img * 1048576 + (long)(512 + m) * 1024 + p] =
              v[r] + (bias ? bias[m] : 0.f);
        }
      } else if (EPI == 3) {
        float* of = (float*)out0;
        const int f = n >> 10, p = n & 1023;
#pragma unroll
        for (int r = 0; r < 4; r++) {
          const int m = m0 + r;
          of[(long)z * 5242880 + (long)f * 1048576 + (long)m * 1024 + p] = v[r];
        }
      } else if (EPI == 4) {
        float* of = (float*)out0 + (long)z * out_zoff;
#pragma unroll
        for (int r = 0; r < 4; r++) of[(long)(m0 + r) * ldo + n] = v[r];
      } else if (EPI == 5) {
        float* of = (float*)out0 + (long)zc * out_zoff;
        *(f32x4*)&of[(long)n * ldo + m0] = v;
      } else {  // EPI == 6: f16 partial row store
        u16* ob = (u16*)out0 + (long)z * out_zoff;
#pragma unroll
        for (int r = 0; r < 4; r++) ob[(long)(m0 + r) * ldo + n] = f2h(v[r]);
      }
    }
  }
}

// ---------- launch ----------
extern "C" void kernel_launch(void* const* d_in, const int* in_sizes, int n_in,
                              void* d_out, int out_size, void* d_ws, size_t ws_size,
                              hipStream_t stream) {
  (void)in_sizes; (void)n_in; (void)out_size;
  const float* query   = (const float*)d_in[0];
  const float* support = (const float*)d_in[1];
  const float* w_sk = (const float*)d_in[2];  const float* b_sk = (const float*)d_in[3];
  const float* w_sv = (const float*)d_in[4];  const float* b_sv = (const float*)d_in[5];
  const float* w_qq = (const float*)d_in[6];  const float* b_qq = (const float*)d_in[7];
  const float* w_qk = (const float*)d_in[8];  const float* b_qk = (const float*)d_in[9];
  const float* w_cq = (const float*)d_in[10]; const float* b_cq = (const float*)d_in[11];
  float* out = (float*)d_out;
  char* ws = (char*)d_ws;

  if (ws_size < 158924800u) return;

  u16* PQ    = (u16*)(ws + 0);
  u16* PS    = (u16*)(ws + 23674880);
  u16* WTSK  = (u16*)(ws + 94699520);
  u16* WTSV  = (u16*)(ws + 97058816);
  u16* WTQQK = (u16*)(ws + 106496000);
  u16* WCQ   = (u16*)(ws + 111214592);
  u16* SKR   = (u16*)(ws + 112263168);
  u16* SVA   = (u16*)(ws + 120127488);
  u16* QQR   = (u16*)(ws + 151584768);
  u16* QKR   = (u16*)(ws + 154206208);
  u16* NEWV  = (u16*)(ws + 156827648);
  u16* P1T   = PS;
  u16* P2T   = PQ;
  u16* PART2 = (u16*)(ws + 94699520);
  float* PARTK = (float*)SVA;
  float* PARTQ = (float*)SVA;

  const float SCALE = 0.08838834764831843f;  // 1/sqrt(128)

  pad_nhwc<<<dim3(320), 256, 0, stream>>>(query, PQ);
  pad_nhwc<<<dim3(960), 256, 0, stream>>>(support, PS);
  wprep<<<dim3(1408), 256, 0, stream>>>(w_sk, w_sv, w_qq, w_qk, w_cq,
                                        WTSK, WTSV, WTQQK, WCQ);

  // sk conv: split-K=2 -> fp32 partials, then reduce(+bias)
  gemm_nt<1, 5, 2><<<dim3(240, 1, 2), 256, 0, stream>>>(
      WTSK, 0, 9216, PS, 0, 0, 4608, 1.0f, nullptr, nullptr, PARTK, nullptr,
      3932160L, 128);
  reduce_sk<<<dim3(3840), 256, 0, stream>>>(PARTK, b_sk, SKR);

  // qq+qk conv: split-K=2 -> fp32 partials, then reduce(+bias)
  gemm_nt<1, 5, 2><<<dim3(80, 2, 2), 256, 0, stream>>>(
      WTQQK, 0, 9216, PQ, 0, 0, 4608, 1.0f, nullptr, nullptr, PARTQ, nullptr,
      2621440L, 256);
  reduce_qqk<<<dim3(2560), 256, 0, stream>>>(PARTQ, b_qq, b_qk, QQR, QKR);

  // sv conv
  gemm256<<<dim3(120, 2), 512, 0, stream>>>(WTSV, PS, b_sv, SVA);

  // qf 1x1 conv
  gemm_nt<2, 2, 1><<<dim3(80, 4, 1), 256, 0, stream>>>(
      WCQ, 0, 1024, PQ, 0, 0, 1024, 1.0f, b_cq, nullptr, out, nullptr, 0, 0);

  // stage 1
  gemm_nt<0, 1, 1><<<dim3(120, 8, 2), 256, 0, stream>>>(
      QQR + 262144, 655360L, 128, SKR, 1966080L, 128, 128, SCALE, nullptr,
      nullptr, P1T, nullptr, 15728640L, 15360);
  row_softmax60<<<dim3(2048), 256, 0, stream>>>(P1T);
  gemm_nt<0, 6, 8><<<dim3(8, 4, 16), 256, 0, stream>>>(
      SVA, 7864320L, 15360, P1T, 15728640L, 15360, 1920, 1.0f, nullptr,
      nullptr, PART2, nullptr, 524288L, 1024);
  reduce8h<<<dim3(1024), 256, 0, stream>>>(PART2, NEWV);

  // stage 2
  gemm_nt<0, 1, 1><<<dim3(8, 40, 2), 256, 0, stream>>>(
      QQR, 655360L, 128, QKR + 262144, 655360L, 128, 128, SCALE, nullptr,
      nullptr, P2T, nullptr, 5242880L, 1024);
  row_softmax4<<<dim3(10240), 256, 0, stream>>>(P2T);
  gemm_nt<0, 3, 1><<<dim3(40, 4, 2), 256, 0, stream>>>(
      NEWV, 524288L, 1024, P2T, 5242880L, 1024, 1024, 1.0f, nullptr, nullptr,
      out, nullptr, 0, 0);
}

// Round 9
// 657.945 us; speedup vs baseline: 1.3887x; 1.0025x over previous
//
#include <hip/hip_runtime.h>
#include <cstdint>

typedef unsigned short u16;
typedef __attribute__((ext_vector_type(8))) u16 u16x8;
typedef __attribute__((ext_vector_type(4))) u16 u16x4;
typedef __attribute__((ext_vector_type(8))) _Float16 f16x8;
typedef __attribute__((ext_vector_type(4))) float f32x4;

// ---------- helpers ----------
__device__ __forceinline__ u16 f2h(float f) {
  _Float16 h = (_Float16)f;
  return __builtin_bit_cast(u16, h);
}
__device__ __forceinline__ float h2f(u16 b) {
  _Float16 h = __builtin_bit_cast(_Float16, b);
  return (float)h;
}
__device__ __forceinline__ void gll16(const void* g, void* l) {
  auto gp = reinterpret_cast<const __attribute__((address_space(1))) unsigned int*>(
      reinterpret_cast<uintptr_t>(g));
  auto lp = reinterpret_cast<__attribute__((address_space(3))) unsigned int*>(
      reinterpret_cast<uintptr_t>(l));
  __builtin_amdgcn_global_load_lds(gp, lp, 16, 0, 0);
}

// ---------- prep: NCHW fp32 -> padded(34x34) NHWC fp16, halo fused ----------
__global__ __launch_bounds__(256) void pad_nhwc(const float* __restrict__ in,
                                                u16* __restrict__ outp) {
  const int img = blockIdx.x >> 5;
  const int y   = blockIdx.x & 31;
  __shared__ float tile[32][33];
  const int tid = threadIdx.x;
  u16* base = outp + (long)img * 34 * 34 * 1024;
  const u16x8 z8 = {0, 0, 0, 0, 0, 0, 0, 0};
  {
    u16* r = base + (long)(y + 1) * 34 * 1024;
    if (tid < 128) *(u16x8*)&r[tid * 8] = z8;
    else *(u16x8*)&r[33 * 1024 + (tid - 128) * 8] = z8;
  }
  if (y == 0) {
    for (int i = tid * 8; i < 34816; i += 2048) *(u16x8*)&base[i] = z8;
  }
  if (y == 31) {
    u16* r = base + 33L * 34 * 1024;
    for (int i = tid * 8; i < 34816; i += 2048) *(u16x8*)&r[i] = z8;
  }
  const int xi = tid & 31, ci = tid >> 5;
  const int xo = tid >> 3, q = tid & 7;
  const float* ip = in + (long)img * 1048576 + y * 32;
  u16* op = base + ((long)(y + 1) * 34 + 1) * 1024;
  for (int c0 = 0; c0 < 1024; c0 += 32) {
#pragma unroll
    for (int k2 = 0; k2 < 4; k2++)
      tile[k2 * 8 + ci][xi] = ip[(long)(c0 + k2 * 8 + ci) * 1024 + xi];
    __syncthreads();
    u16x4 o4;
#pragma unroll
    for (int r = 0; r < 4; r++) o4[r] = f2h(tile[q * 4 + r][xo]);
    *(u16x4*)&op[(long)xo * 1024 + c0 + q * 4] = o4;
    __syncthreads();
  }
}

// ---------- merged weight prep ----------
// 3x3 weights in CHANNEL-BLOCK-MAJOR, TAP-MINOR k-order:
//   k = cblk*576 + tap*64 + ci   (cblk = c>>6, ci = c&63)
__device__ __forceinline__ void wre3_body(const float* __restrict__ wp,
                                          u16* __restrict__ op, float* buf) {
  for (int i = threadIdx.x; i < 9216; i += 256) buf[i] = wp[i];
  __syncthreads();
  for (int k = threadIdx.x; k < 9216; k += 256) {
    const int cblk = k / 576;
    const int r = k - cblk * 576;
    const int t = r >> 6, ci = r & 63;
    op[k] = f2h(buf[(cblk * 64 + ci) * 9 + t]);
  }
}
__global__ __launch_bounds__(256) void wprep(
    const float* __restrict__ w_sk, const float* __restrict__ w_sv,
    const float* __restrict__ w_qq, const float* __restrict__ w_qk,
    const float* __restrict__ w_cq, u16* __restrict__ WTSK,
    u16* __restrict__ WTSV, u16* __restrict__ WTQQK, u16* __restrict__ WCQ) {
  __shared__ float buf[9216];
  const int b = blockIdx.x;
  if (b < 128) {
    wre3_body(w_sk + (long)b * 9216, WTSK + (long)b * 9216, buf);
  } else if (b < 640) {
    const int oc = b - 128;
    wre3_body(w_sv + (long)oc * 9216, WTSV + (long)oc * 9216, buf);
  } else if (b < 768) {
    const int oc = b - 640;
    wre3_body(w_qq + (long)oc * 9216, WTQQK + (long)oc * 9216, buf);
  } else if (b < 896) {
    const int oc = b - 768;
    wre3_body(w_qk + (long)oc * 9216, WTQQK + (long)(oc + 128) * 9216, buf);
  } else {
    const int i = (b - 896) * 1024 + threadIdx.x * 4;
#pragma unroll
    for (int r = 0; r < 4; r++) WCQ[i + r] = f2h(w_cq[i + r]);
  }
}

// ---------- one-pass register softmax, L=15360 ----------
__global__ __launch_bounds__(256) void row_softmax60(u16* __restrict__ P) {
  u16* p = P + (long)blockIdx.x * 15360;
  const int tid = threadIdx.x;
  __shared__ float rm[4], rs[4];
  u16x4 v[15];
#pragma unroll
  for (int j = 0; j < 15; j++)
    v[j] = *(const u16x4*)(p + ((tid + (j << 8)) << 2));
  float m = -3.0e38f;
#pragma unroll
  for (int j = 0; j < 15; j++)
#pragma unroll
    for (int e = 0; e < 4; e++) m = fmaxf(m, h2f(v[j][e]));
#pragma unroll
  for (int o = 32; o > 0; o >>= 1) m = fmaxf(m, __shfl_xor(m, o, 64));
  if ((tid & 63) == 0) rm[tid >> 6] = m;
  __syncthreads();
  const float M = fmaxf(fmaxf(rm[0], rm[1]), fmaxf(rm[2], rm[3]));
  float s = 0.f;
#pragma unroll
  for (int j = 0; j < 15; j++)
#pragma unroll
    for (int e = 0; e < 4; e++) s += __expf(h2f(v[j][e]) - M);
#pragma unroll
  for (int o = 32; o > 0; o >>= 1) s += __shfl_xor(s, o, 64);
  if ((tid & 63) == 0) rs[tid >> 6] = s;
  __syncthreads();
  const float inv = 1.0f / (rs[0] + rs[1] + rs[2] + rs[3]);
#pragma unroll
  for (int j = 0; j < 15; j++) {
    u16x4 o4;
#pragma unroll
    for (int e = 0; e < 4; e++) o4[e] = f2h(__expf(h2f(v[j][e]) - M) * inv);
    *(u16x4*)(p + ((tid + (j << 8)) << 2)) = o4;
  }
}

// ---------- one-pass register softmax, L=1024 ----------
__global__ __launch_bounds__(256) void row_softmax4(u16* __restrict__ P) {
  u16* p = P + (long)blockIdx.x * 1024;
  const int tid = threadIdx.x;
  __shared__ float rm[4], rs[4];
  u16x4 v = *(const u16x4*)(p + (tid << 2));
  float m = fmaxf(fmaxf(h2f(v[0]), h2f(v[1])), fmaxf(h2f(v[2]), h2f(v[3])));
#pragma unroll
  for (int o = 32; o > 0; o >>= 1) m = fmaxf(m, __shfl_xor(m, o, 64));
  if ((tid & 63) == 0) rm[tid >> 6] = m;
  __syncthreads();
  const float M = fmaxf(fmaxf(rm[0], rm[1]), fmaxf(rm[2], rm[3]));
  float s = 0.f;
#pragma unroll
  for (int e = 0; e < 4; e++) s += __expf(h2f(v[e]) - M);
#pragma unroll
  for (int o = 32; o > 0; o >>= 1) s += __shfl_xor(s, o, 64);
  if ((tid & 63) == 0) rs[tid >> 6] = s;
  __syncthreads();
  const float inv = 1.0f / (rs[0] + rs[1] + rs[2] + rs[3]);
  u16x4 o4;
#pragma unroll
  for (int e = 0; e < 4; e++) o4[e] = f2h(__expf(h2f(v[e]) - M) * inv);
  *(u16x4*)(p + (tid << 2)) = o4;
}

// ---------- split-K reducers ----------
__global__ __launch_bounds__(256) void reduce8h(const u16* __restrict__ part,
                                                u16* __restrict__ o) {
  long j = ((long)blockIdx.x * 256 + threadIdx.x) * 4;
  int b = (int)(j >> 19);
  long i = j & 524287;
  const u16* p = part + (long)b * 4194304 + i;
  float s0 = 0.f, s1 = 0.f, s2 = 0.f, s3 = 0.f;
#pragma unroll
  for (int c = 0; c < 8; c++) {
    u16x4 v = *(const u16x4*)&p[(long)c * 524288];
    s0 += h2f(v[0]); s1 += h2f(v[1]); s2 += h2f(v[2]); s3 += h2f(v[3]);
  }
  u16x4 o4 = {f2h(s0), f2h(s1), f2h(s2), f2h(s3)};
  *(u16x4*)&o[j] = o4;
}
__global__ __launch_bounds__(256) void reduce_sk(const float* __restrict__ part,
                                                 const float* __restrict__ bias,
                                                 u16* __restrict__ o) {
  long i = ((long)blockIdx.x * 256 + threadIdx.x) * 4;
  f32x4 s = *(const f32x4*)&part[i];
  s = s + *(const f32x4*)&part[i + 3932160];
  f32x4 bb = *(const f32x4*)&bias[(int)(i & 127)];
  u16x4 o4;
#pragma unroll
  for (int r = 0; r < 4; r++) o4[r] = f2h(s[r] + bb[r]);
  *(u16x4*)&o[i] = o4;
}
__global__ __launch_bounds__(256) void reduce_qqk(
    const float* __restrict__ part, const float* __restrict__ b_qq,
    const float* __restrict__ b_qk, u16* __restrict__ QQR,
    u16* __restrict__ QKR) {
  long i = ((long)blockIdx.x * 256 + threadIdx.x) * 4;
  const int n = (int)(i >> 8), m = (int)(i & 255);
  f32x4 s = *(const f32x4*)&part[i];
  s = s + *(const f32x4*)&part[i + 2621440];
  const int lo = (m < 128);
  const int mm = m & 127;
  const float* bs = lo ? b_qq : b_qk;
  f32x4 bb = *(const f32x4*)&bs[mm];
  u16* dst = (lo ? QQR : QKR) + (long)n * 128 + mm;
  u16x4 o4;
#pragma unroll
  for (int r = 0; r < 4; r++) o4[r] = f2h(s[r] + bb[r]);
  *(u16x4*)dst = o4;
}

// ---------- 256x256 GEMM, barrier-free tile interior + wave ks-stagger ----
// Odd waves consume the two k-halves in swapped order so LDS-read windows
// and MFMA windows anti-align across waves (port ∥ matrix pipe overlap).
// setprio(1) wraps each MFMA cluster. One vmcnt(4)+barrier per K-tile.
__global__ __launch_bounds__(512, 2)
void gemm256(const u16* __restrict__ A, const u16* __restrict__ B,
             const float* __restrict__ bias, u16* __restrict__ out) {
  __shared__ u16 lds[81920];  // A: 2x32KB @0, B: 3x32KB @32768(u16)
  const int tid = threadIdx.x, lane = tid & 63, wave = tid >> 6;
  const int nwg = gridDim.x * gridDim.y;
  int wg = blockIdx.x + gridDim.x * blockIdx.y;
  wg = (wg & 7) * (nwg >> 3) + (wg >> 3);
  const int ntile = wg % gridDim.x;
  const int mtile = wg / gridDim.x;

  const int slog = (lane & 7) ^ ((lane >> 3) & 7);
  const u16* aS[4];
  const u16* bS[4];
  int aD[4], bD[4];
#pragma unroll
  for (int j = 0; j < 4; j++) {
    const int r = wave * 32 + j * 8 + (lane >> 3);
    aS[j] = A + (long)(mtile * 256 + r) * 9216 + slog * 8;
    aD[j] = (wave * 32 + j * 8) * 64;
    const int n = ntile * 256 + r;
    const int img = n >> 10, p = n & 1023;
    const int y = p >> 5, x = p & 31;
    bS[j] = B + ((long)((img * 34 + y) * 34 + x)) * 1024 + slog * 8;
    bD[j] = (wave * 32 + j * 8) * 64;
  }

  const int g = lane >> 4, l15 = lane & 15;
  const int wm = wave >> 2, wn = wave & 3;
  int aRow[8], bRow[4], sx[2];
#pragma unroll
  for (int mi = 0; mi < 8; mi++) aRow[mi] = (wm * 128 + mi * 16 + l15) * 64;
#pragma unroll
  for (int ni = 0; ni < 4; ni++) bRow[ni] = (wn * 64 + ni * 16 + l15) * 64;
#pragma unroll
  for (int ks = 0; ks < 2; ks++) sx[ks] = ((ks * 4 + g) ^ (l15 & 7)) * 8;
  // per-wave ks order stagger: odd waves do ks1 first
  const int w1 = wave & 1;
  const int sFirst = sx[w1], sSecond = sx[w1 ^ 1];

  auto conv_badd = [](int kt) {
    const int cblk = kt / 9;
    const int t = kt - cblk * 9;
    const int dy = t / 3, dx = t - dy * 3;
    return (dy * 34 + dx) * 1024 + cblk * 64;
  };

  f32x4 acc[8][4];
  const f32x4 zero = {0.f, 0.f, 0.f, 0.f};
#pragma unroll
  for (int i = 0; i < 8; i++)
#pragma unroll
    for (int j = 0; j < 4; j++) acc[i][j] = zero;

  const int nkt = 144;
  // prologue: A(0)->abuf0, B(0)->slab0, B(1)->slab1
  {
#pragma unroll
    for (int j = 0; j < 4; j++) gll16(aS[j], &lds[aD[j]]);
    const int b0o = conv_badd(0), b1o = conv_badd(1);
#pragma unroll
    for (int j = 0; j < 4; j++) gll16(bS[j] + b0o, &lds[32768 + bD[j]]);
#pragma unroll
    for (int j = 0; j < 4; j++) gll16(bS[j] + b1o, &lds[49152 + bD[j]]);
    asm volatile("s_waitcnt vmcnt(4)" ::: "memory");
    __builtin_amdgcn_s_barrier();
  }

  // pipelined fragment registers (a3/b2 carry the deferred quadrant)
  f16x8 a0[4], a1[4], a3[4], b0[4], b2[4];
  f16x8 zf;
#pragma unroll
  for (int j = 0; j < 8; j++) zf[j] = (_Float16)0.0f;
#pragma unroll
  for (int i = 0; i < 4; i++) { a3[i] = zf; b2[i] = zf; }

  int bc = 0;
  for (int kt = 0; kt < nkt; ++kt) {
    const int abuf = (kt & 1) << 14;
    const int anbuf = abuf ^ 16384;
    const int bbuf = 32768 + bc * 16384;
    int bsn = bc + 2; if (bsn >= 3) bsn -= 3;
    const int bnbuf = 32768 + bsn * 16384;
    const bool stA = (kt + 1 < nkt);
    const bool stB = (kt + 2 < nkt);
    const int kA = (kt + 1) << 6;
    const int bAdd2 = stB ? conv_badd(kt + 2) : 0;

    // L0: first-half fragments (12 ds_read_b128)
#pragma unroll
    for (int i = 0; i < 4; i++) a0[i] = *(const f16x8*)&lds[abuf + aRow[i] + sFirst];
#pragma unroll
    for (int i = 0; i < 4; i++) b0[i] = *(const f16x8*)&lds[bbuf + bRow[i] + sFirst];
#pragma unroll
    for (int i = 0; i < 4; i++) a1[i] = *(const f16x8*)&lds[abuf + aRow[i + 4] + sFirst];
    // deferred ph3 of previous tile (zeros on kt==0)
    __builtin_amdgcn_s_setprio(1);
#pragma unroll
    for (int mi = 0; mi < 4; mi++)
#pragma unroll
      for (int ni = 0; ni < 4; ni++)
        acc[mi + 4][ni] = __builtin_amdgcn_mfma_f32_16x16x32_f16(
            a3[mi], b2[ni], acc[mi + 4][ni], 0, 0, 0);
    __builtin_amdgcn_s_setprio(0);
    if (stA) {
#pragma unroll
      for (int j = 0; j < 4; j++) gll16(aS[j] + kA, &lds[anbuf + aD[j]]);
    }
    // ph0
    __builtin_amdgcn_s_setprio(1);
#pragma unroll
    for (int mi = 0; mi < 4; mi++)
#pragma unroll
      for (int ni = 0; ni < 4; ni++)
        acc[mi][ni] = __builtin_amdgcn_mfma_f32_16x16x32_f16(
            a0[mi], b0[ni], acc[mi][ni], 0, 0, 0);
    __builtin_amdgcn_s_setprio(0);
    // L1: second-half rows 0-3 (reuse a0) + B second-half
#pragma unroll
    for (int i = 0; i < 4; i++) a0[i] = *(const f16x8*)&lds[abuf + aRow[i] + sSecond];
#pragma unroll
    for (int i = 0; i < 4; i++) b2[i] = *(const f16x8*)&lds[bbuf + bRow[i] + sSecond];
    if (stB) {
#pragma unroll
      for (int j = 0; j < 4; j++) gll16(bS[j] + bAdd2, &lds[bnbuf + bD[j]]);
    }
    // ph1
    __builtin_amdgcn_s_setprio(1);
#pragma unroll
    for (int mi = 0; mi < 4; mi++)
#pragma unroll
      for (int ni = 0; ni < 4; ni++)
        acc[mi + 4][ni] = __builtin_amdgcn_mfma_f32_16x16x32_f16(
            a1[mi], b0[ni], acc[mi + 4][ni], 0, 0, 0);
    __builtin_amdgcn_s_setprio(0);
    // L2: second-half rows 4-7 (feeds deferred ph3 next tile)
#pragma unroll
    for (int i = 0; i < 4; i++) a3[i] = *(const f16x8*)&lds[abuf + aRow[i + 4] + sSecond];
    // ph2
    __builtin_amdgcn_s_setprio(1);
#pragma unroll
    for (int mi = 0; mi < 4; mi++)
#pragma unroll
      for (int ni = 0; ni < 4; ni++)
        acc[mi][ni] = __builtin_amdgcn_mfma_f32_16x16x32_f16(
            a0[mi], b2[ni], acc[mi][ni], 0, 0, 0);
    __builtin_amdgcn_s_setprio(0);
    // tile gate: counted, never drains the dist-2 B prefetch
    if (stB) {
      asm volatile("s_waitcnt vmcnt(4)" ::: "memory");
    } else if (stA) {
      asm volatile("s_waitcnt vmcnt(0)" ::: "memory");
    }
    __builtin_amdgcn_s_barrier();
    bc = bc + 1; if (bc >= 3) bc -= 3;
  }
  // final deferred ph3
#pragma unroll
  for (int mi = 0; mi < 4; mi++)
#pragma unroll
    for (int ni = 0; ni < 4; ni++)
      acc[mi + 4][ni] = __builtin_amdgcn_mfma_f32_16x16x32_f16(
          a3[mi], b2[ni], acc[mi + 4][ni], 0, 0, 0);

  // ---- epilogue: SVA[b][m][col] = acc + bias[m] ----
#pragma unroll
  for (int mi = 0; mi < 8; mi++) {
#pragma unroll
    for (int ni = 0; ni < 4; ni++) {
      f32x4 v = acc[mi][ni];
      const int m0 = mtile * 256 + wm * 128 + mi * 16 + g * 4;
      const int n = ntile * 256 + wn * 64 + ni * 16 + l15;
      const int b = (n >= 15360) ? 1 : 0;
      const int rem = n - b * 15360;
#pragma unroll
      for (int r = 0; r < 4; r++) {
        const int m = m0 + r;
        out[(long)b * 7864320 + (long)m * 15360 + rem] = f2h(v[r] + bias[m]);
      }
    }
  }
}

// ---------- 128x128 NT GEMM (2-phase, general purpose) ----------
template <int BMODE, int EPI, int SPLITK>
__global__ __launch_bounds__(256, 2)
void gemm_nt(const u16* __restrict__ A, long Azoff, int Astride,
             const u16* __restrict__ B, long Bzoff, int Bstride,
             int K, float scale,
             const float* __restrict__ bias, const float* __restrict__ bias2,
             void* __restrict__ out0, void* __restrict__ out1,
             long out_zoff, int ldo) {
  __shared__ u16 lds[4 * 8192];
  const int tid = threadIdx.x;
  const int lane = tid & 63;
  const int wave = tid >> 6;
  const int mtile = blockIdx.y, ntile = blockIdx.x, z = blockIdx.z;

  const int zb = (SPLITK > 1) ? z / SPLITK : z;
  const int zc = (SPLITK > 1) ? z % SPLITK : 0;
  const u16* Ab = A + (long)zb * Azoff + (long)zc * K;
  const u16* Bb = B + (long)zb * Bzoff + ((BMODE == 0) ? (long)zc * K : 0);

  const int r8 = lane >> 3;
  const int sphys = lane & 7;
  const u16* aSrc[4];
  const u16* bSrc[4];
  u16* aDst[4];
  u16* bDst[4];
#pragma unroll
  for (int i = 0; i < 4; i++) {
    const int row = wave * 32 + i * 8 + r8;
    const int slog = sphys ^ (row & 7);
    aSrc[i] = Ab + (long)(mtile * 128 + row) * Astride + slog * 8;
    if (BMODE == 0) {
      bSrc[i] = Bb + (long)(ntile * 128 + row) * Bstride + slog * 8;
    } else {
      const int n = ntile * 128 + row;
      const int img = n >> 10;
      const int p = n & 1023;
      const int y = p >> 5, x = p & 31;
      bSrc[i] = Bb + ((long)(img * 34 + y) * 34 + x) * 1024 + slog * 8;
    }
    aDst[i] = &lds[0] + (wave * 32 + i * 8) * 64;
    bDst[i] = &lds[0] + 8192 + (wave * 32 + i * 8) * 64;
  }

  const int g = lane >> 4, l15 = lane & 15;
  const int wm = wave >> 1, wn = wave & 1;
  int offA[2][4], offB[2][4];
#pragma unroll
  for (int ks = 0; ks < 2; ks++) {
    const int sl = ks * 4 + g;
#pragma unroll
    for (int i = 0; i < 4; i++) {
      const int ra = wm * 64 + i * 16 + l15;
      offA[ks][i] = ra * 64 + ((sl ^ (ra & 7)) * 8);
      const int rb = wn * 64 + i * 16 + l15;
      offB[ks][i] = 8192 + rb * 64 + ((sl ^ (rb & 7)) * 8);
    }
  }

  auto stage = [&](int buf, int kb) {
    int bAdd;
    if (BMODE == 0) {
      bAdd = kb;
    } else if (BMODE == 1) {
      const int ktg = (zc * K + kb) >> 6;
      const int cblk = ktg / 9;
      const int t = ktg - cblk * 9;
      const int dy = t / 3, dx = t - dy * 3;
      bAdd = (dy * 34 + dx) * 1024 + cblk * 64;
    } else {
      bAdd = 35 * 1024 + kb;
    }
    const int bufo = buf * 16384;
#pragma unroll
    for (int i = 0; i < 4; i++) gll16(aSrc[i] + kb, aDst[i] + bufo);
#pragma unroll
    for (int i = 0; i < 4; i++) gll16(bSrc[i] + bAdd, bDst[i] + bufo);
  };

  f32x4 acc[4][4];
  const f32x4 zero = {0.f, 0.f, 0.f, 0.f};
#pragma unroll
  for (int i = 0; i < 4; i++)
#pragma unroll
    for (int j = 0; j < 4; j++) acc[i][j] = zero;

  const int nkt = K >> 6;
  stage(0, 0);
  __syncthreads();
  for (int kt = 0; kt < nkt; ++kt) {
    const int buf = kt & 1;
    if (kt + 1 < nkt) stage(buf ^ 1, (kt + 1) << 6);
#pragma unroll
    for (int ks = 0; ks < 2; ks++) {
      f16x8 af[4], bfg[4];
#pragma unroll
      for (int i = 0; i < 4; i++)
        af[i] = *(const f16x8*)&lds[buf * 16384 + offA[ks][i]];
#pragma unroll
      for (int i = 0; i < 4; i++)
        bfg[i] = *(const f16x8*)&lds[buf * 16384 + offB[ks][i]];
#pragma unroll
      for (int mi = 0; mi < 4; mi++)
#pragma unroll
        for (int ni = 0; ni < 4; ni++)
          acc[mi][ni] = __builtin_amdgcn_mfma_f32_16x16x32_f16(
              af[mi], bfg[ni], acc[mi][ni], 0, 0, 0);
    }
    __syncthreads();
  }

#pragma unroll
  for (int mi = 0; mi < 4; mi++) {
#pragma unroll
    for (int ni = 0; ni < 4; ni++) {
      f32x4 v = acc[mi][ni];
      const int m0 = mtile * 128 + wm * 64 + mi * 16 + g * 4;
      const int n = ntile * 128 + wn * 64 + ni * 16 + l15;
      if (EPI == 0) {
        u16* ob = (u16*)out0;
        const float* bs = bias;
        int mm = m0;
        if (out1 != nullptr && m0 >= 128) { ob = (u16*)out1; bs = bias2; mm = m0 - 128; }
        u16x4 pk;
#pragma unroll
        for (int r = 0; r < 4; r++) {
          float val = v[r] * scale + (bs ? bs[mm + r] : 0.f);
          pk[r] = f2h(val);
        }
        *(u16x4*)&ob[(long)n * ldo + mm] = pk;
      } else if (EPI == 1) {
        u16* ob = (u16*)out0 + (long)z * out_zoff;
#pragma unroll
        for (int r = 0; r < 4; r++) {
          const int m = m0 + r;
          float val = v[r] * scale + (bias ? bias[m] : 0.f);
          ob[(long)m * ldo + n] = f2h(val);
        }
      } else if (EPI == 2) {
        float* of = (float*)out0;
        const int img = n >> 10, p = n & 1023;
#pragma unroll
        for (int r = 0; r < 4; r++) {
          const int m = m0 + r;
          of[(long)img * 1048576 + (long)(512 + m) * 1024 + p] =
              v[r] + (bias ? bias[m] : 0.f);
        }
      } else if (EPI == 3) {
        float* of = (float*)out0;
        const int f = n >> 10, p = n & 1023;
#pragma unroll
        for (int r = 0; r < 4; r++) {
          const int m = m0 + r;
          of[(long)z * 5242880 + (long)f * 1048576 + (long)m * 1024 + p] = v[r];
        }
      } else if (EPI == 4) {
        float* of = (float*)out0 + (long)z * out_zoff;
#pragma unroll
        for (int r = 0; r < 4; r++) of[(long)(m0 + r) * ldo + n] = v[r];
      } else if (EPI == 5) {
        float* of = (float*)out0 + (long)zc * out_zoff;
        *(f32x4*)&of[(long)n * ldo + m0] = v;
      } else {  // EPI == 6: f16 partial row store
        u16* ob = (u16*)out0 + (long)z * out_zoff;
#pragma unroll
        for (int r = 0; r < 4; r++) ob[(long)(m0 + r) * ldo + n] = f2h(v[r]);
      }
    }
  }
}

// ---------- launch ----------
extern "C" void kernel_launch(void* const* d_in, const int* in_sizes, int n_in,
                              void* d_out, int out_size, void* d_ws, size_t ws_size,
                              hipStream_t stream) {
  (void)in_sizes; (void)n_in; (void)out_size;
  const float* query   = (const float*)d_in[0];
  const float* support = (const float*)d_in[1];
  const float* w_sk = (const float*)d_in[2];  const float* b_sk = (const float*)d_in[3];
  const float* w_sv = (const float*)d_in[4];  const float* b_sv = (const float*)d_in[5];
  const float* w_qq = (const float*)d_in[6];  const float* b_qq = (const float*)d_in[7];
  const float* w_qk = (const float*)d_in[8];  const float* b_qk = (const float*)d_in[9];
  const float* w_cq = (const float*)d_in[10]; const float* b_cq = (const float*)d_in[11];
  float* out = (float*)d_out;
  char* ws = (char*)d_ws;

  if (ws_size < 158924800u) return;

  u16* PQ    = (u16*)(ws + 0);
  u16* PS    = (u16*)(ws + 23674880);
  u16* WTSK  = (u16*)(ws + 94699520);
  u16* WTSV  = (u16*)(ws + 97058816);
  u16* WTQQK = (u16*)(ws + 106496000);
  u16* WCQ   = (u16*)(ws + 111214592);
  u16* SKR   = (u16*)(ws + 112263168);
  u16* SVA   = (u16*)(ws + 120127488);
  u16* QQR   = (u16*)(ws + 151584768);
  u16* QKR   = (u16*)(ws + 154206208);
  u16* NEWV  = (u16*)(ws + 156827648);
  u16* P1T   = PS;
  u16* P2T   = PQ;
  u16* PART2 = (u16*)(ws + 94699520);
  float* PARTK = (float*)SVA;
  float* PARTQ = (float*)SVA;

  const float SCALE = 0.08838834764831843f;  // 1/sqrt(128)

  pad_nhwc<<<dim3(320), 256, 0, stream>>>(query, PQ);
  pad_nhwc<<<dim3(960), 256, 0, stream>>>(support, PS);
  wprep<<<dim3(1408), 256, 0, stream>>>(w_sk, w_sv, w_qq, w_qk, w_cq,
                                        WTSK, WTSV, WTQQK, WCQ);

  // sk conv: split-K=2 -> fp32 partials, then reduce(+bias)
  gemm_nt<1, 5, 2><<<dim3(240, 1, 2), 256, 0, stream>>>(
      WTSK, 0, 9216, PS, 0, 0, 4608, 1.0f, nullptr, nullptr, PARTK, nullptr,
      3932160L, 128);
  reduce_sk<<<dim3(3840), 256, 0, stream>>>(PARTK, b_sk, SKR);

  // qq+qk conv: split-K=2 -> fp32 partials, then reduce(+bias)
  gemm_nt<1, 5, 2><<<dim3(80, 2, 2), 256, 0, stream>>>(
      WTQQK, 0, 9216, PQ, 0, 0, 4608, 1.0f, nullptr, nullptr, PARTQ, nullptr,
      2621440L, 256);
  reduce_qqk<<<dim3(2560), 256, 0, stream>>>(PARTQ, b_qq, b_qk, QQR, QKR);

  // sv conv
  gemm256<<<dim3(120, 2), 512, 0, stream>>>(WTSV, PS, b_sv, SVA);

  // qf 1x1 conv
  gemm_nt<2, 2, 1><<<dim3(80, 4, 1), 256, 0, stream>>>(
      WCQ, 0, 1024, PQ, 0, 0, 1024, 1.0f, b_cq, nullptr, out, nullptr, 0, 0);

  // stage 1
  gemm_nt<0, 1, 1><<<dim3(120, 8, 2), 256, 0, stream>>>(
      QQR + 262144, 655360L, 128, SKR, 1966080L, 128, 128, SCALE, nullptr,
      nullptr, P1T, nullptr, 15728640L, 15360);
  row_softmax60<<<dim3(2048), 256, 0, stream>>>(P1T);
  gemm_nt<0, 6, 8><<<dim3(8, 4, 16), 256, 0, stream>>>(
      SVA, 7864320L, 15360, P1T, 15728640L, 15360, 1920, 1.0f, nullptr,
      nullptr, PART2, nullptr, 524288L, 1024);
  reduce8h<<<dim3(1024), 256, 0, stream>>>(PART2, NEWV);

  // stage 2
  gemm_nt<0, 1, 1><<<dim3(8, 40, 2), 256, 0, stream>>>(
      QQR, 655360L, 128, QKR + 262144, 655360L, 128, 128, SCALE, nullptr,
      nullptr, P2T, nullptr, 5242880L, 1024);
  row_softmax4<<<dim3(10240), 256, 0, stream>>>(P2T);
  gemm_nt<0, 3, 1><<<dim3(40, 4, 2), 256, 0, stream>>>(
      NEWV, 524288L, 1024, P2T, 5242880L, 1024, 1024, 1.0f, nullptr, nullptr,
      out, nullptr, 0, 0);
}

// Round 10
// 593.940 us; speedup vs baseline: 1.5384x; 1.1078x over previous
//
#include <hip/hip_runtime.h>
#include <cstdint>

typedef unsigned short u16;
typedef __attribute__((ext_vector_type(8))) u16 u16x8;
typedef __attribute__((ext_vector_type(4))) u16 u16x4;
typedef __attribute__((ext_vector_type(8))) _Float16 f16x8;
typedef __attribute__((ext_vector_type(4))) float f32x4;

// ---------- helpers ----------
__device__ __forceinline__ u16 f2h(float f) {
  _Float16 h = (_Float16)f;
  return __builtin_bit_cast(u16, h);
}
__device__ __forceinline__ float h2f(u16 b) {
  _Float16 h = __builtin_bit_cast(_Float16, b);
  return (float)h;
}
__device__ __forceinline__ void gll16(const void* g, void* l) {
  auto gp = reinterpret_cast<const __attribute__((address_space(1))) unsigned int*>(
      reinterpret_cast<uintptr_t>(g));
  auto lp = reinterpret_cast<__attribute__((address_space(3))) unsigned int*>(
      reinterpret_cast<uintptr_t>(l));
  __builtin_amdgcn_global_load_lds(gp, lp, 16, 0, 0);
}

// ---------- prep: NCHW fp32 -> padded(34x34) NHWC fp16, both inputs ----------
__global__ __launch_bounds__(256) void pad_both(const float* __restrict__ qsrc,
                                                const float* __restrict__ ssrc,
                                                u16* __restrict__ PQ,
                                                u16* __restrict__ PS) {
  const int gi = blockIdx.x >> 5;
  const int y  = blockIdx.x & 31;
  const float* in;
  u16* outp;
  int img;
  if (gi < 10) { in = qsrc; outp = PQ; img = gi; }
  else         { in = ssrc; outp = PS; img = gi - 10; }
  __shared__ float tile[32][33];
  const int tid = threadIdx.x;
  u16* base = outp + (long)img * 34 * 34 * 1024;
  const u16x8 z8 = {0, 0, 0, 0, 0, 0, 0, 0};
  {
    u16* r = base + (long)(y + 1) * 34 * 1024;
    if (tid < 128) *(u16x8*)&r[tid * 8] = z8;
    else *(u16x8*)&r[33 * 1024 + (tid - 128) * 8] = z8;
  }
  if (y == 0) {
    for (int i = tid * 8; i < 34816; i += 2048) *(u16x8*)&base[i] = z8;
  }
  if (y == 31) {
    u16* r = base + 33L * 34 * 1024;
    for (int i = tid * 8; i < 34816; i += 2048) *(u16x8*)&r[i] = z8;
  }
  const int xi = tid & 31, ci = tid >> 5;
  const int xo = tid >> 3, q = tid & 7;
  const float* ip = in + (long)img * 1048576 + y * 32;
  u16* op = base + ((long)(y + 1) * 34 + 1) * 1024;
  for (int c0 = 0; c0 < 1024; c0 += 32) {
#pragma unroll
    for (int k2 = 0; k2 < 4; k2++)
      tile[k2 * 8 + ci][xi] = ip[(long)(c0 + k2 * 8 + ci) * 1024 + xi];
    __syncthreads();
    u16x4 o4;
#pragma unroll
    for (int r = 0; r < 4; r++) o4[r] = f2h(tile[q * 4 + r][xo]);
    *(u16x4*)&op[(long)xo * 1024 + c0 + q * 4] = o4;
    __syncthreads();
  }
}

// ---------- merged weight prep ----------
// 3x3 weights in CHANNEL-BLOCK-MAJOR, TAP-MINOR k-order:
//   k = cblk*576 + tap*64 + ci   (cblk = c>>6, ci = c&63)
__device__ __forceinline__ void wre3_body(const float* __restrict__ wp,
                                          u16* __restrict__ op, float* buf) {
  for (int i = threadIdx.x; i < 9216; i += 256) buf[i] = wp[i];
  __syncthreads();
  for (int k = threadIdx.x; k < 9216; k += 256) {
    const int cblk = k / 576;
    const int r = k - cblk * 576;
    const int t = r >> 6, ci = r & 63;
    op[k] = f2h(buf[(cblk * 64 + ci) * 9 + t]);
  }
}
__global__ __launch_bounds__(256) void wprep(
    const float* __restrict__ w_sk, const float* __restrict__ w_sv,
    const float* __restrict__ w_qq, const float* __restrict__ w_qk,
    const float* __restrict__ w_cq, u16* __restrict__ WTSK,
    u16* __restrict__ WTSV, u16* __restrict__ WTQQK, u16* __restrict__ WCQ) {
  __shared__ float buf[9216];
  const int b = blockIdx.x;
  if (b < 128) {
    wre3_body(w_sk + (long)b * 9216, WTSK + (long)b * 9216, buf);
  } else if (b < 640) {
    const int oc = b - 128;
    wre3_body(w_sv + (long)oc * 9216, WTSV + (long)oc * 9216, buf);
  } else if (b < 768) {
    const int oc = b - 640;
    wre3_body(w_qq + (long)oc * 9216, WTQQK + (long)oc * 9216, buf);
  } else if (b < 896) {
    const int oc = b - 768;
    wre3_body(w_qk + (long)oc * 9216, WTQQK + (long)(oc + 128) * 9216, buf);
  } else {
    const int i = (b - 896) * 1024 + threadIdx.x * 4;
#pragma unroll
    for (int r = 0; r < 4; r++) WCQ[i + r] = f2h(w_cq[i + r]);
  }
}

// ---------- row-sum kernels (max-free softmax denominators) ----------
__global__ __launch_bounds__(256) void rowsum60(const u16* __restrict__ P,
                                                float* __restrict__ D) {
  const u16* p = P + (long)blockIdx.x * 15360;
  const int tid = threadIdx.x;
  __shared__ float rs[4];
  float s = 0.f;
  for (int i = tid; i < 1920; i += 256) {
    u16x8 v = *(const u16x8*)(p + (i << 3));
#pragma unroll
    for (int j = 0; j < 8; j++) s += h2f(v[j]);
  }
#pragma unroll
  for (int o = 32; o > 0; o >>= 1) s += __shfl_xor(s, o, 64);
  if ((tid & 63) == 0) rs[tid >> 6] = s;
  __syncthreads();
  if (tid == 0) D[blockIdx.x] = rs[0] + rs[1] + rs[2] + rs[3];
}
__global__ __launch_bounds__(256) void rowsum4(const u16* __restrict__ P,
                                               float* __restrict__ D) {
  const u16* p = P + (long)blockIdx.x * 1024;
  const int tid = threadIdx.x;
  __shared__ float rs[4];
  u16x4 v = *(const u16x4*)(p + (tid << 2));
  float s = h2f(v[0]) + h2f(v[1]) + h2f(v[2]) + h2f(v[3]);
#pragma unroll
  for (int o = 32; o > 0; o >>= 1) s += __shfl_xor(s, o, 64);
  if ((tid & 63) == 0) rs[tid >> 6] = s;
  __syncthreads();
  if (tid == 0) D[blockIdx.x] = rs[0] + rs[1] + rs[2] + rs[3];
}

// ---------- split-K reducers ----------
// NEWV f16 = (sum of 8 f16 chunks) / D1[q]
__global__ __launch_bounds__(256) void reduce8h(const u16* __restrict__ part,
                                                const float* __restrict__ D,
                                                u16* __restrict__ o) {
  long j = ((long)blockIdx.x * 256 + threadIdx.x) * 4;
  int b = (int)(j >> 19);
  long i = j & 524287;
  int q = (int)(i & 1023);
  const u16* p = part + (long)b * 4194304 + i;
  float s0 = 0.f, s1 = 0.f, s2 = 0.f, s3 = 0.f;
#pragma unroll
  for (int c = 0; c < 8; c++) {
    u16x4 v = *(const u16x4*)&p[(long)c * 524288];
    s0 += h2f(v[0]); s1 += h2f(v[1]); s2 += h2f(v[2]); s3 += h2f(v[3]);
  }
  f32x4 dv = *(const f32x4*)&D[b * 1024 + q];
  u16x4 o4 = {f2h(s0 / dv[0]), f2h(s1 / dv[1]), f2h(s2 / dv[2]),
              f2h(s3 / dv[3])};
  *(u16x4*)&o[j] = o4;
}
__global__ __launch_bounds__(256) void reduce_sk(const float* __restrict__ part,
                                                 const float* __restrict__ bias,
                                                 u16* __restrict__ o) {
  long i = ((long)blockIdx.x * 256 + threadIdx.x) * 4;
  f32x4 s = *(const f32x4*)&part[i];
  s = s + *(const f32x4*)&part[i + 3932160];
  f32x4 bb = *(const f32x4*)&bias[(int)(i & 127)];
  u16x4 o4;
#pragma unroll
  for (int r = 0; r < 4; r++) o4[r] = f2h(s[r] + bb[r]);
  *(u16x4*)&o[i] = o4;
}
__global__ __launch_bounds__(256) void reduce_qqk(
    const float* __restrict__ part, const float* __restrict__ b_qq,
    const float* __restrict__ b_qk, u16* __restrict__ QQR,
    u16* __restrict__ QKR) {
  long i = ((long)blockIdx.x * 256 + threadIdx.x) * 4;
  const int n = (int)(i >> 8), m = (int)(i & 255);
  f32x4 s = *(const f32x4*)&part[i];
  s = s + *(const f32x4*)&part[i + 2621440];
  const int lo = (m < 128);
  const int mm = m & 127;
  const float* bs = lo ? b_qq : b_qk;
  f32x4 bb = *(const f32x4*)&bs[mm];
  u16* dst = (lo ? QQR : QKR) + (long)n * 128 + mm;
  u16x4 o4;
#pragma unroll
  for (int r = 0; r < 4; r++) o4[r] = f2h(s[r] + bb[r]);
  *(u16x4*)dst = o4;
}

// ---------- 256x256 GEMM, barrier-free K-tile interior (r8 body) ----------
__global__ __launch_bounds__(512, 1)
void gemm256(const u16* __restrict__ A, const u16* __restrict__ B,
             const float* __restrict__ bias, u16* __restrict__ out) {
  __shared__ u16 lds[81920];  // A: 2x32KB @0, B: 3x32KB @32768(u16)
  const int tid = threadIdx.x, lane = tid & 63, wave = tid >> 6;
  const int nwg = gridDim.x * gridDim.y;
  int wg = blockIdx.x + gridDim.x * blockIdx.y;
  wg = (wg & 7) * (nwg >> 3) + (wg >> 3);
  const int ntile = wg % gridDim.x;
  const int mtile = wg / gridDim.x;

  const int slog = (lane & 7) ^ ((lane >> 3) & 7);
  const u16* aS[4];
  const u16* bS[4];
  int aD[4], bD[4];
#pragma unroll
  for (int j = 0; j < 4; j++) {
    const int r = wave * 32 + j * 8 + (lane >> 3);
    aS[j] = A + (long)(mtile * 256 + r) * 9216 + slog * 8;
    aD[j] = (wave * 32 + j * 8) * 64;
    const int n = ntile * 256 + r;
    const int img = n >> 10, p = n & 1023;
    const int y = p >> 5, x = p & 31;
    bS[j] = B + ((long)((img * 34 + y) * 34 + x)) * 1024 + slog * 8;
    bD[j] = (wave * 32 + j * 8) * 64;
  }

  const int g = lane >> 4, l15 = lane & 15;
  const int wm = wave >> 2, wn = wave & 3;
  int aRow[8], bRow[4], sx[2];
#pragma unroll
  for (int mi = 0; mi < 8; mi++) aRow[mi] = (wm * 128 + mi * 16 + l15) * 64;
#pragma unroll
  for (int ni = 0; ni < 4; ni++) bRow[ni] = (wn * 64 + ni * 16 + l15) * 64;
#pragma unroll
  for (int ks = 0; ks < 2; ks++) sx[ks] = ((ks * 4 + g) ^ (l15 & 7)) * 8;

  auto conv_badd = [](int kt) {
    const int cblk = kt / 9;
    const int t = kt - cblk * 9;
    const int dy = t / 3, dx = t - dy * 3;
    return (dy * 34 + dx) * 1024 + cblk * 64;
  };

  f32x4 acc[8][4];
  const f32x4 zero = {0.f, 0.f, 0.f, 0.f};
#pragma unroll
  for (int i = 0; i < 8; i++)
#pragma unroll
    for (int j = 0; j < 4; j++) acc[i][j] = zero;

  const int nkt = 144;
  {
#pragma unroll
    for (int j = 0; j < 4; j++) gll16(aS[j], &lds[aD[j]]);
    const int b0o = conv_badd(0), b1o = conv_badd(1);
#pragma unroll
    for (int j = 0; j < 4; j++) gll16(bS[j] + b0o, &lds[32768 + bD[j]]);
#pragma unroll
    for (int j = 0; j < 4; j++) gll16(bS[j] + b1o, &lds[49152 + bD[j]]);
    asm volatile("s_waitcnt vmcnt(4)" ::: "memory");
    __builtin_amdgcn_s_barrier();
  }

  f16x8 a0[4], a1[4], a3[4], b0[4], b2[4];
  f16x8 zf;
#pragma unroll
  for (int j = 0; j < 8; j++) zf[j] = (_Float16)0.0f;
#pragma unroll
  for (int i = 0; i < 4; i++) { a3[i] = zf; b2[i] = zf; }

  int bc = 0;
  for (int kt = 0; kt < nkt; ++kt) {
    const int abuf = (kt & 1) << 14;
    const int anbuf = abuf ^ 16384;
    const int bbuf = 32768 + bc * 16384;
    int bsn = bc + 2; if (bsn >= 3) bsn -= 3;
    const int bnbuf = 32768 + bsn * 16384;
    const bool stA = (kt + 1 < nkt);
    const bool stB = (kt + 2 < nkt);
    const int kA = (kt + 1) << 6;
    const int bAdd2 = stB ? conv_badd(kt + 2) : 0;

    // L0: ks0 fragments
#pragma unroll
    for (int i = 0; i < 4; i++) a0[i] = *(const f16x8*)&lds[abuf + aRow[i] + sx[0]];
#pragma unroll
    for (int i = 0; i < 4; i++) b0[i] = *(const f16x8*)&lds[bbuf + bRow[i] + sx[0]];
#pragma unroll
    for (int i = 0; i < 4; i++) a1[i] = *(const f16x8*)&lds[abuf + aRow[i + 4] + sx[0]];
    // deferred ph3 of previous tile (zeros on kt==0)
#pragma unroll
    for (int mi = 0; mi < 4; mi++)
#pragma unroll
      for (int ni = 0; ni < 4; ni++)
        acc[mi + 4][ni] = __builtin_amdgcn_mfma_f32_16x16x32_f16(
            a3[mi], b2[ni], acc[mi + 4][ni], 0, 0, 0);
    if (stA) {
#pragma unroll
      for (int j = 0; j < 4; j++) gll16(aS[j] + kA, &lds[anbuf + aD[j]]);
    }
    // ph0
#pragma unroll
    for (int mi = 0; mi < 4; mi++)
#pragma unroll
      for (int ni = 0; ni < 4; ni++)
        acc[mi][ni] = __builtin_amdgcn_mfma_f32_16x16x32_f16(
            a0[mi], b0[ni], acc[mi][ni], 0, 0, 0);
    // L1: ks1 rows 0-3 + B ks1
#pragma unroll
    for (int i = 0; i < 4; i++) a0[i] = *(const f16x8*)&lds[abuf + aRow[i] + sx[1]];
#pragma unroll
    for (int i = 0; i < 4; i++) b2[i] = *(const f16x8*)&lds[bbuf + bRow[i] + sx[1]];
    if (stB) {
#pragma unroll
      for (int j = 0; j < 4; j++) gll16(bS[j] + bAdd2, &lds[bnbuf + bD[j]]);
    }
    // ph1
#pragma unroll
    for (int mi = 0; mi < 4; mi++)
#pragma unroll
      for (int ni = 0; ni < 4; ni++)
        acc[mi + 4][ni] = __builtin_amdgcn_mfma_f32_16x16x32_f16(
            a1[mi], b0[ni], acc[mi + 4][ni], 0, 0, 0);
    // L2: ks1 rows 4-7 (feeds deferred ph3 next tile)
#pragma unroll
    for (int i = 0; i < 4; i++) a3[i] = *(const f16x8*)&lds[abuf + aRow[i + 4] + sx[1]];
    // ph2
#pragma unroll
    for (int mi = 0; mi < 4; mi++)
#pragma unroll
      for (int ni = 0; ni < 4; ni++)
        acc[mi][ni] = __builtin_amdgcn_mfma_f32_16x16x32_f16(
            a0[mi], b2[ni], acc[mi][ni], 0, 0, 0);
    if (stB) {
      asm volatile("s_waitcnt vmcnt(4)" ::: "memory");
    } else if (stA) {
      asm volatile("s_waitcnt vmcnt(0)" ::: "memory");
    }
    __builtin_amdgcn_s_barrier();
    bc = bc + 1; if (bc >= 3) bc -= 3;
  }
  // final deferred ph3
#pragma unroll
  for (int mi = 0; mi < 4; mi++)
#pragma unroll
    for (int ni = 0; ni < 4; ni++)
      acc[mi + 4][ni] = __builtin_amdgcn_mfma_f32_16x16x32_f16(
          a3[mi], b2[ni], acc[mi + 4][ni], 0, 0, 0);

  // ---- epilogue: SVA[b][m][col] = acc + bias[m] ----
#pragma unroll
  for (int mi = 0; mi < 8; mi++) {
#pragma unroll
    for (int ni = 0; ni < 4; ni++) {
      f32x4 v = acc[mi][ni];
      const int m0 = mtile * 256 + wm * 128 + mi * 16 + g * 4;
      const int n = ntile * 256 + wn * 64 + ni * 16 + l15;
      const int b = (n >= 15360) ? 1 : 0;
      const int rem = n - b * 15360;
#pragma unroll
      for (int r = 0; r < 4; r++) {
        const int m = m0 + r;
        out[(long)b * 7864320 + (long)m * 15360 + rem] = f2h(v[r] + bias[m]);
      }
    }
  }
}

// ---------- 128x128 NT GEMM (2-phase, general purpose) ----------
// EPI: 0 f16 transposed store; 1 f16 row store *scale(+bias); 2 qf fp32;
//      3 final fp32 (/bias2[z*5120+n]); 4 fp32 partial row; 5 fp32 transposed
//      partial; 6 f16 partial row; 7 f16 row store exp(v*scale - cexp)
template <int BMODE, int EPI, int SPLITK>
__global__ __launch_bounds__(256, 2)
void gemm_nt(const u16* __restrict__ A, long Azoff, int Astride,
             const u16* __restrict__ B, long Bzoff, int Bstride,
             int K, float scale,
             const float* __restrict__ bias, const float* __restrict__ bias2,
             void* __restrict__ out0, void* __restrict__ out1,
             long out_zoff, int ldo, float cexp = 0.f) {
  __shared__ u16 lds[4 * 8192];
  const int tid = threadIdx.x;
  const int lane = tid & 63;
  const int wave = tid >> 6;
  const int mtile = blockIdx.y, ntile = blockIdx.x, z = blockIdx.z;

  const int zb = (SPLITK > 1) ? z / SPLITK : z;
  const int zc = (SPLITK > 1) ? z % SPLITK : 0;
  const u16* Ab = A + (long)zb * Azoff + (long)zc * K;
  const u16* Bb = B + (long)zb * Bzoff + ((BMODE == 0) ? (long)zc * K : 0);

  const int r8 = lane >> 3;
  const int sphys = lane & 7;
  const u16* aSrc[4];
  const u16* bSrc[4];
  u16* aDst[4];
  u16* bDst[4];
#pragma unroll
  for (int i = 0; i < 4; i++) {
    const int row = wave * 32 + i * 8 + r8;
    const int slog = sphys ^ (row & 7);
    aSrc[i] = Ab + (long)(mtile * 128 + row) * Astride + slog * 8;
    if (BMODE == 0) {
      bSrc[i] = Bb + (long)(ntile * 128 + row) * Bstride + slog * 8;
    } else {
      const int n = ntile * 128 + row;
      const int img = n >> 10;
      const int p = n & 1023;
      const int y = p >> 5, x = p & 31;
      bSrc[i] = Bb + ((long)(img * 34 + y) * 34 + x) * 1024 + slog * 8;
    }
    aDst[i] = &lds[0] + (wave * 32 + i * 8) * 64;
    bDst[i] = &lds[0] + 8192 + (wave * 32 + i * 8) * 64;
  }

  const int g = lane >> 4, l15 = lane & 15;
  const int wm = wave >> 1, wn = wave & 1;
  int offA[2][4], offB[2][4];
#pragma unroll
  for (int ks = 0; ks < 2; ks++) {
    const int sl = ks * 4 + g;
#pragma unroll
    for (int i = 0; i < 4; i++) {
      const int ra = wm * 64 + i * 16 + l15;
      offA[ks][i] = ra * 64 + ((sl ^ (ra & 7)) * 8);
      const int rb = wn * 64 + i * 16 + l15;
      offB[ks][i] = 8192 + rb * 64 + ((sl ^ (rb & 7)) * 8);
    }
  }

  auto stage = [&](int buf, int kb) {
    int bAdd;
    if (BMODE == 0) {
      bAdd = kb;
    } else if (BMODE == 1) {
      const int ktg = (zc * K + kb) >> 6;
      const int cblk = ktg / 9;
      const int t = ktg - cblk * 9;
      const int dy = t / 3, dx = t - dy * 3;
      bAdd = (dy * 34 + dx) * 1024 + cblk * 64;
    } else {
      bAdd = 35 * 1024 + kb;
    }
    const int bufo = buf * 16384;
#pragma unroll
    for (int i = 0; i < 4; i++) gll16(aSrc[i] + kb, aDst[i] + bufo);
#pragma unroll
    for (int i = 0; i < 4; i++) gll16(bSrc[i] + bAdd, bDst[i] + bufo);
  };

  f32x4 acc[4][4];
  const f32x4 zero = {0.f, 0.f, 0.f, 0.f};
#pragma unroll
  for (int i = 0; i < 4; i++)
#pragma unroll
    for (int j = 0; j < 4; j++) acc[i][j] = zero;

  const int nkt = K >> 6;
  stage(0, 0);
  __syncthreads();
  for (int kt = 0; kt < nkt; ++kt) {
    const int buf = kt & 1;
    if (kt + 1 < nkt) stage(buf ^ 1, (kt + 1) << 6);
#pragma unroll
    for (int ks = 0; ks < 2; ks++) {
      f16x8 af[4], bfg[4];
#pragma unroll
      for (int i = 0; i < 4; i++)
        af[i] = *(const f16x8*)&lds[buf * 16384 + offA[ks][i]];
#pragma unroll
      for (int i = 0; i < 4; i++)
        bfg[i] = *(const f16x8*)&lds[buf * 16384 + offB[ks][i]];
#pragma unroll
      for (int mi = 0; mi < 4; mi++)
#pragma unroll
        for (int ni = 0; ni < 4; ni++)
          acc[mi][ni] = __builtin_amdgcn_mfma_f32_16x16x32_f16(
              af[mi], bfg[ni], acc[mi][ni], 0, 0, 0);
    }
    __syncthreads();
  }

#pragma unroll
  for (int mi = 0; mi < 4; mi++) {
#pragma unroll
    for (int ni = 0; ni < 4; ni++) {
      f32x4 v = acc[mi][ni];
      const int m0 = mtile * 128 + wm * 64 + mi * 16 + g * 4;
      const int n = ntile * 128 + wn * 64 + ni * 16 + l15;
      if (EPI == 0) {
        u16* ob = (u16*)out0;
        const float* bs = bias;
        int mm = m0;
        if (out1 != nullptr && m0 >= 128) { ob = (u16*)out1; bs = bias2; mm = m0 - 128; }
        u16x4 pk;
#pragma unroll
        for (int r = 0; r < 4; r++) {
          float val = v[r] * scale + (bs ? bs[mm + r] : 0.f);
          pk[r] = f2h(val);
        }
        *(u16x4*)&ob[(long)n * ldo + mm] = pk;
      } else if (EPI == 1) {
        u16* ob = (u16*)out0 + (long)z * out_zoff;
#pragma unroll
        for (int r = 0; r < 4; r++) {
          const int m = m0 + r;
          float val = v[r] * scale + (bias ? bias[m] : 0.f);
          ob[(long)m * ldo + n] = f2h(val);
        }
      } else if (EPI == 2) {
        float* of = (float*)out0;
        const int img = n >> 10, p = n & 1023;
#pragma unroll
        for (int r = 0; r < 4; r++) {
          const int m = m0 + r;
          of[(long)img * 1048576 + (long)(512 + m) * 1024 + p] =
              v[r] + (bias ? bias[m] : 0.f);
        }
      } else if (EPI == 3) {
        float* of = (float*)out0;
        const int f = n >> 10, p = n & 1023;
        const float dinv = 1.0f / bias2[(long)z * 5120 + n];
#pragma unroll
        for (int r = 0; r < 4; r++) {
          const int m = m0 + r;
          of[(long)z * 5242880 + (long)f * 1048576 + (long)m * 1024 + p] =
              v[r] * dinv;
        }
      } else if (EPI == 4) {
        float* of = (float*)out0 + (long)z * out_zoff;
#pragma unroll
        for (int r = 0; r < 4; r++) of[(long)(m0 + r) * ldo + n] = v[r];
      } else if (EPI == 5) {
        float* of = (float*)out0 + (long)zc * out_zoff;
        *(f32x4*)&of[(long)n * ldo + m0] = v;
      } else if (EPI == 6) {
        u16* ob = (u16*)out0 + (long)z * out_zoff;
#pragma unroll
        for (int r = 0; r < 4; r++) ob[(long)(m0 + r) * ldo + n] = f2h(v[r]);
      } else {  // EPI == 7: f16 row store of exp(v*scale - cexp)
        u16* ob = (u16*)out0 + (long)z * out_zoff;
#pragma unroll
        for (int r = 0; r < 4; r++) {
          const int m = m0 + r;
          ob[(long)m * ldo + n] = f2h(__expf(v[r] * scale - cexp));
        }
      }
    }
  }
}

// ---------- launch ----------
extern "C" void kernel_launch(void* const* d_in, const int* in_sizes, int n_in,
                              void* d_out, int out_size, void* d_ws, size_t ws_size,
                              hipStream_t stream) {
  (void)in_sizes; (void)n_in; (void)out_size;
  const float* query   = (const float*)d_in[0];
  const float* support = (const float*)d_in[1];
  const float* w_sk = (const float*)d_in[2];  const float* b_sk = (const float*)d_in[3];
  const float* w_sv = (const float*)d_in[4];  const float* b_sv = (const float*)d_in[5];
  const float* w_qq = (const float*)d_in[6];  const float* b_qq = (const float*)d_in[7];
  const float* w_qk = (const float*)d_in[8];  const float* b_qk = (const float*)d_in[9];
  const float* w_cq = (const float*)d_in[10]; const float* b_cq = (const float*)d_in[11];
  float* out = (float*)d_out;
  char* ws = (char*)d_ws;

  if (ws_size < 158924800u) return;

  u16* PQ    = (u16*)(ws + 0);
  u16* PS    = (u16*)(ws + 23674880);
  u16* WTSK  = (u16*)(ws + 94699520);
  u16* WTSV  = (u16*)(ws + 97058816);
  u16* WTQQK = (u16*)(ws + 106496000);
  u16* WCQ   = (u16*)(ws + 111214592);
  u16* SKR   = (u16*)(ws + 112263168);
  u16* SVA   = (u16*)(ws + 120127488);
  u16* QQR   = (u16*)(ws + 151584768);
  u16* QKR   = (u16*)(ws + 154206208);
  u16* NEWV  = (u16*)(ws + 156827648);
  u16* P1T   = PS;                       // alias (PS dead after sv conv)
  u16* P2T   = PQ;                       // alias (PQ dead after qqk/qf convs)
  u16* PART2 = (u16*)(ws + 94699520);    // over weights: [16][512][1024] f16
  float* PARTK = (float*)SVA;            // pre-sv aliases
  float* PARTQ = (float*)SVA;
  float* D1 = (float*)(ws + 112263168);  // over SKR (dead after P1 gemm): 2048 f32
  float* D2 = D1 + 2048;                 // 10240 f32

  const float SCALE = 0.08838834764831843f;  // 1/sqrt(128)

  pad_both<<<dim3(1280), 256, 0, stream>>>(query, support, PQ, PS);
  wprep<<<dim3(1408), 256, 0, stream>>>(w_sk, w_sv, w_qq, w_qk, w_cq,
                                        WTSK, WTSV, WTQQK, WCQ);

  // sk conv: split-K=2 -> fp32 partials, then reduce(+bias)
  gemm_nt<1, 5, 2><<<dim3(240, 1, 2), 256, 0, stream>>>(
      WTSK, 0, 9216, PS, 0, 0, 4608, 1.0f, nullptr, nullptr, PARTK, nullptr,
      3932160L, 128);
  reduce_sk<<<dim3(3840), 256, 0, stream>>>(PARTK, b_sk, SKR);

  // qq+qk conv: split-K=2 -> fp32 partials, then reduce(+bias)
  gemm_nt<1, 5, 2><<<dim3(80, 2, 2), 256, 0, stream>>>(
      WTQQK, 0, 9216, PQ, 0, 0, 4608, 1.0f, nullptr, nullptr, PARTQ, nullptr,
      2621440L, 256);
  reduce_qqk<<<dim3(2560), 256, 0, stream>>>(PARTQ, b_qq, b_qk, QQR, QKR);

  // sv conv
  gemm256<<<dim3(120, 2), 512, 0, stream>>>(WTSV, PS, b_sv, SVA);

  // qf 1x1 conv
  gemm_nt<2, 2, 1><<<dim3(80, 4, 1), 256, 0, stream>>>(
      WCQ, 0, 1024, PQ, 0, 0, 1024, 1.0f, b_cq, nullptr, out, nullptr, 0, 0);

  // stage 1: P1hat = exp(QK/sqrt(d) - 12), rowsum D1, newV = SV*P1hat / D1
  gemm_nt<0, 7, 1><<<dim3(120, 8, 2), 256, 0, stream>>>(
      QQR + 262144, 655360L, 128, SKR, 1966080L, 128, 128, SCALE, nullptr,
      nullptr, P1T, nullptr, 15728640L, 15360, 12.0f);
  rowsum60<<<dim3(2048), 256, 0, stream>>>(P1T, D1);
  gemm_nt<0, 6, 8><<<dim3(8, 4, 16), 256, 0, stream>>>(
      SVA, 7864320L, 15360, P1T, 15728640L, 15360, 1920, 1.0f, nullptr,
      nullptr, PART2, nullptr, 524288L, 1024);
  reduce8h<<<dim3(1024), 256, 0, stream>>>(PART2, D1, NEWV);

  // stage 2: P2hat = exp(QK/sqrt(d) - 10), rowsum D2, Out = newV*P2hat / D2
  gemm_nt<0, 7, 1><<<dim3(8, 40, 2), 256, 0, stream>>>(
      QQR, 655360L, 128, QKR + 262144, 655360L, 128, 128, SCALE, nullptr,
      nullptr, P2T, nullptr, 5242880L, 1024, 10.0f);
  rowsum4<<<dim3(10240), 256, 0, stream>>>(P2T, D2);
  gemm_nt<0, 3, 1><<<dim3(40, 4, 2), 256, 0, stream>>>(
      NEWV, 524288L, 1024, P2T, 5242880L, 1024, 1024, 1.0f, nullptr, D2,
      out, nullptr, 0, 0);
}